// Round 7
// baseline (1599.382 us; speedup 1.0000x reference)
//
#include <hip/hip_runtime.h>
#include <hip/hip_bf16.h>

// ---------------------------------------------------------------------------
// StackGCNEncoder on MI355X — round 7:
//   + split passes ELIMINATED: GEMM stages A as raw f32 (global_load_lds),
//     converts to hi/lo bf16 in-register after ds_read (truncate-split;
//     lo captures exact remainder -> same 2^-16 residual as before)
//   + pad rows routed to a zeroed page via per-lane global source address
//   + L0 spmm epilogue writes f32 A for layer 1 (no split math)
//   + RNA+PROT spmm merged into one dispatch per layer; hist/fill z-merged
// ---------------------------------------------------------------------------

typedef unsigned short u16;
typedef short s16x8 __attribute__((ext_vector_type(8)));
typedef float f32x4 __attribute__((ext_vector_type(4)));
typedef __attribute__((ext_vector_type(2))) unsigned short u16x2;

__device__ __forceinline__ u16 f2bf(float x) {            // RNE f32->bf16
    unsigned u = __float_as_uint(x);
    return (u16)((u + 0x7fff + ((u >> 16) & 1)) >> 16);
}
__device__ __forceinline__ float bf2f(u16 h) {
    return __uint_as_float(((unsigned)h) << 16);
}

__device__ __forceinline__ void gload16(const u16* g, u16* l) {
    __builtin_amdgcn_global_load_lds(
        (const __attribute__((address_space(1))) unsigned int*)g,
        (__attribute__((address_space(3))) unsigned int*)l,
        16, 0, 0);
}
__device__ __forceinline__ void gload16f(const float* g, float* l) {
    __builtin_amdgcn_global_load_lds(
        (const __attribute__((address_space(1))) unsigned int*)g,
        (__attribute__((address_space(3))) unsigned int*)l,
        16, 0, 0);
}

// truncate-split 8 f32 -> hi/lo bf16x8 (lo = exact remainder, trunc-packed)
__device__ __forceinline__ void cvt_split8(f32x4 a, f32x4 b, s16x8& hi, s16x8& lo)
{
    union U { unsigned u[4]; s16x8 v; };
    U H, L;
    float f[8];
    #pragma unroll
    for (int i = 0; i < 4; ++i) { f[i] = a[i]; f[4 + i] = b[i]; }
    #pragma unroll
    for (int i = 0; i < 4; ++i) {
        float x = f[2 * i], y = f[2 * i + 1];
        unsigned ux = __float_as_uint(x), uy = __float_as_uint(y);
        H.u[i] = (ux >> 16) | (uy & 0xFFFF0000u);
        float rx = __uint_as_float(ux & 0xFFFF0000u);
        float ry = __uint_as_float(uy & 0xFFFF0000u);
        unsigned lx = __float_as_uint(x - rx), ly = __float_as_uint(y - ry);
        L.u[i] = (lx >> 16) | (ly & 0xFFFF0000u);
    }
    hi = H.v; lo = L.v;
}

// ---------------------------------------------------------------------------
// Split-bf16 GEMM, A from f32: [T16|Yb] = A x B^T[N][K]. 128x128 tile, BK=32.
// A rows: row<M1 -> baseR[row]; row<P0 -> zp; row<M2 -> baseP[row-P0]; else zp.
// A staged f32 (16B chunks, phys = logical ^ (row&7)); converted per-fragment.
// B staged hi/lo bf16 (round-6 swizzle, proven conflict-free).
// ---------------------------------------------------------------------------
__global__ __launch_bounds__(256)
void gemm_f32a_kernel(const float* __restrict__ baseR, const float* __restrict__ baseP,
                      const float* __restrict__ zp, int M1, int P0, int M2,
                      const u16* __restrict__ Bh, const u16* __restrict__ Bl,
                      u16* __restrict__ T16, int ldt,
                      float* __restrict__ Yb, int ldb, int tmpw,
                      int K, int nxmask, int nxshift)
{
    __shared__ float ldsA[2][4096];        // 32 KB : 128 rows x 32 f32
    __shared__ u16   ldsB[2][2][4096];     // 32 KB : [hi/lo][128 rows x 32 bf16]

    // bijective XCD swizzle
    const int nwg = gridDim.x;
    const int q   = nwg >> 3, r8 = nwg & 7;
    const int xcd = blockIdx.x & 7, pos = blockIdx.x >> 3;
    const int lin = (xcd < r8 ? xcd * (q + 1) : r8 * (q + 1) + (xcd - r8) * q) + pos;
    const int bm0 = (lin >> nxshift) * 128;
    const int bn0 = (lin & nxmask) * 128;

    const int tid  = threadIdx.x;
    const int lane = tid & 63;
    const int wid  = tid >> 6;
    const int wr   = wid >> 1;
    const int wc   = wid & 1;

    // --- A staging: 4 chunk-loads/thread; call j covers row wid*32+j*8+(lane>>3),
    //     phys chunk lane&7, logical chunk (lane&7)^(lane>>3). Row ptr invariant.
    const int   acl4 = ((lane & 7) ^ (lane >> 3)) * 4;      // f32 offset in row slice
    const float* aptr[4];
    #pragma unroll
    for (int j = 0; j < 4; ++j) {
        const int grow = bm0 + wid * 32 + j * 8 + (lane >> 3);
        const float* p;
        if (grow < M1)      p = baseR + (size_t)grow * K;
        else if (grow < P0) p = zp;
        else if (grow < M2) p = baseP + (size_t)(grow - P0) * K;
        else                p = zp;
        aptr[j] = p + acl4;
    }
    // A LDS dest chunk for call j: (wid*256 + j*64 + lane)*4 floats
    const int adst = (wid * 256 + lane) * 4;

    // --- B staging (round-6): 2 chunk-loads/thread per array
    const int   bsrow = tid >> 2;
    const int   bscol = ((tid & 3) ^ ((tid >> 3) & 3)) * 8;
    const size_t boff0 = (size_t)(bn0 + bsrow) * K + bscol;
    const size_t boff1 = (size_t)(bn0 + bsrow + 64) * K + bscol;
    const int c0 = tid * 8, c1 = 2048 + tid * 8;

    f32x4 zero = {0.f, 0.f, 0.f, 0.f};
    f32x4 acc[4][4];
    #pragma unroll
    for (int i = 0; i < 4; ++i)
        #pragma unroll
        for (int j = 0; j < 4; ++j) acc[i][j] = zero;

    // fragment read constants
    const int m8 = lane & 7;               // row&7 on read side
    const int g2 = (lane >> 4) * 2;
    const int arow_b = wr * 64 + (lane & 15);
    const int fchunk = ((lane >> 4) ^ ((lane >> 1) & 3)) * 8;
    const int b_fr = (wc * 64 + (lane & 15)) * 32 + fchunk;

    const int nk = K >> 5;

    // prologue: stage tile 0 into buf 0
    {
        #pragma unroll
        for (int j = 0; j < 4; ++j)
            gload16f(aptr[j], &ldsA[0][adst + j * 256]);
        gload16(Bh + boff0, &ldsB[0][0][c0]);  gload16(Bh + boff1, &ldsB[0][0][c1]);
        gload16(Bl + boff0, &ldsB[0][1][c0]);  gload16(Bl + boff1, &ldsB[0][1][c1]);
    }

    int cur = 0;
    for (int t = 0; t < nk; ++t) {
        __syncthreads();
        if (t + 1 < nk) {
            const int k0 = (t + 1) * 32;
            const int nb = cur ^ 1;
            #pragma unroll
            for (int j = 0; j < 4; ++j)
                gload16f(aptr[j] + k0, &ldsA[nb][adst + j * 256]);
            gload16(Bh + boff0 + k0, &ldsB[nb][0][c0]);  gload16(Bh + boff1 + k0, &ldsB[nb][0][c1]);
            gload16(Bl + boff0 + k0, &ldsB[nb][1][c0]);  gload16(Bl + boff1 + k0, &ldsB[nb][1][c1]);
        }
        const float* LA  = &ldsA[cur][0];
        const u16*   LBh = &ldsB[cur][0][0];
        const u16*   LBl = &ldsB[cur][1][0];
        s16x8 bh[4], bl[4];
        #pragma unroll
        for (int nf = 0; nf < 4; ++nf) {
            bh[nf] = *(const s16x8*)(LBh + b_fr + nf * 512);
            bl[nf] = *(const s16x8*)(LBl + b_fr + nf * 512);
        }
        #pragma unroll
        for (int mf = 0; mf < 4; ++mf) {
            const int abase = (arow_b + mf * 16) * 32;
            f32x4 e0 = *(const f32x4*)(LA + abase + ((g2 ^ m8) << 2));
            f32x4 e1 = *(const f32x4*)(LA + abase + (((g2 + 1) ^ m8) << 2));
            s16x8 ahv, alv;
            cvt_split8(e0, e1, ahv, alv);
            #pragma unroll
            for (int nf = 0; nf < 4; ++nf) {
                acc[mf][nf] = __builtin_amdgcn_mfma_f32_16x16x32_bf16(ahv, bh[nf], acc[mf][nf], 0, 0, 0);
                acc[mf][nf] = __builtin_amdgcn_mfma_f32_16x16x32_bf16(ahv, bl[nf], acc[mf][nf], 0, 0, 0);
                acc[mf][nf] = __builtin_amdgcn_mfma_f32_16x16x32_bf16(alv, bh[nf], acc[mf][nf], 0, 0, 0);
            }
        }
        cur ^= 1;
    }

    // epilogue: whole block is either tmp (bf16) or base (f32), tmpw%128==0
    if (bn0 < tmpw) {
        #pragma unroll
        for (int mf = 0; mf < 4; ++mf) {
            const int row0 = bm0 + wr * 64 + mf * 16 + (lane >> 4) * 4;
            #pragma unroll
            for (int nf = 0; nf < 4; ++nf) {
                const int col = bn0 + wc * 64 + nf * 16 + (lane & 15);
                #pragma unroll
                for (int r = 0; r < 4; ++r)
                    T16[(size_t)(row0 + r) * ldt + col] = f2bf(acc[mf][nf][r]);
            }
        }
    } else {
        #pragma unroll
        for (int mf = 0; mf < 4; ++mf) {
            const int row0 = bm0 + wr * 64 + mf * 16 + (lane >> 4) * 4;
            #pragma unroll
            for (int nf = 0; nf < 4; ++nf) {
                const int col = bn0 + wc * 64 + nf * 16 + (lane & 15) - tmpw;
                #pragma unroll
                for (int r = 0; r < 4; ++r)
                    Yb[(size_t)(row0 + r) * ldb + col] = acc[mf][nf][r];
            }
        }
    }
}

// ---------------------------------------------------------------------------
// small utils
// ---------------------------------------------------------------------------
__global__ __launch_bounds__(256)
void zero_f32_kernel(float* __restrict__ p, int n)
{
    int i = blockIdx.x * 256 + threadIdx.x;
    if (i < n) p[i] = 0.f;
}

__global__ __launch_bounds__(256)
void zero_i32_kernel(int* __restrict__ p, int n)
{
    int i = blockIdx.x * 256 + threadIdx.x;
    if (i < n) p[i] = 0;
}

// ---------------------------------------------------------------------------
// CSR build (both sides in one launch via blockIdx.z)
// ---------------------------------------------------------------------------
__global__ __launch_bounds__(256)
void hist2_kernel(const int* __restrict__ rowsR, const int* __restrict__ rowsP,
                  int* __restrict__ cntR, int* __restrict__ cntP,
                  int NR, int NP, int E)
{
    int s = blockIdx.y;
    int e = blockIdx.x * 256 + threadIdx.x;
    if (e >= E) return;
    if (blockIdx.z == 0) atomicAdd(cntR + s * NR + rowsR[(size_t)s * E + e], 1);
    else                 atomicAdd(cntP + s * NP + rowsP[(size_t)s * E + e], 1);
}

__global__ __launch_bounds__(256)
void scan_block_kernel(const int* __restrict__ counts, int* __restrict__ rowptr,
                       int* __restrict__ blocksum, int N, int np1, int NB)
{
    __shared__ int sd[256];
    int s = blockIdx.y;
    int i = blockIdx.x * 256 + threadIdx.x;
    int tid = threadIdx.x;
    int v = (i < N) ? counts[s * N + i] : 0;
    sd[tid] = v;
    __syncthreads();
    #pragma unroll
    for (int off = 1; off < 256; off <<= 1) {
        int t = (tid >= off) ? sd[tid - off] : 0;
        __syncthreads();
        sd[tid] += t;
        __syncthreads();
    }
    if (i < N) rowptr[s * np1 + i] = sd[tid] - v;
    if (tid == 255) blocksum[s * NB + blockIdx.x] = sd[255];
}

__global__ __launch_bounds__(256)
void scan_aux_kernel(int* __restrict__ blocksum, int NB)
{
    __shared__ int sd[256];
    int s = blockIdx.x;
    int tid = threadIdx.x;
    int v = (tid < NB) ? blocksum[s * NB + tid] : 0;
    sd[tid] = v;
    __syncthreads();
    #pragma unroll
    for (int off = 1; off < 256; off <<= 1) {
        int t = (tid >= off) ? sd[tid - off] : 0;
        __syncthreads();
        sd[tid] += t;
        __syncthreads();
    }
    if (tid < NB) blocksum[s * NB + tid] = sd[tid] - v;
}

__global__ __launch_bounds__(256)
void finalize_rowptr_kernel(int* __restrict__ rowptr, const int* __restrict__ blocksum,
                            int* __restrict__ cursor, int N, int np1, int NB, int E)
{
    int s = blockIdx.y;
    int i = blockIdx.x * 256 + threadIdx.x;
    if (i < N) {
        int v = rowptr[s * np1 + i] + blocksum[s * NB + blockIdx.x];
        rowptr[s * np1 + i] = v;
        cursor[s * N + i] = v;
    }
    if (i == N) rowptr[s * np1 + N] = E;
}

__global__ __launch_bounds__(256)
void fill2_kernel(const int* __restrict__ rowsR, const int* __restrict__ colsR,
                  const float* __restrict__ valsR,
                  const int* __restrict__ rowsP, const int* __restrict__ colsP,
                  const float* __restrict__ valsP,
                  int* __restrict__ curR, int* __restrict__ curP,
                  int2* __restrict__ evR, int2* __restrict__ evP,
                  int NR, int NP, int E)
{
    int s = blockIdx.y;
    int e = blockIdx.x * 256 + threadIdx.x;
    if (e >= E) return;
    size_t idx = (size_t)s * E + e;
    if (blockIdx.z == 0) {
        int pos = atomicAdd(curR + s * NR + rowsR[idx], 1);
        evR[(size_t)s * E + pos] = make_int2(colsR[idx], __float_as_int(valsR[idx]));
    } else {
        int pos = atomicAdd(curP + s * NP + rowsP[idx], 1);
        evP[(size_t)s * E + pos] = make_int2(colsP[idx], __float_as_int(valsP[idx]));
    }
}

// ---------------------------------------------------------------------------
// CSR SpMM over bf16 tmp, both sides in one grid. 4 waves = 4 relations.
// MODE 0: Base[r][col] += acc          (fallback L1)
// MODE 1: Out[r][col] = relu(Base+acc) (f32)
// ---------------------------------------------------------------------------
template<int KCH, int MODE>
__global__ __launch_bounds__(256)
void spmm2_kernel(const int* __restrict__ rpR, const int* __restrict__ rpP,
                  int np1R, int np1P,
                  const int2* __restrict__ evRg, const int2* __restrict__ evPg,
                  const u16* __restrict__ InR, const u16* __restrict__ InP, int ldi,
                  float* __restrict__ BaseR, float* __restrict__ BaseP, int ldb,
                  float* __restrict__ OutR, float* __restrict__ OutP, int ldo,
                  int NR, int E)
{
    int r = blockIdx.x;
    const int s    = threadIdx.x >> 6;
    const int lane = threadIdx.x & 63;
    const int* rp; const int2* ev; const u16* In; float* Base; float* Out; int np1;
    if (r < NR) { rp = rpR; ev = evRg; In = InR; Base = BaseR; Out = OutR; np1 = np1R; }
    else { r -= NR; rp = rpP; ev = evPg; In = InP; Base = BaseP; Out = OutP; np1 = np1P; }
    int e0 = rp[s * np1 + r];
    int e1 = rp[s * np1 + r + 1];
    if (MODE == 0 && e0 == e1) return;
    ev += (size_t)s * E;

    if (KCH == 128) {
        const int col = s * 128 + lane * 2;
        float ax = 0.f, ay = 0.f;
        int e = e0;
        for (; e + 3 < e1; e += 4) {
            int2 pa = ev[e], pb = ev[e+1], pc = ev[e+2], pd = ev[e+3];
            float va = __int_as_float(pa.y), vb = __int_as_float(pb.y);
            float vc = __int_as_float(pc.y), vd = __int_as_float(pd.y);
            u16x2 xa = *(const u16x2*)(In + (size_t)pa.x * ldi + col);
            u16x2 xb = *(const u16x2*)(In + (size_t)pb.x * ldi + col);
            u16x2 xc = *(const u16x2*)(In + (size_t)pc.x * ldi + col);
            u16x2 xd = *(const u16x2*)(In + (size_t)pd.x * ldi + col);
            ax += va * bf2f(xa[0]) + vb * bf2f(xb[0]) + vc * bf2f(xc[0]) + vd * bf2f(xd[0]);
            ay += va * bf2f(xa[1]) + vb * bf2f(xb[1]) + vc * bf2f(xc[1]) + vd * bf2f(xd[1]);
        }
        for (; e < e1; ++e) {
            int2 p = ev[e];
            float v = __int_as_float(p.y);
            u16x2 x = *(const u16x2*)(In + (size_t)p.x * ldi + col);
            ax += v * bf2f(x[0]);  ay += v * bf2f(x[1]);
        }
        if (MODE == 0) {
            float2* o = (float2*)(Base + (size_t)r * ldb + col);
            float2 cv = *o; cv.x += ax; cv.y += ay; *o = cv;
        } else {
            const float2 b = *(const float2*)(Base + (size_t)r * ldb + col);
            float2 o; o.x = fmaxf(b.x + ax, 0.f); o.y = fmaxf(b.y + ay, 0.f);
            *(float2*)(Out + (size_t)r * ldo + col) = o;
        }
    } else {   // KCH == 64
        const int col = s * 64 + lane;
        float acc = 0.f;
        int e = e0;
        for (; e + 3 < e1; e += 4) {
            int2 pa = ev[e], pb = ev[e+1], pc = ev[e+2], pd = ev[e+3];
            acc += __int_as_float(pa.y) * bf2f(In[(size_t)pa.x * ldi + col])
                 + __int_as_float(pb.y) * bf2f(In[(size_t)pb.x * ldi + col])
                 + __int_as_float(pc.y) * bf2f(In[(size_t)pc.x * ldi + col])
                 + __int_as_float(pd.y) * bf2f(In[(size_t)pd.x * ldi + col]);
        }
        for (; e < e1; ++e) {
            int2 p = ev[e];
            acc += __int_as_float(p.y) * bf2f(In[(size_t)p.x * ldi + col]);
        }
        if (MODE == 0) {
            Base[(size_t)r * ldb + col] += acc;
        } else {
            Out[(size_t)r * ldo + col] = fmaxf(Base[(size_t)r * ldb + col] + acc, 0.f);
        }
    }
}

// fallback-only final relu (Base ld 256, rows contiguous)
__global__ __launch_bounds__(256)
void relu_out_kernel(const float* __restrict__ Z, float* __restrict__ out, int M)
{
    int g = blockIdx.x * 256 + threadIdx.x;
    if (g >= M * 256) return;
    out[g] = fmaxf(Z[g], 0.f);
}

// ---------------------------------------------------------------------------
// weight packing (transposed [N][K], hi/lo)
// ---------------------------------------------------------------------------
__global__ __launch_bounds__(256)
void pack_b0_split_kernel(const float* __restrict__ w0, const float* __restrict__ sw0,
                          u16* __restrict__ Bh, u16* __restrict__ Bl)
{
    int g = blockIdx.x * 256 + threadIdx.x;
    int j = g >> 10, d = g & 1023;
    float v;
    if (j < 512) v = w0[((size_t)(j >> 7) * 1024 + d) * 128 + (j & 127)];
    else         v = sw0[(size_t)d * 512 + (j - 512)];
    u16 h = f2bf(v);
    Bh[g] = h;
    Bl[g] = f2bf(v - bf2f(h));
}

__global__ __launch_bounds__(256)
void pack_b1_split_kernel(const float* __restrict__ w1, const float* __restrict__ sw1,
                          u16* __restrict__ Bh, u16* __restrict__ Bl)
{
    int g = blockIdx.x * 256 + threadIdx.x;
    int j = g >> 9, d = g & 511;
    float v;
    if (j < 256) v = w1[((size_t)(j >> 6) * 512 + d) * 64 + (j & 63)];
    else         v = sw1[(size_t)d * 256 + (j - 256)];
    u16 h = f2bf(v);
    Bh[g] = h;
    Bl[g] = f2bf(v - bf2f(h));
}

extern "C" void kernel_launch(void* const* d_in, const int* in_sizes, int n_in,
                              void* d_out, int out_size, void* d_ws, size_t ws_size,
                              hipStream_t stream)
{
    const int*   rna_rows  = (const int*)  d_in[0];
    const int*   rna_cols  = (const int*)  d_in[1];
    const float* rna_vals  = (const float*)d_in[2];
    const int*   prot_rows = (const int*)  d_in[3];
    const int*   prot_cols = (const int*)  d_in[4];
    const float* prot_vals = (const float*)d_in[5];
    const float* H_rna     = (const float*)d_in[6];
    const float* H_prot    = (const float*)d_in[7];
    const float* w0        = (const float*)d_in[8];
    const float* sw0       = (const float*)d_in[9];
    const float* w1        = (const float*)d_in[10];
    const float* sw1       = (const float*)d_in[11];

    const int NRNA = 50000, NPROT = 20000, S = 4, E = 500000;
    const int MP_RNA = 50048, MP_PROT = 20096;
    const int MP_ALL = MP_RNA + MP_PROT;           // 70144 = 548 * 128
    const int M1 = NRNA, P0 = MP_RNA, M2 = MP_RNA + NPROT;   // A-row mapping
    const int NP1_R = NRNA + 1, NP1_P = NPROT + 1;
    const int NB_R = (NRNA + 255) / 256;
    const int NB_P = (NPROT + 255) / 256;
    const int EB   = (E + 255) / 256;
    const int ZPN  = 4096;                          // zero page floats (16 KB)

    // --- ws layout ---
    char* ws = (char*)d_ws;
    size_t off = 0;
    float* Ybase = (float*)(ws + off); off += (size_t)MP_ALL * 512 * 4;   // L0 ld512 / L1 ld256
    u16*   Tmp0  = (u16*)  (ws + off); off += (size_t)MP_ALL * 512 * 2;   // L0 ld512; L1 ld256 alias
    float* F32A  = (float*)(ws + off); off += (size_t)MP_ALL * 512 * 4;   // layer-1 A (f32)
    u16*   B0h   = (u16*)  (ws + off); off += (size_t)1024 * 1024 * 2;
    u16*   B0l   = (u16*)  (ws + off); off += (size_t)1024 * 1024 * 2;
    u16*   B1h   = (u16*)  (ws + off); off += (size_t)512 * 512 * 2;
    u16*   B1l   = (u16*)  (ws + off); off += (size_t)512 * 512 * 2;
    float* zp    = (float*)(ws + off); off += (size_t)ZPN * 4;
    size_t base_bytes = off;

    // CSR scratch size (ev packed int2)
    size_t csr_bytes = 0;
    csr_bytes += (size_t)S * E * 8 * 2;                       // evR + evP
    csr_bytes += ((size_t)S * (NRNA * 2 + NP1_R + NB_R)) * 4;
    csr_bytes += ((size_t)S * (NPROT * 2 + NP1_P + NB_P)) * 4;
    const bool csr_in_ws = (ws_size >= base_bytes + csr_bytes);

    char* csr = csr_in_ws ? (ws + base_bytes) : (char*)d_out;
    size_t coff = 0;
    int2*  evR     = (int2*) (csr + coff); coff += (size_t)S * E * 8;
    int2*  evP     = (int2*) (csr + coff); coff += (size_t)S * E * 8;
    int*   countsR = (int*)  (csr + coff); coff += (size_t)S * NRNA * 4;
    int*   rowptrR = (int*)  (csr + coff); coff += (size_t)S * NP1_R * 4;
    int*   cursorR = (int*)  (csr + coff); coff += (size_t)S * NRNA * 4;
    int*   bsumR   = (int*)  (csr + coff); coff += (size_t)S * NB_R * 4;
    int*   countsP = (int*)  (csr + coff); coff += (size_t)S * NPROT * 4;
    int*   rowptrP = (int*)  (csr + coff); coff += (size_t)S * NP1_P * 4;
    int*   cursorP = (int*)  (csr + coff); coff += (size_t)S * NPROT * 4;
    int*   bsumP   = (int*)  (csr + coff); coff += (size_t)S * NB_P * 4;

    dim3 blk(256);
    float* out = (float*)d_out;

    // --- packs + zero page ---
    pack_b0_split_kernel<<<(1024 * 1024) / 256, blk, 0, stream>>>(w0, sw0, B0h, B0l);
    pack_b1_split_kernel<<<(512 * 512) / 256, blk, 0, stream>>>(w1, sw1, B1h, B1l);
    zero_f32_kernel<<<ZPN / 256, blk, 0, stream>>>(zp, ZPN);

    // --- CSR build (once; reused by both layers) ---
    zero_i32_kernel<<<(S * NRNA + 255) / 256, blk, 0, stream>>>(countsR, S * NRNA);
    zero_i32_kernel<<<(S * NPROT + 255) / 256, blk, 0, stream>>>(countsP, S * NPROT);
    hist2_kernel<<<dim3(EB, S, 2), blk, 0, stream>>>(rna_rows, prot_rows,
                                                     countsR, countsP, NRNA, NPROT, E);
    scan_block_kernel<<<dim3(NB_R, S), blk, 0, stream>>>(countsR, rowptrR, bsumR, NRNA, NP1_R, NB_R);
    scan_block_kernel<<<dim3(NB_P, S), blk, 0, stream>>>(countsP, rowptrP, bsumP, NPROT, NP1_P, NB_P);
    scan_aux_kernel<<<S, blk, 0, stream>>>(bsumR, NB_R);
    scan_aux_kernel<<<S, blk, 0, stream>>>(bsumP, NB_P);
    finalize_rowptr_kernel<<<dim3(NB_R, S), blk, 0, stream>>>(rowptrR, bsumR, cursorR, NRNA, NP1_R, NB_R, E);
    finalize_rowptr_kernel<<<dim3(NB_P, S), blk, 0, stream>>>(rowptrP, bsumP, cursorP, NPROT, NP1_P, NB_P, E);
    fill2_kernel<<<dim3(EB, S, 2), blk, 0, stream>>>(rna_rows, rna_cols, rna_vals,
                                                     prot_rows, prot_cols, prot_vals,
                                                     cursorR, cursorP, evR, evP, NRNA, NPROT, E);

    // --- layer 0 GEMM: A = [H_rna | pad | H_prot | pad] f32, K=1024, 8 N-blocks ---
    gemm_f32a_kernel<<<8 * (MP_ALL / 128), blk, 0, stream>>>(
        H_rna, H_prot, zp, M1, P0, M2,
        B0h, B0l, Tmp0, 512, Ybase, 512, 512, 1024, 7, 3);

    // --- layer 0 SpMM (merged sides): F32A = relu(Ybase + agg(Tmp_other)) ---
    spmm2_kernel<128, 1><<<NRNA + NPROT, blk, 0, stream>>>(
        rowptrR, rowptrP, NP1_R, NP1_P, evR, evP,
        Tmp0 + (size_t)MP_RNA * 512,      // RNA gathers prot tmp
        Tmp0,                             // PROT gathers rna tmp
        512,
        Ybase, Ybase + (size_t)MP_RNA * 512, 512,
        F32A,  F32A  + (size_t)MP_RNA * 512, 512,
        NRNA, E);

    // --- layer 1 GEMM: A = F32A (pads via zp), K=512, 4 N-blocks ---
    gemm_f32a_kernel<<<4 * (MP_ALL / 128), blk, 0, stream>>>(
        F32A, F32A + (size_t)P0 * 512, zp, M1, P0, M2,
        B1h, B1l, Tmp0, 256, Ybase, 256, 256, 512, 3, 2);

    // --- layer 1 SpMM ---
    if (csr_in_ws) {
        spmm2_kernel<64, 1><<<NRNA + NPROT, blk, 0, stream>>>(
            rowptrR, rowptrP, NP1_R, NP1_P, evR, evP,
            Tmp0 + (size_t)MP_RNA * 256, Tmp0, 256,
            Ybase, Ybase + (size_t)MP_RNA * 256, 256,
            out,   out   + (size_t)NRNA * 256, 256,
            NRNA, E);
    } else {
        spmm2_kernel<64, 0><<<NRNA + NPROT, blk, 0, stream>>>(
            rowptrR, rowptrP, NP1_R, NP1_P, evR, evP,
            Tmp0 + (size_t)MP_RNA * 256, Tmp0, 256,
            Ybase, Ybase + (size_t)MP_RNA * 256, 256,
            nullptr, nullptr, 0,
            NRNA, E);
        relu_out_kernel<<<(NRNA * 256) / 256, blk, 0, stream>>>(Ybase, out, NRNA);
        relu_out_kernel<<<(NPROT * 256) / 256, blk, 0, stream>>>(
            Ybase + (size_t)MP_RNA * 256, out + (size_t)NRNA * 256, NPROT);
    }
}

// Round 8
// 1535.495 us; speedup vs baseline: 1.0416x; 1.0416x over previous
//
#include <hip/hip_runtime.h>
#include <hip/hip_bf16.h>

// ---------------------------------------------------------------------------
// StackGCNEncoder on MI355X — round 8:
//   REVERT r7's in-register split (VALU-bound regression) -> round-6 GEMM
//   (pre-split bf16 hi/lo staging, XOR-swizzled LDS, 0 bank conflicts)
//   + T4 counted-vmcnt pipeline: stage-early, s_waitcnt vmcnt(8) + raw
//     s_barrier (prefetch loads stay in flight across MFMA), second bare
//     barrier after reads. No vmcnt(0) drain in the main loop.
//   + merged small launches (zero/scan/finalize z-merged; hist2/fill2/spmm2
//     both-sides kept from r7)
// ---------------------------------------------------------------------------

typedef unsigned short u16;
typedef short s16x8 __attribute__((ext_vector_type(8)));
typedef float f32x4 __attribute__((ext_vector_type(4)));
typedef __attribute__((ext_vector_type(4))) unsigned short u16x4;
typedef __attribute__((ext_vector_type(2))) unsigned short u16x2;

__device__ __forceinline__ u16 f2bf(float x) {            // RNE f32->bf16
    unsigned u = __float_as_uint(x);
    return (u16)((u + 0x7fff + ((u >> 16) & 1)) >> 16);
}
__device__ __forceinline__ float bf2f(u16 h) {
    return __uint_as_float(((unsigned)h) << 16);
}

__device__ __forceinline__ void gload16(const u16* g, u16* l) {
    __builtin_amdgcn_global_load_lds(
        (const __attribute__((address_space(1))) unsigned int*)g,
        (__attribute__((address_space(3))) unsigned int*)l,
        16, 0, 0);
}

// ---------------------------------------------------------------------------
// Split-bf16 GEMM: [T16|Yb] = A[Mpad][K] x B^T[N][K]. 128x128 tile, BK=32.
// LDS: [128 rows][4 chunks of 8 u16], phys chunk = logical ^ ((row>>1)&3)
// (pre-swizzled global source; linear LDS dest; same XOR on ds_read).
// Pipeline: counted vmcnt (8 loads in flight across MFMA), raw barriers.
// ---------------------------------------------------------------------------
__global__ __launch_bounds__(256)
void gemm_split_kernel(const u16* __restrict__ Ah, const u16* __restrict__ Al,
                       const u16* __restrict__ Bh, const u16* __restrict__ Bl,
                       u16* __restrict__ T16, int ldt,
                       float* __restrict__ Yb, int ldb, int tmpw,
                       int K, int nxmask, int nxshift)
{
    __shared__ u16 lds[2][4][128 * 32];   // 64 KB

    // bijective XCD swizzle: consecutive lin ids -> same XCD
    const int nwg = gridDim.x;
    const int q   = nwg >> 3, r8 = nwg & 7;
    const int xcd = blockIdx.x & 7, pos = blockIdx.x >> 3;
    const int lin = (xcd < r8 ? xcd * (q + 1) : r8 * (q + 1) + (xcd - r8) * q) + pos;
    const int bm0 = (lin >> nxshift) * 128;
    const int bn0 = (lin & nxmask) * 128;

    const int tid  = threadIdx.x;
    const int lane = tid & 63;
    const int wid  = tid >> 6;
    const int wr   = wid >> 1;
    const int wc   = wid & 1;

    // staging: thread t -> physical (row = t>>2 [+64], chunk p = t&3);
    // source logical chunk = p ^ ((row>>1)&3)
    const int srow = tid >> 2;
    const int scol = ((tid & 3) ^ ((tid >> 3) & 3)) * 8;   // u16 units
    const size_t aoff0 = (size_t)(bm0 + srow) * K + scol;
    const size_t aoff1 = (size_t)(bm0 + srow + 64) * K + scol;
    const size_t boff0 = (size_t)(bn0 + srow) * K + scol;
    const size_t boff1 = (size_t)(bn0 + srow + 64) * K + scol;
    const int c0 = tid * 8;               // linear LDS dest (u16 units)
    const int c1 = 2048 + tid * 8;

    u16* L0 = &lds[0][0][0];

    f32x4 zero = {0.f, 0.f, 0.f, 0.f};
    f32x4 acc[4][4];
    #pragma unroll
    for (int i = 0; i < 4; ++i)
        #pragma unroll
        for (int j = 0; j < 4; ++j) acc[i][j] = zero;

    // fragment reads: row = (lane&15)+16*mf+64*w, logical chunk = lane>>4,
    // mask = (lane>>1)&3
    const int fchunk = (((lane >> 4) ^ ((lane >> 1) & 3))) * 8;
    const int a_fr = (wr * 64 + (lane & 15)) * 32 + fchunk;
    const int b_fr = (wc * 64 + (lane & 15)) * 32 + fchunk;

    const int nk = K >> 5;

    // prologue: stage tile 0 into buf 0 (8 loads outstanding)
    {
        u16* L = L0;
        gload16(Ah + aoff0, L + c0);            gload16(Ah + aoff1, L + c1);
        gload16(Al + aoff0, L + 4096 + c0);     gload16(Al + aoff1, L + 4096 + c1);
        gload16(Bh + boff0, L + 8192 + c0);     gload16(Bh + boff1, L + 8192 + c1);
        gload16(Bl + boff0, L + 12288 + c0);    gload16(Bl + boff1, L + 12288 + c1);
    }

    int cur = 0;
    for (int t = 0; t < nk; ++t) {
        // stage next tile FIRST (prev reads of that buffer ended at barrier2
        // of iter t-1), then counted wait: oldest 8 (buf[cur]) retired, the
        // 8 just issued stay in flight across the MFMA phase.
        if (t + 1 < nk) {
            const int k0 = (t + 1) * 32;
            u16* L = L0 + (cur ^ 1) * 16384;
            gload16(Ah + aoff0 + k0, L + c0);         gload16(Ah + aoff1 + k0, L + c1);
            gload16(Al + aoff0 + k0, L + 4096 + c0);  gload16(Al + aoff1 + k0, L + 4096 + c1);
            gload16(Bh + boff0 + k0, L + 8192 + c0);  gload16(Bh + boff1 + k0, L + 8192 + c1);
            gload16(Bl + boff0 + k0, L + 12288 + c0); gload16(Bl + boff1 + k0, L + 12288 + c1);
            asm volatile("s_waitcnt vmcnt(8)\n\ts_barrier" ::: "memory");
        } else {
            asm volatile("s_waitcnt vmcnt(0)\n\ts_barrier" ::: "memory");
        }

        const u16* L = L0 + cur * 16384;
        s16x8 bh[4], bl[4];
        #pragma unroll
        for (int nf = 0; nf < 4; ++nf) {
            const int o = b_fr + nf * 512;
            bh[nf] = *(const s16x8*)(L + 8192 + o);
            bl[nf] = *(const s16x8*)(L + 12288 + o);
        }
        #pragma unroll
        for (int mf = 0; mf < 4; ++mf) {
            const int o = a_fr + mf * 512;
            s16x8 ahv = *(const s16x8*)(L + o);
            s16x8 alv = *(const s16x8*)(L + 4096 + o);
            #pragma unroll
            for (int nf = 0; nf < 4; ++nf) {
                acc[mf][nf] = __builtin_amdgcn_mfma_f32_16x16x32_bf16(ahv, bh[nf], acc[mf][nf], 0, 0, 0);
                acc[mf][nf] = __builtin_amdgcn_mfma_f32_16x16x32_bf16(ahv, bl[nf], acc[mf][nf], 0, 0, 0);
                acc[mf][nf] = __builtin_amdgcn_mfma_f32_16x16x32_bf16(alv, bh[nf], acc[mf][nf], 0, 0, 0);
            }
        }
        // all waves done reading buf[cur] before next iter overwrites it
        asm volatile("s_barrier" ::: "memory");
        cur ^= 1;
    }

    // epilogue: whole block is either tmp (bf16) or base (f32), tmpw%128==0
    if (bn0 < tmpw) {
        #pragma unroll
        for (int mf = 0; mf < 4; ++mf) {
            const int row0 = bm0 + wr * 64 + mf * 16 + (lane >> 4) * 4;
            #pragma unroll
            for (int nf = 0; nf < 4; ++nf) {
                const int col = bn0 + wc * 64 + nf * 16 + (lane & 15);
                #pragma unroll
                for (int r = 0; r < 4; ++r)
                    T16[(size_t)(row0 + r) * ldt + col] = f2bf(acc[mf][nf][r]);
            }
        }
    } else {
        #pragma unroll
        for (int mf = 0; mf < 4; ++mf) {
            const int row0 = bm0 + wr * 64 + mf * 16 + (lane >> 4) * 4;
            #pragma unroll
            for (int nf = 0; nf < 4; ++nf) {
                const int col = bn0 + wc * 64 + nf * 16 + (lane & 15) - tmpw;
                #pragma unroll
                for (int r = 0; r < 4; ++r)
                    Yb[(size_t)(row0 + r) * ldb + col] = acc[mf][nf][r];
            }
        }
    }
}

// ---------------------------------------------------------------------------
// f32 [M][K] -> hi/lo bf16 [Mpad][K], zero-padded rows. 4 elems/thread.
// ---------------------------------------------------------------------------
__global__ __launch_bounds__(256)
void split_kernel(const float* __restrict__ A, u16* __restrict__ Hh,
                  u16* __restrict__ Hl, int M, int kshift)
{
    const size_t g  = (size_t)blockIdx.x * 256 + threadIdx.x;
    const size_t i4 = g * 4;
    const int row   = (int)(i4 >> kshift);
    f32x4 v = {0.f, 0.f, 0.f, 0.f};
    if (row < M) v = *(const f32x4*)(A + i4);
    u16x4 h, l;
    #pragma unroll
    for (int j = 0; j < 4; ++j) {
        u16 hb = f2bf(v[j]);
        h[j] = hb;
        l[j] = f2bf(v[j] - bf2f(hb));
    }
    *(u16x4*)(Hh + i4) = h;
    *(u16x4*)(Hl + i4) = l;
}

__global__ __launch_bounds__(256)
void zero2_u16_kernel(u16* __restrict__ a, u16* __restrict__ b, int n)
{
    int i = blockIdx.x * 256 + threadIdx.x;
    if (i < n) { a[i] = 0; b[i] = 0; }
}

// ---------------------------------------------------------------------------
// CSR build (merged R+P launches)
// ---------------------------------------------------------------------------
__global__ __launch_bounds__(256)
void zero2_i32_kernel(int* __restrict__ a, int na, int* __restrict__ b, int nb)
{
    int i = blockIdx.x * 256 + threadIdx.x;
    if (i < na) a[i] = 0;
    if (i < nb) b[i] = 0;
}

__global__ __launch_bounds__(256)
void hist2_kernel(const int* __restrict__ rowsR, const int* __restrict__ rowsP,
                  int* __restrict__ cntR, int* __restrict__ cntP,
                  int NR, int NP, int E)
{
    int s = blockIdx.y;
    int e = blockIdx.x * 256 + threadIdx.x;
    if (e >= E) return;
    if (blockIdx.z == 0) atomicAdd(cntR + s * NR + rowsR[(size_t)s * E + e], 1);
    else                 atomicAdd(cntP + s * NP + rowsP[(size_t)s * E + e], 1);
}

// grid (NB_R, S, 2); z=1 -> P side (extra x-blocks return)
__global__ __launch_bounds__(256)
void scan_block2_kernel(const int* __restrict__ cR, int* __restrict__ rpR,
                        int* __restrict__ bsR, int NR, int np1R, int NBR,
                        const int* __restrict__ cP, int* __restrict__ rpP,
                        int* __restrict__ bsP, int NP, int np1P, int NBP)
{
    const int side = blockIdx.z;
    const int NB = side ? NBP : NBR;
    if ((int)blockIdx.x >= NB) return;
    const int N = side ? NP : NR;
    const int np1 = side ? np1P : np1R;
    const int* counts = side ? cP : cR;
    int* rowptr = side ? rpP : rpR;
    int* blocksum = side ? bsP : bsR;

    __shared__ int sd[256];
    int s = blockIdx.y;
    int i = blockIdx.x * 256 + threadIdx.x;
    int tid = threadIdx.x;
    int v = (i < N) ? counts[s * N + i] : 0;
    sd[tid] = v;
    __syncthreads();
    #pragma unroll
    for (int off = 1; off < 256; off <<= 1) {
        int t = (tid >= off) ? sd[tid - off] : 0;
        __syncthreads();
        sd[tid] += t;
        __syncthreads();
    }
    if (i < N) rowptr[s * np1 + i] = sd[tid] - v;
    if (tid == 255) blocksum[s * NB + blockIdx.x] = sd[255];
}

// grid (8): side = bi>>2, s = bi&3
__global__ __launch_bounds__(256)
void scan_aux2_kernel(int* __restrict__ bsR, int NBR, int* __restrict__ bsP, int NBP)
{
    const int side = blockIdx.x >> 2;
    const int s = blockIdx.x & 3;
    int* blocksum = side ? bsP : bsR;
    const int NB = side ? NBP : NBR;

    __shared__ int sd[256];
    int tid = threadIdx.x;
    int v = (tid < NB) ? blocksum[s * NB + tid] : 0;
    sd[tid] = v;
    __syncthreads();
    #pragma unroll
    for (int off = 1; off < 256; off <<= 1) {
        int t = (tid >= off) ? sd[tid - off] : 0;
        __syncthreads();
        sd[tid] += t;
        __syncthreads();
    }
    if (tid < NB) blocksum[s * NB + tid] = sd[tid] - v;
}

// grid (NB_R, S, 2)
__global__ __launch_bounds__(256)
void finalize2_kernel(int* __restrict__ rpR, const int* __restrict__ bsR,
                      int* __restrict__ curR, int NR, int np1R, int NBR,
                      int* __restrict__ rpP, const int* __restrict__ bsP,
                      int* __restrict__ curP, int NP, int np1P, int NBP, int E)
{
    const int side = blockIdx.z;
    const int NB = side ? NBP : NBR;
    if ((int)blockIdx.x >= NB) return;
    const int N = side ? NP : NR;
    const int np1 = side ? np1P : np1R;
    int* rowptr = side ? rpP : rpR;
    const int* blocksum = side ? bsP : bsR;
    int* cursor = side ? curP : curR;

    int s = blockIdx.y;
    int i = blockIdx.x * 256 + threadIdx.x;
    if (i < N) {
        int v = rowptr[s * np1 + i] + blocksum[s * NB + blockIdx.x];
        rowptr[s * np1 + i] = v;
        cursor[s * N + i] = v;
    }
    if (i == N) rowptr[s * np1 + N] = E;
}

__global__ __launch_bounds__(256)
void fill2_kernel(const int* __restrict__ rowsR, const int* __restrict__ colsR,
                  const float* __restrict__ valsR,
                  const int* __restrict__ rowsP, const int* __restrict__ colsP,
                  const float* __restrict__ valsP,
                  int* __restrict__ curR, int* __restrict__ curP,
                  int2* __restrict__ evR, int2* __restrict__ evP,
                  int NR, int NP, int E)
{
    int s = blockIdx.y;
    int e = blockIdx.x * 256 + threadIdx.x;
    if (e >= E) return;
    size_t idx = (size_t)s * E + e;
    if (blockIdx.z == 0) {
        int pos = atomicAdd(curR + s * NR + rowsR[idx], 1);
        evR[(size_t)s * E + pos] = make_int2(colsR[idx], __float_as_int(valsR[idx]));
    } else {
        int pos = atomicAdd(curP + s * NP + rowsP[idx], 1);
        evP[(size_t)s * E + pos] = make_int2(colsP[idx], __float_as_int(valsP[idx]));
    }
}

// ---------------------------------------------------------------------------
// CSR SpMM over bf16 tmp, both sides in one grid. 4 waves = 4 relations.
// MODE 0: Base[r][col] += acc                          (fallback L1)
// MODE 1: OutH/OutL[r][col] = split(relu(Base+acc))    (L0 -> layer-1 A)
// MODE 2: OutF[r][col]      = relu(Base+acc)           (L1 -> d_out)
// ---------------------------------------------------------------------------
template<int KCH, int MODE>
__global__ __launch_bounds__(256)
void spmm2_kernel(const int* __restrict__ rpR, const int* __restrict__ rpP,
                  int np1R, int np1P,
                  const int2* __restrict__ evRg, const int2* __restrict__ evPg,
                  const u16* __restrict__ InR, const u16* __restrict__ InP, int ldi,
                  float* __restrict__ BaseR, float* __restrict__ BaseP, int ldb,
                  u16* __restrict__ OHR, u16* __restrict__ OLR,
                  u16* __restrict__ OHP, u16* __restrict__ OLP,
                  float* __restrict__ OFR, float* __restrict__ OFP, int ldo,
                  int NR, int E)
{
    int r = blockIdx.x;
    const int s    = threadIdx.x >> 6;
    const int lane = threadIdx.x & 63;
    const int* rp; const int2* ev; const u16* In; float* Base; int np1;
    u16* OH; u16* OL; float* OF;
    if (r < NR) { rp = rpR; ev = evRg; In = InR; Base = BaseR; np1 = np1R;
                  OH = OHR; OL = OLR; OF = OFR; }
    else { r -= NR; rp = rpP; ev = evPg; In = InP; Base = BaseP; np1 = np1P;
           OH = OHP; OL = OLP; OF = OFP; }
    int e0 = rp[s * np1 + r];
    int e1 = rp[s * np1 + r + 1];
    if (MODE == 0 && e0 == e1) return;
    ev += (size_t)s * E;

    if (KCH == 128) {
        const int col = s * 128 + lane * 2;
        float ax = 0.f, ay = 0.f;
        int e = e0;
        for (; e + 3 < e1; e += 4) {
            int2 pa = ev[e], pb = ev[e+1], pc = ev[e+2], pd = ev[e+3];
            float va = __int_as_float(pa.y), vb = __int_as_float(pb.y);
            float vc = __int_as_float(pc.y), vd = __int_as_float(pd.y);
            u16x2 xa = *(const u16x2*)(In + (size_t)pa.x * ldi + col);
            u16x2 xb = *(const u16x2*)(In + (size_t)pb.x * ldi + col);
            u16x2 xc = *(const u16x2*)(In + (size_t)pc.x * ldi + col);
            u16x2 xd = *(const u16x2*)(In + (size_t)pd.x * ldi + col);
            ax += va * bf2f(xa[0]) + vb * bf2f(xb[0]) + vc * bf2f(xc[0]) + vd * bf2f(xd[0]);
            ay += va * bf2f(xa[1]) + vb * bf2f(xb[1]) + vc * bf2f(xc[1]) + vd * bf2f(xd[1]);
        }
        for (; e < e1; ++e) {
            int2 p = ev[e];
            float v = __int_as_float(p.y);
            u16x2 x = *(const u16x2*)(In + (size_t)p.x * ldi + col);
            ax += v * bf2f(x[0]);  ay += v * bf2f(x[1]);
        }
        if (MODE == 0) {
            float2* o = (float2*)(Base + (size_t)r * ldb + col);
            float2 cv = *o; cv.x += ax; cv.y += ay; *o = cv;
        } else if (MODE == 1) {
            const float2 b = *(const float2*)(Base + (size_t)r * ldb + col);
            float fx = fmaxf(b.x + ax, 0.f), fy = fmaxf(b.y + ay, 0.f);
            u16 hx = f2bf(fx), hy = f2bf(fy);
            u16x2 h = {hx, hy};
            u16x2 l = {f2bf(fx - bf2f(hx)), f2bf(fy - bf2f(hy))};
            *(u16x2*)(OH + (size_t)r * ldo + col) = h;
            *(u16x2*)(OL + (size_t)r * ldo + col) = l;
        } else {
            const float2 b = *(const float2*)(Base + (size_t)r * ldb + col);
            float2 o; o.x = fmaxf(b.x + ax, 0.f); o.y = fmaxf(b.y + ay, 0.f);
            *(float2*)(OF + (size_t)r * ldo + col) = o;
        }
    } else {   // KCH == 64
        const int col = s * 64 + lane;
        float acc = 0.f;
        int e = e0;
        for (; e + 3 < e1; e += 4) {
            int2 pa = ev[e], pb = ev[e+1], pc = ev[e+2], pd = ev[e+3];
            acc += __int_as_float(pa.y) * bf2f(In[(size_t)pa.x * ldi + col])
                 + __int_as_float(pb.y) * bf2f(In[(size_t)pb.x * ldi + col])
                 + __int_as_float(pc.y) * bf2f(In[(size_t)pc.x * ldi + col])
                 + __int_as_float(pd.y) * bf2f(In[(size_t)pd.x * ldi + col]);
        }
        for (; e < e1; ++e) {
            int2 p = ev[e];
            acc += __int_as_float(p.y) * bf2f(In[(size_t)p.x * ldi + col]);
        }
        if (MODE == 0) {
            Base[(size_t)r * ldb + col] += acc;
        } else {
            OF[(size_t)r * ldo + col] = fmaxf(Base[(size_t)r * ldb + col] + acc, 0.f);
        }
    }
}

// fallback-only final relu (Base ld 256, rows contiguous)
__global__ __launch_bounds__(256)
void relu_out_kernel(const float* __restrict__ Z, float* __restrict__ out, int M)
{
    int g = blockIdx.x * 256 + threadIdx.x;
    if (g >= M * 256) return;
    out[g] = fmaxf(Z[g], 0.f);
}

// ---------------------------------------------------------------------------
// weight packing (transposed [N][K], hi/lo)
// ---------------------------------------------------------------------------
__global__ __launch_bounds__(256)
void pack_b0_split_kernel(const float* __restrict__ w0, const float* __restrict__ sw0,
                          u16* __restrict__ Bh, u16* __restrict__ Bl)
{
    int g = blockIdx.x * 256 + threadIdx.x;
    int j = g >> 10, d = g & 1023;
    float v;
    if (j < 512) v = w0[((size_t)(j >> 7) * 1024 + d) * 128 + (j & 127)];
    else         v = sw0[(size_t)d * 512 + (j - 512)];
    u16 h = f2bf(v);
    Bh[g] = h;
    Bl[g] = f2bf(v - bf2f(h));
}

__global__ __launch_bounds__(256)
void pack_b1_split_kernel(const float* __restrict__ w1, const float* __restrict__ sw1,
                          u16* __restrict__ Bh, u16* __restrict__ Bl)
{
    int g = blockIdx.x * 256 + threadIdx.x;
    int j = g >> 9, d = g & 511;
    float v;
    if (j < 256) v = w1[((size_t)(j >> 6) * 512 + d) * 64 + (j & 63)];
    else         v = sw1[(size_t)d * 256 + (j - 256)];
    u16 h = f2bf(v);
    Bh[g] = h;
    Bl[g] = f2bf(v - bf2f(h));
}

extern "C" void kernel_launch(void* const* d_in, const int* in_sizes, int n_in,
                              void* d_out, int out_size, void* d_ws, size_t ws_size,
                              hipStream_t stream)
{
    const int*   rna_rows  = (const int*)  d_in[0];
    const int*   rna_cols  = (const int*)  d_in[1];
    const float* rna_vals  = (const float*)d_in[2];
    const int*   prot_rows = (const int*)  d_in[3];
    const int*   prot_cols = (const int*)  d_in[4];
    const float* prot_vals = (const float*)d_in[5];
    const float* H_rna     = (const float*)d_in[6];
    const float* H_prot    = (const float*)d_in[7];
    const float* w0        = (const float*)d_in[8];
    const float* sw0       = (const float*)d_in[9];
    const float* w1        = (const float*)d_in[10];
    const float* sw1       = (const float*)d_in[11];

    const int NRNA = 50000, NPROT = 20000, S = 4, E = 500000;
    const int MP_RNA = 50048, MP_PROT = 20096;
    const int MP_ALL = MP_RNA + MP_PROT;           // 70144 = 548 * 128
    const int NP1_R = NRNA + 1, NP1_P = NPROT + 1;
    const int NB_R = (NRNA + 255) / 256;
    const int NB_P = (NPROT + 255) / 256;
    const int EB   = (E + 255) / 256;

    // --- ws layout ---
    char* ws = (char*)d_ws;
    size_t off = 0;
    float* Ybase = (float*)(ws + off); off += (size_t)MP_ALL * 512 * 4;   // L0 ld512 / L1 ld256
    u16*   Tmp0  = (u16*)  (ws + off); off += (size_t)MP_ALL * 512 * 2;   // L0 ld512; L1 ld256 alias
    u16*   Ahbig = (u16*)  (ws + off); off += (size_t)MP_ALL * 1024 * 2;
    u16*   Albig = (u16*)  (ws + off); off += (size_t)MP_ALL * 1024 * 2;
    u16*   B0h   = (u16*)  (ws + off); off += (size_t)1024 * 1024 * 2;
    u16*   B0l   = (u16*)  (ws + off); off += (size_t)1024 * 1024 * 2;
    u16*   B1h   = (u16*)  (ws + off); off += (size_t)512 * 512 * 2;
    u16*   B1l   = (u16*)  (ws + off); off += (size_t)512 * 512 * 2;
    size_t base_bytes = off;

    u16* AhR = Ahbig;                               // layer-1 A views [MP_ALL][512]
    u16* AlR = Albig;
    u16* AhP = Ahbig + (size_t)MP_RNA * 512;
    u16* AlP = Albig + (size_t)MP_RNA * 512;

    // CSR scratch size (ev packed int2)
    size_t csr_bytes = 0;
    csr_bytes += (size_t)S * E * 8 * 2;                       // evR + evP
    csr_bytes += ((size_t)S * (NRNA * 2 + NP1_R + NB_R)) * 4;
    csr_bytes += ((size_t)S * (NPROT * 2 + NP1_P + NB_P)) * 4;
    const bool csr_in_ws = (ws_size >= base_bytes + csr_bytes);

    char* csr = csr_in_ws ? (ws + base_bytes) : (char*)d_out;
    size_t coff = 0;
    int2*  evR     = (int2*) (csr + coff); coff += (size_t)S * E * 8;
    int2*  evP     = (int2*) (csr + coff); coff += (size_t)S * E * 8;
    int*   countsR = (int*)  (csr + coff); coff += (size_t)S * NRNA * 4;
    int*   rowptrR = (int*)  (csr + coff); coff += (size_t)S * NP1_R * 4;
    int*   cursorR = (int*)  (csr + coff); coff += (size_t)S * NRNA * 4;
    int*   bsumR   = (int*)  (csr + coff); coff += (size_t)S * NB_R * 4;
    int*   countsP = (int*)  (csr + coff); coff += (size_t)S * NPROT * 4;
    int*   rowptrP = (int*)  (csr + coff); coff += (size_t)S * NP1_P * 4;
    int*   cursorP = (int*)  (csr + coff); coff += (size_t)S * NPROT * 4;
    int*   bsumP   = (int*)  (csr + coff); coff += (size_t)S * NB_P * 4;

    dim3 blk(256);
    float* out = (float*)d_out;

    // --- pack weights ---
    pack_b0_split_kernel<<<(1024 * 1024) / 256, blk, 0, stream>>>(w0, sw0, B0h, B0l);
    pack_b1_split_kernel<<<(512 * 512) / 256, blk, 0, stream>>>(w1, sw1, B1h, B1l);

    // --- CSR build (once; reused by both layers) ---
    zero2_i32_kernel<<<(S * NRNA + 255) / 256, blk, 0, stream>>>(countsR, S * NRNA,
                                                                 countsP, S * NPROT);
    hist2_kernel<<<dim3(EB, S, 2), blk, 0, stream>>>(rna_rows, prot_rows,
                                                     countsR, countsP, NRNA, NPROT, E);
    scan_block2_kernel<<<dim3(NB_R, S, 2), blk, 0, stream>>>(
        countsR, rowptrR, bsumR, NRNA, NP1_R, NB_R,
        countsP, rowptrP, bsumP, NPROT, NP1_P, NB_P);
    scan_aux2_kernel<<<8, blk, 0, stream>>>(bsumR, NB_R, bsumP, NB_P);
    finalize2_kernel<<<dim3(NB_R, S, 2), blk, 0, stream>>>(
        rowptrR, bsumR, cursorR, NRNA, NP1_R, NB_R,
        rowptrP, bsumP, cursorP, NPROT, NP1_P, NB_P, E);
    fill2_kernel<<<dim3(EB, S, 2), blk, 0, stream>>>(rna_rows, rna_cols, rna_vals,
                                                     prot_rows, prot_cols, prot_vals,
                                                     cursorR, cursorP, evR, evP, NRNA, NPROT, E);

    // --- layer 0: split (RNA + PROT concatenated over M) + one GEMM ---
    split_kernel<<<MP_RNA, blk, 0, stream>>>(H_rna, Ahbig, Albig, NRNA, 10);
    split_kernel<<<MP_PROT, blk, 0, stream>>>(H_prot, Ahbig + (size_t)MP_RNA * 1024,
                                              Albig + (size_t)MP_RNA * 1024, NPROT, 10);
    gemm_split_kernel<<<8 * (MP_ALL / 128), blk, 0, stream>>>(
        Ahbig, Albig, B0h, B0l, Tmp0, 512, Ybase, 512, 512, 1024, 7, 3);

    // --- layer 0 SpMM (merged sides): Ah/Al = split(relu(Ybase + agg)) ---
    spmm2_kernel<128, 1><<<NRNA + NPROT, blk, 0, stream>>>(
        rowptrR, rowptrP, NP1_R, NP1_P, evR, evP,
        Tmp0 + (size_t)MP_RNA * 512,      // RNA gathers prot tmp
        Tmp0,                             // PROT gathers rna tmp
        512,
        Ybase, Ybase + (size_t)MP_RNA * 512, 512,
        AhR, AlR, AhP, AlP, nullptr, nullptr, 512,
        NRNA, E);

    // --- zero layer-1 A pad rows ---
    zero2_u16_kernel<<<(48 * 512 + 255) / 256, blk, 0, stream>>>(
        AhR + (size_t)NRNA * 512, AlR + (size_t)NRNA * 512, 48 * 512);
    zero2_u16_kernel<<<(96 * 512 + 255) / 256, blk, 0, stream>>>(
        AhP + (size_t)NPROT * 512, AlP + (size_t)NPROT * 512, 96 * 512);

    // --- layer 1: one merged GEMM (N=K=512) ---
    gemm_split_kernel<<<4 * (MP_ALL / 128), blk, 0, stream>>>(
        Ahbig, Albig, B1h, B1l, Tmp0, 256, Ybase, 256, 256, 512, 3, 2);

    // --- layer 1 SpMM ---
    if (csr_in_ws) {
        spmm2_kernel<64, 2><<<NRNA + NPROT, blk, 0, stream>>>(
            rowptrR, rowptrP, NP1_R, NP1_P, evR, evP,
            Tmp0 + (size_t)MP_RNA * 256, Tmp0, 256,
            Ybase, Ybase + (size_t)MP_RNA * 256, 256,
            nullptr, nullptr, nullptr, nullptr,
            out, out + (size_t)NRNA * 256, 256,
            NRNA, E);
    } else {
        spmm2_kernel<64, 0><<<NRNA + NPROT, blk, 0, stream>>>(
            rowptrR, rowptrP, NP1_R, NP1_P, evR, evP,
            Tmp0 + (size_t)MP_RNA * 256, Tmp0, 256,
            Ybase, Ybase + (size_t)MP_RNA * 256, 256,
            nullptr, nullptr, nullptr, nullptr,
            nullptr, nullptr, 0,
            NRNA, E);
        relu_out_kernel<<<(NRNA * 256) / 256, blk, 0, stream>>>(Ybase, out, NRNA);
        relu_out_kernel<<<(NPROT * 256) / 256, blk, 0, stream>>>(
            Ybase + (size_t)MP_RNA * 256, out + (size_t)NRNA * 256, NPROT);
    }
}

// Round 9
// 1522.865 us; speedup vs baseline: 1.0502x; 1.0083x over previous
//
#include <hip/hip_runtime.h>
#include <hip/hip_bf16.h>

// ---------------------------------------------------------------------------
// StackGCNEncoder on MI355X — round 9:
//   GEMM regeometried: 256x256 block tile, 8 waves (512 thr), wave tile
//   128x64, BK=32, 128 KB double-buffered LDS. Cuts LDS bytes/FLOP 1.33x
//   (2-phase was LDS-read-throughput-bound at MfmaUtil ~50%).
//   XOR chunk-swizzle + linear gload_lds staging + counted-vmcnt barriers
//   carried over unchanged from r8 (all row-bit math identical).
//   Non-GEMM pipeline identical to round 8.
// ---------------------------------------------------------------------------

typedef unsigned short u16;
typedef short s16x8 __attribute__((ext_vector_type(8)));
typedef float f32x4 __attribute__((ext_vector_type(4)));
typedef __attribute__((ext_vector_type(4))) unsigned short u16x4;
typedef __attribute__((ext_vector_type(2))) unsigned short u16x2;

__device__ __forceinline__ u16 f2bf(float x) {            // RNE f32->bf16
    unsigned u = __float_as_uint(x);
    return (u16)((u + 0x7fff + ((u >> 16) & 1)) >> 16);
}
__device__ __forceinline__ float bf2f(u16 h) {
    return __uint_as_float(((unsigned)h) << 16);
}

__device__ __forceinline__ void gload16(const u16* g, u16* l) {
    __builtin_amdgcn_global_load_lds(
        (const __attribute__((address_space(1))) unsigned int*)g,
        (__attribute__((address_space(3))) unsigned int*)l,
        16, 0, 0);
}

// ---------------------------------------------------------------------------
// Split-bf16 GEMM: [T16|Yb] = A[Mpad][K] x B^T[N][K].
// 256x256 block, 8 waves (2Mx4N), wave tile 128x64, BK=32.
// LDS buffer (64 KB): [Ah|Al|Bh|Bl] sections of 256 rows x 32 u16;
// phys chunk = logical ^ ((row>>1)&3); linear gload_lds dest.
// ---------------------------------------------------------------------------
__global__ __launch_bounds__(512, 2)
void gemm_split_kernel(const u16* __restrict__ Ah, const u16* __restrict__ Al,
                       const u16* __restrict__ Bh, const u16* __restrict__ Bl,
                       u16* __restrict__ T16, int ldt,
                       float* __restrict__ Yb, int ldb, int tmpw,
                       int K, int nxmask, int nxshift)
{
    __shared__ u16 lds[2][32768];   // 128 KB

    // bijective XCD swizzle: consecutive lin ids -> same XCD
    const int nwg = gridDim.x;
    const int q   = nwg >> 3, r8 = nwg & 7;
    const int xcd = blockIdx.x & 7, pos = blockIdx.x >> 3;
    const int lin = (xcd < r8 ? xcd * (q + 1) : r8 * (q + 1) + (xcd - r8) * q) + pos;
    const int bm0 = (lin >> nxshift) * 256;
    const int bn0 = (lin & nxmask) * 256;

    const int tid  = threadIdx.x;
    const int lane = tid & 63;
    const int wid  = tid >> 6;      // 0..7
    const int wr   = wid >> 2;      // 0..1 -> 128-row half
    const int wc   = wid & 3;       // 0..3 -> 64-col quarter

    // staging: section chunk c = tid (rows 0..127) and tid+512 (rows 128..255);
    // phys chunk = c&3, row = c>>2, source logical chunk = (c&3)^((c>>3)&3)
    const int srow = tid >> 2;                        // 0..127
    const int scol = ((tid & 3) ^ ((tid >> 3) & 3)) * 8;
    const size_t aoff0 = (size_t)(bm0 + srow) * K + scol;
    const size_t aoff1 = (size_t)(bm0 + srow + 128) * K + scol;
    const size_t boff0 = (size_t)(bn0 + srow) * K + scol;
    const size_t boff1 = (size_t)(bn0 + srow + 128) * K + scol;
    const int c0 = tid * 8;          // linear LDS dest (u16 units)
    const int c1 = 4096 + tid * 8;

    f32x4 zero = {0.f, 0.f, 0.f, 0.f};
    f32x4 acc[8][4];
    #pragma unroll
    for (int i = 0; i < 8; ++i)
        #pragma unroll
        for (int j = 0; j < 4; ++j) acc[i][j] = zero;

    // fragment reads: row = base + 16*frag + (lane&15), logical chunk = lane>>4,
    // mask = ((row>>1)&3) = ((lane>>1)&3)  (frag/w offsets only touch bits >=4)
    const int fchunk = (((lane >> 4) ^ ((lane >> 1) & 3))) * 8;
    const int a_fr = (wr * 128 + (lane & 15)) * 32 + fchunk;
    const int b_fr = (wc * 64  + (lane & 15)) * 32 + fchunk;

    const int nk = K >> 5;

    // prologue: stage tile 0 into buf 0 (8 loads outstanding)
    {
        u16* L = lds[0];
        gload16(Ah + aoff0, L + c0);           gload16(Ah + aoff1, L + c1);
        gload16(Al + aoff0, L + 8192 + c0);    gload16(Al + aoff1, L + 8192 + c1);
        gload16(Bh + boff0, L + 16384 + c0);   gload16(Bh + boff1, L + 16384 + c1);
        gload16(Bl + boff0, L + 24576 + c0);   gload16(Bl + boff1, L + 24576 + c1);
    }

    int cur = 0;
    for (int t = 0; t < nk; ++t) {
        // stage next tile first; counted wait retires only buf[cur]'s 8 loads,
        // the 8 just issued stay in flight across the MFMA phase.
        if (t + 1 < nk) {
            const int k0 = (t + 1) * 32;
            u16* L = lds[cur ^ 1];
            gload16(Ah + aoff0 + k0, L + c0);          gload16(Ah + aoff1 + k0, L + c1);
            gload16(Al + aoff0 + k0, L + 8192 + c0);   gload16(Al + aoff1 + k0, L + 8192 + c1);
            gload16(Bh + boff0 + k0, L + 16384 + c0);  gload16(Bh + boff1 + k0, L + 16384 + c1);
            gload16(Bl + boff0 + k0, L + 24576 + c0);  gload16(Bl + boff1 + k0, L + 24576 + c1);
            asm volatile("s_waitcnt vmcnt(8)\n\ts_barrier" ::: "memory");
        } else {
            asm volatile("s_waitcnt vmcnt(0)\n\ts_barrier" ::: "memory");
        }

        const u16* L = lds[cur];
        s16x8 bh[4], bl[4];
        #pragma unroll
        for (int nf = 0; nf < 4; ++nf) {
            const int o = b_fr + nf * 512;
            bh[nf] = *(const s16x8*)(L + 16384 + o);
            bl[nf] = *(const s16x8*)(L + 24576 + o);
        }
        #pragma unroll
        for (int mf = 0; mf < 8; ++mf) {
            const int o = a_fr + mf * 512;
            s16x8 ahv = *(const s16x8*)(L + o);
            s16x8 alv = *(const s16x8*)(L + 8192 + o);
            #pragma unroll
            for (int nf = 0; nf < 4; ++nf) {
                acc[mf][nf] = __builtin_amdgcn_mfma_f32_16x16x32_bf16(ahv, bh[nf], acc[mf][nf], 0, 0, 0);
                acc[mf][nf] = __builtin_amdgcn_mfma_f32_16x16x32_bf16(ahv, bl[nf], acc[mf][nf], 0, 0, 0);
                acc[mf][nf] = __builtin_amdgcn_mfma_f32_16x16x32_bf16(alv, bh[nf], acc[mf][nf], 0, 0, 0);
            }
        }
        // all waves done reading buf[cur] before next iter overwrites it
        asm volatile("s_barrier" ::: "memory");
        cur ^= 1;
    }

    // epilogue: whole block is either tmp (bf16) or base (f32), tmpw%256==0
    if (bn0 < tmpw) {
        #pragma unroll
        for (int mf = 0; mf < 8; ++mf) {
            const int row0 = bm0 + wr * 128 + mf * 16 + (lane >> 4) * 4;
            #pragma unroll
            for (int nf = 0; nf < 4; ++nf) {
                const int col = bn0 + wc * 64 + nf * 16 + (lane & 15);
                #pragma unroll
                for (int r = 0; r < 4; ++r)
                    T16[(size_t)(row0 + r) * ldt + col] = f2bf(acc[mf][nf][r]);
            }
        }
    } else {
        #pragma unroll
        for (int mf = 0; mf < 8; ++mf) {
            const int row0 = bm0 + wr * 128 + mf * 16 + (lane >> 4) * 4;
            #pragma unroll
            for (int nf = 0; nf < 4; ++nf) {
                const int col = bn0 + wc * 64 + nf * 16 + (lane & 15) - tmpw;
                #pragma unroll
                for (int r = 0; r < 4; ++r)
                    Yb[(size_t)(row0 + r) * ldb + col] = acc[mf][nf][r];
            }
        }
    }
}

// ---------------------------------------------------------------------------
// f32 [M][K] -> hi/lo bf16 [Mpad][K], zero-padded rows. 4 elems/thread.
// ---------------------------------------------------------------------------
__global__ __launch_bounds__(256)
void split_kernel(const float* __restrict__ A, u16* __restrict__ Hh,
                  u16* __restrict__ Hl, int M, int kshift)
{
    const size_t g  = (size_t)blockIdx.x * 256 + threadIdx.x;
    const size_t i4 = g * 4;
    const int row   = (int)(i4 >> kshift);
    f32x4 v = {0.f, 0.f, 0.f, 0.f};
    if (row < M) v = *(const f32x4*)(A + i4);
    u16x4 h, l;
    #pragma unroll
    for (int j = 0; j < 4; ++j) {
        u16 hb = f2bf(v[j]);
        h[j] = hb;
        l[j] = f2bf(v[j] - bf2f(hb));
    }
    *(u16x4*)(Hh + i4) = h;
    *(u16x4*)(Hl + i4) = l;
}

__global__ __launch_bounds__(256)
void zero2_u16_kernel(u16* __restrict__ a, u16* __restrict__ b, int n)
{
    int i = blockIdx.x * 256 + threadIdx.x;
    if (i < n) { a[i] = 0; b[i] = 0; }
}

// ---------------------------------------------------------------------------
// CSR build (merged R+P launches)
// ---------------------------------------------------------------------------
__global__ __launch_bounds__(256)
void zero2_i32_kernel(int* __restrict__ a, int na, int* __restrict__ b, int nb)
{
    int i = blockIdx.x * 256 + threadIdx.x;
    if (i < na) a[i] = 0;
    if (i < nb) b[i] = 0;
}

__global__ __launch_bounds__(256)
void hist2_kernel(const int* __restrict__ rowsR, const int* __restrict__ rowsP,
                  int* __restrict__ cntR, int* __restrict__ cntP,
                  int NR, int NP, int E)
{
    int s = blockIdx.y;
    int e = blockIdx.x * 256 + threadIdx.x;
    if (e >= E) return;
    if (blockIdx.z == 0) atomicAdd(cntR + s * NR + rowsR[(size_t)s * E + e], 1);
    else                 atomicAdd(cntP + s * NP + rowsP[(size_t)s * E + e], 1);
}

// grid (NB_R, S, 2); z=1 -> P side (extra x-blocks return)
__global__ __launch_bounds__(256)
void scan_block2_kernel(const int* __restrict__ cR, int* __restrict__ rpR,
                        int* __restrict__ bsR, int NR, int np1R, int NBR,
                        const int* __restrict__ cP, int* __restrict__ rpP,
                        int* __restrict__ bsP, int NP, int np1P, int NBP)
{
    const int side = blockIdx.z;
    const int NB = side ? NBP : NBR;
    if ((int)blockIdx.x >= NB) return;
    const int N = side ? NP : NR;
    const int np1 = side ? np1P : np1R;
    const int* counts = side ? cP : cR;
    int* rowptr = side ? rpP : rpR;
    int* blocksum = side ? bsP : bsR;

    __shared__ int sd[256];
    int s = blockIdx.y;
    int i = blockIdx.x * 256 + threadIdx.x;
    int tid = threadIdx.x;
    int v = (i < N) ? counts[s * N + i] : 0;
    sd[tid] = v;
    __syncthreads();
    #pragma unroll
    for (int off = 1; off < 256; off <<= 1) {
        int t = (tid >= off) ? sd[tid - off] : 0;
        __syncthreads();
        sd[tid] += t;
        __syncthreads();
    }
    if (i < N) rowptr[s * np1 + i] = sd[tid] - v;
    if (tid == 255) blocksum[s * NB + blockIdx.x] = sd[255];
}

// grid (8): side = bi>>2, s = bi&3
__global__ __launch_bounds__(256)
void scan_aux2_kernel(int* __restrict__ bsR, int NBR, int* __restrict__ bsP, int NBP)
{
    const int side = blockIdx.x >> 2;
    const int s = blockIdx.x & 3;
    int* blocksum = side ? bsP : bsR;
    const int NB = side ? NBP : NBR;

    __shared__ int sd[256];
    int tid = threadIdx.x;
    int v = (tid < NB) ? blocksum[s * NB + tid] : 0;
    sd[tid] = v;
    __syncthreads();
    #pragma unroll
    for (int off = 1; off < 256; off <<= 1) {
        int t = (tid >= off) ? sd[tid - off] : 0;
        __syncthreads();
        sd[tid] += t;
        __syncthreads();
    }
    if (tid < NB) blocksum[s * NB + tid] = sd[tid] - v;
}

// grid (NB_R, S, 2)
__global__ __launch_bounds__(256)
void finalize2_kernel(int* __restrict__ rpR, const int* __restrict__ bsR,
                      int* __restrict__ curR, int NR, int np1R, int NBR,
                      int* __restrict__ rpP, const int* __restrict__ bsP,
                      int* __restrict__ curP, int NP, int np1P, int NBP, int E)
{
    const int side = blockIdx.z;
    const int NB = side ? NBP : NBR;
    if ((int)blockIdx.x >= NB) return;
    const int N = side ? NP : NR;
    const int np1 = side ? np1P : np1R;
    int* rowptr = side ? rpP : rpR;
    const int* blocksum = side ? bsP : bsR;
    int* cursor = side ? curP : curR;

    int s = blockIdx.y;
    int i = blockIdx.x * 256 + threadIdx.x;
    if (i < N) {
        int v = rowptr[s * np1 + i] + blocksum[s * NB + blockIdx.x];
        rowptr[s * np1 + i] = v;
        cursor[s * N + i] = v;
    }
    if (i == N) rowptr[s * np1 + N] = E;
}

__global__ __launch_bounds__(256)
void fill2_kernel(const int* __restrict__ rowsR, const int* __restrict__ colsR,
                  const float* __restrict__ valsR,
                  const int* __restrict__ rowsP, const int* __restrict__ colsP,
                  const float* __restrict__ valsP,
                  int* __restrict__ curR, int* __restrict__ curP,
                  int2* __restrict__ evR, int2* __restrict__ evP,
                  int NR, int NP, int E)
{
    int s = blockIdx.y;
    int e = blockIdx.x * 256 + threadIdx.x;
    if (e >= E) return;
    size_t idx = (size_t)s * E + e;
    if (blockIdx.z == 0) {
        int pos = atomicAdd(curR + s * NR + rowsR[idx], 1);
        evR[(size_t)s * E + pos] = make_int2(colsR[idx], __float_as_int(valsR[idx]));
    } else {
        int pos = atomicAdd(curP + s * NP + rowsP[idx], 1);
        evP[(size_t)s * E + pos] = make_int2(colsP[idx], __float_as_int(valsP[idx]));
    }
}

// ---------------------------------------------------------------------------
// CSR SpMM over bf16 tmp, both sides in one grid. 4 waves = 4 relations.
// MODE 0: Base[r][col] += acc                          (fallback L1)
// MODE 1: OutH/OutL[r][col] = split(relu(Base+acc))    (L0 -> layer-1 A)
// MODE 2: OutF[r][col]      = relu(Base+acc)           (L1 -> d_out)
// ---------------------------------------------------------------------------
template<int KCH, int MODE>
__global__ __launch_bounds__(256)
void spmm2_kernel(const int* __restrict__ rpR, const int* __restrict__ rpP,
                  int np1R, int np1P,
                  const int2* __restrict__ evRg, const int2* __restrict__ evPg,
                  const u16* __restrict__ InR, const u16* __restrict__ InP, int ldi,
                  float* __restrict__ BaseR, float* __restrict__ BaseP, int ldb,
                  u16* __restrict__ OHR, u16* __restrict__ OLR,
                  u16* __restrict__ OHP, u16* __restrict__ OLP,
                  float* __restrict__ OFR, float* __restrict__ OFP, int ldo,
                  int NR, int E)
{
    int r = blockIdx.x;
    const int s    = threadIdx.x >> 6;
    const int lane = threadIdx.x & 63;
    const int* rp; const int2* ev; const u16* In; float* Base; int np1;
    u16* OH; u16* OL; float* OF;
    if (r < NR) { rp = rpR; ev = evRg; In = InR; Base = BaseR; np1 = np1R;
                  OH = OHR; OL = OLR; OF = OFR; }
    else { r -= NR; rp = rpP; ev = evPg; In = InP; Base = BaseP; np1 = np1P;
           OH = OHP; OL = OLP; OF = OFP; }
    int e0 = rp[s * np1 + r];
    int e1 = rp[s * np1 + r + 1];
    if (MODE == 0 && e0 == e1) return;
    ev += (size_t)s * E;

    if (KCH == 128) {
        const int col = s * 128 + lane * 2;
        float ax = 0.f, ay = 0.f;
        int e = e0;
        for (; e + 3 < e1; e += 4) {
            int2 pa = ev[e], pb = ev[e+1], pc = ev[e+2], pd = ev[e+3];
            float va = __int_as_float(pa.y), vb = __int_as_float(pb.y);
            float vc = __int_as_float(pc.y), vd = __int_as_float(pd.y);
            u16x2 xa = *(const u16x2*)(In + (size_t)pa.x * ldi + col);
            u16x2 xb = *(const u16x2*)(In + (size_t)pb.x * ldi + col);
            u16x2 xc = *(const u16x2*)(In + (size_t)pc.x * ldi + col);
            u16x2 xd = *(const u16x2*)(In + (size_t)pd.x * ldi + col);
            ax += va * bf2f(xa[0]) + vb * bf2f(xb[0]) + vc * bf2f(xc[0]) + vd * bf2f(xd[0]);
            ay += va * bf2f(xa[1]) + vb * bf2f(xb[1]) + vc * bf2f(xc[1]) + vd * bf2f(xd[1]);
        }
        for (; e < e1; ++e) {
            int2 p = ev[e];
            float v = __int_as_float(p.y);
            u16x2 x = *(const u16x2*)(In + (size_t)p.x * ldi + col);
            ax += v * bf2f(x[0]);  ay += v * bf2f(x[1]);
        }
        if (MODE == 0) {
            float2* o = (float2*)(Base + (size_t)r * ldb + col);
            float2 cv = *o; cv.x += ax; cv.y += ay; *o = cv;
        } else if (MODE == 1) {
            const float2 b = *(const float2*)(Base + (size_t)r * ldb + col);
            float fx = fmaxf(b.x + ax, 0.f), fy = fmaxf(b.y + ay, 0.f);
            u16 hx = f2bf(fx), hy = f2bf(fy);
            u16x2 h = {hx, hy};
            u16x2 l = {f2bf(fx - bf2f(hx)), f2bf(fy - bf2f(hy))};
            *(u16x2*)(OH + (size_t)r * ldo + col) = h;
            *(u16x2*)(OL + (size_t)r * ldo + col) = l;
        } else {
            const float2 b = *(const float2*)(Base + (size_t)r * ldb + col);
            float2 o; o.x = fmaxf(b.x + ax, 0.f); o.y = fmaxf(b.y + ay, 0.f);
            *(float2*)(OF + (size_t)r * ldo + col) = o;
        }
    } else {   // KCH == 64
        const int col = s * 64 + lane;
        float acc = 0.f;
        int e = e0;
        for (; e + 3 < e1; e += 4) {
            int2 pa = ev[e], pb = ev[e+1], pc = ev[e+2], pd = ev[e+3];
            acc += __int_as_float(pa.y) * bf2f(In[(size_t)pa.x * ldi + col])
                 + __int_as_float(pb.y) * bf2f(In[(size_t)pb.x * ldi + col])
                 + __int_as_float(pc.y) * bf2f(In[(size_t)pc.x * ldi + col])
                 + __int_as_float(pd.y) * bf2f(In[(size_t)pd.x * ldi + col]);
        }
        for (; e < e1; ++e) {
            int2 p = ev[e];
            acc += __int_as_float(p.y) * bf2f(In[(size_t)p.x * ldi + col]);
        }
        if (MODE == 0) {
            Base[(size_t)r * ldb + col] += acc;
        } else {
            OF[(size_t)r * ldo + col] = fmaxf(Base[(size_t)r * ldb + col] + acc, 0.f);
        }
    }
}

// fallback-only final relu (Base ld 256, rows contiguous)
__global__ __launch_bounds__(256)
void relu_out_kernel(const float* __restrict__ Z, float* __restrict__ out, int M)
{
    int g = blockIdx.x * 256 + threadIdx.x;
    if (g >= M * 256) return;
    out[g] = fmaxf(Z[g], 0.f);
}

// ---------------------------------------------------------------------------
// weight packing (transposed [N][K], hi/lo)
// ---------------------------------------------------------------------------
__global__ __launch_bounds__(256)
void pack_b0_split_kernel(const float* __restrict__ w0, const float* __restrict__ sw0,
                          u16* __restrict__ Bh, u16* __restrict__ Bl)
{
    int g = blockIdx.x * 256 + threadIdx.x;
    int j = g >> 10, d = g & 1023;
    float v;
    if (j < 512) v = w0[((size_t)(j >> 7) * 1024 + d) * 128 + (j & 127)];
    else         v = sw0[(size_t)d * 512 + (j - 512)];
    u16 h = f2bf(v);
    Bh[g] = h;
    Bl[g] = f2bf(v - bf2f(h));
}

__global__ __launch_bounds__(256)
void pack_b1_split_kernel(const float* __restrict__ w1, const float* __restrict__ sw1,
                          u16* __restrict__ Bh, u16* __restrict__ Bl)
{
    int g = blockIdx.x * 256 + threadIdx.x;
    int j = g >> 9, d = g & 511;
    float v;
    if (j < 256) v = w1[((size_t)(j >> 6) * 512 + d) * 64 + (j & 63)];
    else         v = sw1[(size_t)d * 256 + (j - 256)];
    u16 h = f2bf(v);
    Bh[g] = h;
    Bl[g] = f2bf(v - bf2f(h));
}

extern "C" void kernel_launch(void* const* d_in, const int* in_sizes, int n_in,
                              void* d_out, int out_size, void* d_ws, size_t ws_size,
                              hipStream_t stream)
{
    const int*   rna_rows  = (const int*)  d_in[0];
    const int*   rna_cols  = (const int*)  d_in[1];
    const float* rna_vals  = (const float*)d_in[2];
    const int*   prot_rows = (const int*)  d_in[3];
    const int*   prot_cols = (const int*)  d_in[4];
    const float* prot_vals = (const float*)d_in[5];
    const float* H_rna     = (const float*)d_in[6];
    const float* H_prot    = (const float*)d_in[7];
    const float* w0        = (const float*)d_in[8];
    const float* sw0       = (const float*)d_in[9];
    const float* w1        = (const float*)d_in[10];
    const float* sw1       = (const float*)d_in[11];

    const int NRNA = 50000, NPROT = 20000, S = 4, E = 500000;
    const int MP_RNA = 50048, MP_PROT = 20096;
    const int MP_ALL = MP_RNA + MP_PROT;           // 70144 = 274 * 256
    const int NP1_R = NRNA + 1, NP1_P = NPROT + 1;
    const int NB_R = (NRNA + 255) / 256;
    const int NB_P = (NPROT + 255) / 256;
    const int EB   = (E + 255) / 256;

    // --- ws layout ---
    char* ws = (char*)d_ws;
    size_t off = 0;
    float* Ybase = (float*)(ws + off); off += (size_t)MP_ALL * 512 * 4;   // L0 ld512 / L1 ld256
    u16*   Tmp0  = (u16*)  (ws + off); off += (size_t)MP_ALL * 512 * 2;   // L0 ld512; L1 ld256 alias
    u16*   Ahbig = (u16*)  (ws + off); off += (size_t)MP_ALL * 1024 * 2;
    u16*   Albig = (u16*)  (ws + off); off += (size_t)MP_ALL * 1024 * 2;
    u16*   B0h   = (u16*)  (ws + off); off += (size_t)1024 * 1024 * 2;
    u16*   B0l   = (u16*)  (ws + off); off += (size_t)1024 * 1024 * 2;
    u16*   B1h   = (u16*)  (ws + off); off += (size_t)512 * 512 * 2;
    u16*   B1l   = (u16*)  (ws + off); off += (size_t)512 * 512 * 2;
    size_t base_bytes = off;

    u16* AhR = Ahbig;                               // layer-1 A views [MP_ALL][512]
    u16* AlR = Albig;
    u16* AhP = Ahbig + (size_t)MP_RNA * 512;
    u16* AlP = Albig + (size_t)MP_RNA * 512;

    // CSR scratch size (ev packed int2)
    size_t csr_bytes = 0;
    csr_bytes += (size_t)S * E * 8 * 2;                       // evR + evP
    csr_bytes += ((size_t)S * (NRNA * 2 + NP1_R + NB_R)) * 4;
    csr_bytes += ((size_t)S * (NPROT * 2 + NP1_P + NB_P)) * 4;
    const bool csr_in_ws = (ws_size >= base_bytes + csr_bytes);

    char* csr = csr_in_ws ? (ws + base_bytes) : (char*)d_out;
    size_t coff = 0;
    int2*  evR     = (int2*) (csr + coff); coff += (size_t)S * E * 8;
    int2*  evP     = (int2*) (csr + coff); coff += (size_t)S * E * 8;
    int*   countsR = (int*)  (csr + coff); coff += (size_t)S * NRNA * 4;
    int*   rowptrR = (int*)  (csr + coff); coff += (size_t)S * NP1_R * 4;
    int*   cursorR = (int*)  (csr + coff); coff += (size_t)S * NRNA * 4;
    int*   bsumR   = (int*)  (csr + coff); coff += (size_t)S * NB_R * 4;
    int*   countsP = (int*)  (csr + coff); coff += (size_t)S * NPROT * 4;
    int*   rowptrP = (int*)  (csr + coff); coff += (size_t)S * NP1_P * 4;
    int*   cursorP = (int*)  (csr + coff); coff += (size_t)S * NPROT * 4;
    int*   bsumP   = (int*)  (csr + coff); coff += (size_t)S * NB_P * 4;

    dim3 blk(256);
    dim3 blk512(512);
    float* out = (float*)d_out;

    // --- pack weights ---
    pack_b0_split_kernel<<<(1024 * 1024) / 256, blk, 0, stream>>>(w0, sw0, B0h, B0l);
    pack_b1_split_kernel<<<(512 * 512) / 256, blk, 0, stream>>>(w1, sw1, B1h, B1l);

    // --- CSR build (once; reused by both layers) ---
    zero2_i32_kernel<<<(S * NRNA + 255) / 256, blk, 0, stream>>>(countsR, S * NRNA,
                                                                 countsP, S * NPROT);
    hist2_kernel<<<dim3(EB, S, 2), blk, 0, stream>>>(rna_rows, prot_rows,
                                                     countsR, countsP, NRNA, NPROT, E);
    scan_block2_kernel<<<dim3(NB_R, S, 2), blk, 0, stream>>>(
        countsR, rowptrR, bsumR, NRNA, NP1_R, NB_R,
        countsP, rowptrP, bsumP, NPROT, NP1_P, NB_P);
    scan_aux2_kernel<<<8, blk, 0, stream>>>(bsumR, NB_R, bsumP, NB_P);
    finalize2_kernel<<<dim3(NB_R, S, 2), blk, 0, stream>>>(
        rowptrR, bsumR, cursorR, NRNA, NP1_R, NB_R,
        rowptrP, bsumP, cursorP, NPROT, NP1_P, NB_P, E);
    fill2_kernel<<<dim3(EB, S, 2), blk, 0, stream>>>(rna_rows, rna_cols, rna_vals,
                                                     prot_rows, prot_cols, prot_vals,
                                                     cursorR, cursorP, evR, evP, NRNA, NPROT, E);

    // --- layer 0: split (RNA + PROT concatenated over M) + one GEMM ---
    split_kernel<<<MP_RNA, blk, 0, stream>>>(H_rna, Ahbig, Albig, NRNA, 10);
    split_kernel<<<MP_PROT, blk, 0, stream>>>(H_prot, Ahbig + (size_t)MP_RNA * 1024,
                                              Albig + (size_t)MP_RNA * 1024, NPROT, 10);
    gemm_split_kernel<<<4 * (MP_ALL / 256), blk512, 0, stream>>>(
        Ahbig, Albig, B0h, B0l, Tmp0, 512, Ybase, 512, 512, 1024, 3, 2);

    // --- layer 0 SpMM (merged sides): Ah/Al = split(relu(Ybase + agg)) ---
    spmm2_kernel<128, 1><<<NRNA + NPROT, blk, 0, stream>>>(
        rowptrR, rowptrP, NP1_R, NP1_P, evR, evP,
        Tmp0 + (size_t)MP_RNA * 512,      // RNA gathers prot tmp
        Tmp0,                             // PROT gathers rna tmp
        512,
        Ybase, Ybase + (size_t)MP_RNA * 512, 512,
        AhR, AlR, AhP, AlP, nullptr, nullptr, 512,
        NRNA, E);

    // --- zero layer-1 A pad rows ---
    zero2_u16_kernel<<<(48 * 512 + 255) / 256, blk, 0, stream>>>(
        AhR + (size_t)NRNA * 512, AlR + (size_t)NRNA * 512, 48 * 512);
    zero2_u16_kernel<<<(96 * 512 + 255) / 256, blk, 0, stream>>>(
        AhP + (size_t)NPROT * 512, AlP + (size_t)NPROT * 512, 96 * 512);

    // --- layer 1: one merged GEMM (N=K=512) ---
    gemm_split_kernel<<<2 * (MP_ALL / 256), blk512, 0, stream>>>(
        Ahbig, Albig, B1h, B1l, Tmp0, 256, Ybase, 256, 256, 512, 1, 1);

    // --- layer 1 SpMM ---
    if (csr_in_ws) {
        spmm2_kernel<64, 2><<<NRNA + NPROT, blk, 0, stream>>>(
            rowptrR, rowptrP, NP1_R, NP1_P, evR, evP,
            Tmp0 + (size_t)MP_RNA * 256, Tmp0, 256,
            Ybase, Ybase + (size_t)MP_RNA * 256, 256,
            nullptr, nullptr, nullptr, nullptr,
            out, out + (size_t)NRNA * 256, 256,
            NRNA, E);
    } else {
        spmm2_kernel<64, 0><<<NRNA + NPROT, blk, 0, stream>>>(
            rowptrR, rowptrP, NP1_R, NP1_P, evR, evP,
            Tmp0 + (size_t)MP_RNA * 256, Tmp0, 256,
            Ybase, Ybase + (size_t)MP_RNA * 256, 256,
            nullptr, nullptr, nullptr, nullptr,
            nullptr, nullptr, 0,
            NRNA, E);
        relu_out_kernel<<<(NRNA * 256) / 256, blk, 0, stream>>>(Ybase, out, NRNA);
        relu_out_kernel<<<(NPROT * 256) / 256, blk, 0, stream>>>(
            Ybase + (size_t)MP_RNA * 256, out + (size_t)NRNA * 256, NPROT);
    }
}

// Round 10
// 1303.630 us; speedup vs baseline: 1.2269x; 1.1682x over previous
//
#include <hip/hip_runtime.h>
#include <hip/hip_bf16.h>

// ---------------------------------------------------------------------------
// StackGCNEncoder on MI355X — round 10:
//   REVERT r9 geometry -> r8 128x128 / 4-wave / BK=32 (256 thr).
//   GEMM term reduction by accuracy budget:
//     base blocks (f32 out): 2-term AhBh + AlBh   (B single bf16, err ~0.0025)
//     tmp  blocks (bf16 out): 1-term AhBh         (err below bf16 storage rnd)
//   Bl eliminated everywhere (packing, ws, staging). LDS 48 KB -> 3 blocks/CU.
//   Counted-vmcnt barriers kept (6 full / 4 light loads in flight).
//   Non-GEMM pipeline identical to round 9.
// ---------------------------------------------------------------------------

typedef unsigned short u16;
typedef short s16x8 __attribute__((ext_vector_type(8)));
typedef float f32x4 __attribute__((ext_vector_type(4)));
typedef __attribute__((ext_vector_type(4))) unsigned short u16x4;
typedef __attribute__((ext_vector_type(2))) unsigned short u16x2;

__device__ __forceinline__ u16 f2bf(float x) {            // RNE f32->bf16
    unsigned u = __float_as_uint(x);
    return (u16)((u + 0x7fff + ((u >> 16) & 1)) >> 16);
}
__device__ __forceinline__ float bf2f(u16 h) {
    return __uint_as_float(((unsigned)h) << 16);
}

__device__ __forceinline__ void gload16(const u16* g, u16* l) {
    __builtin_amdgcn_global_load_lds(
        (const __attribute__((address_space(1))) unsigned int*)g,
        (__attribute__((address_space(3))) unsigned int*)l,
        16, 0, 0);
}

// ---------------------------------------------------------------------------
// Mixed-precision GEMM: [T16|Yb] = A x B^T[N][K]. 128x128 tile, BK=32.
// LDS buffer: [Ah | Al | Bh] sections of 128 rows x 32 u16 (24 KB), dbuf 48 KB.
// phys chunk = logical ^ ((row>>1)&3); linear gload_lds dest (r6-proven).
// Block-uniform: bn0 < tmpw -> 1-term (Ah,Bh only) writing bf16;
//                else       -> 2-term (Ah+Al, Bh) writing f32.
// ---------------------------------------------------------------------------
__global__ __launch_bounds__(256)
void gemm_mixed_kernel(const u16* __restrict__ Ah, const u16* __restrict__ Al,
                       const u16* __restrict__ Bh,
                       u16* __restrict__ T16, int ldt,
                       float* __restrict__ Yb, int ldb, int tmpw,
                       int K, int nxmask, int nxshift)
{
    __shared__ u16 lds[2][3][4096];   // 48 KB

    // bijective XCD swizzle: consecutive lin ids -> same XCD
    const int nwg = gridDim.x;
    const int q   = nwg >> 3, r8 = nwg & 7;
    const int xcd = blockIdx.x & 7, pos = blockIdx.x >> 3;
    const int lin = (xcd < r8 ? xcd * (q + 1) : r8 * (q + 1) + (xcd - r8) * q) + pos;
    const int bm0 = (lin >> nxshift) * 128;
    const int bn0 = (lin & nxmask) * 128;
    const bool light = (bn0 < tmpw);

    const int tid  = threadIdx.x;
    const int lane = tid & 63;
    const int wid  = tid >> 6;
    const int wr   = wid >> 1;
    const int wc   = wid & 1;

    // staging: thread t -> physical (row = t>>2 [+64], chunk p = t&3);
    // source logical chunk = p ^ ((row>>1)&3)
    const int srow = tid >> 2;
    const int scol = ((tid & 3) ^ ((tid >> 3) & 3)) * 8;   // u16 units
    const size_t aoff0 = (size_t)(bm0 + srow) * K + scol;
    const size_t aoff1 = (size_t)(bm0 + srow + 64) * K + scol;
    const size_t boff0 = (size_t)(bn0 + srow) * K + scol;
    const size_t boff1 = (size_t)(bn0 + srow + 64) * K + scol;
    const int c0 = tid * 8;               // linear LDS dest within section
    const int c1 = 2048 + tid * 8;

    u16* L0 = &lds[0][0][0];              // buffer stride 12288 u16

    f32x4 zero = {0.f, 0.f, 0.f, 0.f};
    f32x4 acc[4][4];
    #pragma unroll
    for (int i = 0; i < 4; ++i)
        #pragma unroll
        for (int j = 0; j < 4; ++j) acc[i][j] = zero;

    // fragment reads: row = (lane&15)+16*mf+64*w, logical chunk = lane>>4,
    // mask = (lane>>1)&3
    const int fchunk = (((lane >> 4) ^ ((lane >> 1) & 3))) * 8;
    const int a_fr = (wr * 64 + (lane & 15)) * 32 + fchunk;
    const int b_fr = (wc * 64 + (lane & 15)) * 32 + fchunk;

    const int nk = K >> 5;

    if (light) {
        // ---------------- 1-term path: Ah x Bh -> bf16 tmp ----------------
        {
            u16* L = L0;
            gload16(Ah + aoff0, L + c0);          gload16(Ah + aoff1, L + c1);
            gload16(Bh + boff0, L + 8192 + c0);   gload16(Bh + boff1, L + 8192 + c1);
        }
        int cur = 0;
        for (int t = 0; t < nk; ++t) {
            if (t + 1 < nk) {
                const int k0 = (t + 1) * 32;
                u16* L = L0 + (cur ^ 1) * 12288;
                gload16(Ah + aoff0 + k0, L + c0);         gload16(Ah + aoff1 + k0, L + c1);
                gload16(Bh + boff0 + k0, L + 8192 + c0);  gload16(Bh + boff1 + k0, L + 8192 + c1);
                asm volatile("s_waitcnt vmcnt(4)\n\ts_barrier" ::: "memory");
            } else {
                asm volatile("s_waitcnt vmcnt(0)\n\ts_barrier" ::: "memory");
            }
            const u16* L = L0 + cur * 12288;
            s16x8 bh[4];
            #pragma unroll
            for (int nf = 0; nf < 4; ++nf)
                bh[nf] = *(const s16x8*)(L + 8192 + b_fr + nf * 512);
            #pragma unroll
            for (int mf = 0; mf < 4; ++mf) {
                s16x8 ahv = *(const s16x8*)(L + a_fr + mf * 512);
                #pragma unroll
                for (int nf = 0; nf < 4; ++nf)
                    acc[mf][nf] = __builtin_amdgcn_mfma_f32_16x16x32_bf16(ahv, bh[nf], acc[mf][nf], 0, 0, 0);
            }
            asm volatile("s_barrier" ::: "memory");
            cur ^= 1;
        }
        #pragma unroll
        for (int mf = 0; mf < 4; ++mf) {
            const int row0 = bm0 + wr * 64 + mf * 16 + (lane >> 4) * 4;
            #pragma unroll
            for (int nf = 0; nf < 4; ++nf) {
                const int col = bn0 + wc * 64 + nf * 16 + (lane & 15);
                #pragma unroll
                for (int r = 0; r < 4; ++r)
                    T16[(size_t)(row0 + r) * ldt + col] = f2bf(acc[mf][nf][r]);
            }
        }
    } else {
        // ---------------- 2-term path: (Ah+Al) x Bh -> f32 base ----------------
        {
            u16* L = L0;
            gload16(Ah + aoff0, L + c0);          gload16(Ah + aoff1, L + c1);
            gload16(Al + aoff0, L + 4096 + c0);   gload16(Al + aoff1, L + 4096 + c1);
            gload16(Bh + boff0, L + 8192 + c0);   gload16(Bh + boff1, L + 8192 + c1);
        }
        int cur = 0;
        for (int t = 0; t < nk; ++t) {
            if (t + 1 < nk) {
                const int k0 = (t + 1) * 32;
                u16* L = L0 + (cur ^ 1) * 12288;
                gload16(Ah + aoff0 + k0, L + c0);         gload16(Ah + aoff1 + k0, L + c1);
                gload16(Al + aoff0 + k0, L + 4096 + c0);  gload16(Al + aoff1 + k0, L + 4096 + c1);
                gload16(Bh + boff0 + k0, L + 8192 + c0);  gload16(Bh + boff1 + k0, L + 8192 + c1);
                asm volatile("s_waitcnt vmcnt(6)\n\ts_barrier" ::: "memory");
            } else {
                asm volatile("s_waitcnt vmcnt(0)\n\ts_barrier" ::: "memory");
            }
            const u16* L = L0 + cur * 12288;
            s16x8 bh[4];
            #pragma unroll
            for (int nf = 0; nf < 4; ++nf)
                bh[nf] = *(const s16x8*)(L + 8192 + b_fr + nf * 512);
            #pragma unroll
            for (int mf = 0; mf < 4; ++mf) {
                s16x8 ahv = *(const s16x8*)(L + a_fr + mf * 512);
                s16x8 alv = *(const s16x8*)(L + 4096 + a_fr + mf * 512);
                #pragma unroll
                for (int nf = 0; nf < 4; ++nf) {
                    acc[mf][nf] = __builtin_amdgcn_mfma_f32_16x16x32_bf16(ahv, bh[nf], acc[mf][nf], 0, 0, 0);
                    acc[mf][nf] = __builtin_amdgcn_mfma_f32_16x16x32_bf16(alv, bh[nf], acc[mf][nf], 0, 0, 0);
                }
            }
            asm volatile("s_barrier" ::: "memory");
            cur ^= 1;
        }
        #pragma unroll
        for (int mf = 0; mf < 4; ++mf) {
            const int row0 = bm0 + wr * 64 + mf * 16 + (lane >> 4) * 4;
            #pragma unroll
            for (int nf = 0; nf < 4; ++nf) {
                const int col = bn0 + wc * 64 + nf * 16 + (lane & 15) - tmpw;
                #pragma unroll
                for (int r = 0; r < 4; ++r)
                    Yb[(size_t)(row0 + r) * ldb + col] = acc[mf][nf][r];
            }
        }
    }
}

// ---------------------------------------------------------------------------
// f32 [M][K] -> hi/lo bf16 [Mpad][K], zero-padded rows. 4 elems/thread.
// ---------------------------------------------------------------------------
__global__ __launch_bounds__(256)
void split_kernel(const float* __restrict__ A, u16* __restrict__ Hh,
                  u16* __restrict__ Hl, int M, int kshift)
{
    const size_t g  = (size_t)blockIdx.x * 256 + threadIdx.x;
    const size_t i4 = g * 4;
    const int row   = (int)(i4 >> kshift);
    f32x4 v = {0.f, 0.f, 0.f, 0.f};
    if (row < M) v = *(const f32x4*)(A + i4);
    u16x4 h, l;
    #pragma unroll
    for (int j = 0; j < 4; ++j) {
        u16 hb = f2bf(v[j]);
        h[j] = hb;
        l[j] = f2bf(v[j] - bf2f(hb));
    }
    *(u16x4*)(Hh + i4) = h;
    *(u16x4*)(Hl + i4) = l;
}

__global__ __launch_bounds__(256)
void zero2_u16_kernel(u16* __restrict__ a, u16* __restrict__ b, int n)
{
    int i = blockIdx.x * 256 + threadIdx.x;
    if (i < n) { a[i] = 0; b[i] = 0; }
}

// ---------------------------------------------------------------------------
// CSR build (merged R+P launches)
// ---------------------------------------------------------------------------
__global__ __launch_bounds__(256)
void zero2_i32_kernel(int* __restrict__ a, int na, int* __restrict__ b, int nb)
{
    int i = blockIdx.x * 256 + threadIdx.x;
    if (i < na) a[i] = 0;
    if (i < nb) b[i] = 0;
}

__global__ __launch_bounds__(256)
void hist2_kernel(const int* __restrict__ rowsR, const int* __restrict__ rowsP,
                  int* __restrict__ cntR, int* __restrict__ cntP,
                  int NR, int NP, int E)
{
    int s = blockIdx.y;
    int e = blockIdx.x * 256 + threadIdx.x;
    if (e >= E) return;
    if (blockIdx.z == 0) atomicAdd(cntR + s * NR + rowsR[(size_t)s * E + e], 1);
    else                 atomicAdd(cntP + s * NP + rowsP[(size_t)s * E + e], 1);
}

// grid (NB_R, S, 2); z=1 -> P side (extra x-blocks return)
__global__ __launch_bounds__(256)
void scan_block2_kernel(const int* __restrict__ cR, int* __restrict__ rpR,
                        int* __restrict__ bsR, int NR, int np1R, int NBR,
                        const int* __restrict__ cP, int* __restrict__ rpP,
                        int* __restrict__ bsP, int NP, int np1P, int NBP)
{
    const int side = blockIdx.z;
    const int NB = side ? NBP : NBR;
    if ((int)blockIdx.x >= NB) return;
    const int N = side ? NP : NR;
    const int np1 = side ? np1P : np1R;
    const int* counts = side ? cP : cR;
    int* rowptr = side ? rpP : rpR;
    int* blocksum = side ? bsP : bsR;

    __shared__ int sd[256];
    int s = blockIdx.y;
    int i = blockIdx.x * 256 + threadIdx.x;
    int tid = threadIdx.x;
    int v = (i < N) ? counts[s * N + i] : 0;
    sd[tid] = v;
    __syncthreads();
    #pragma unroll
    for (int off = 1; off < 256; off <<= 1) {
        int t = (tid >= off) ? sd[tid - off] : 0;
        __syncthreads();
        sd[tid] += t;
        __syncthreads();
    }
    if (i < N) rowptr[s * np1 + i] = sd[tid] - v;
    if (tid == 255) blocksum[s * NB + blockIdx.x] = sd[255];
}

// grid (8): side = bi>>2, s = bi&3
__global__ __launch_bounds__(256)
void scan_aux2_kernel(int* __restrict__ bsR, int NBR, int* __restrict__ bsP, int NBP)
{
    const int side = blockIdx.x >> 2;
    const int s = blockIdx.x & 3;
    int* blocksum = side ? bsP : bsR;
    const int NB = side ? NBP : NBR;

    __shared__ int sd[256];
    int tid = threadIdx.x;
    int v = (tid < NB) ? blocksum[s * NB + tid] : 0;
    sd[tid] = v;
    __syncthreads();
    #pragma unroll
    for (int off = 1; off < 256; off <<= 1) {
        int t = (tid >= off) ? sd[tid - off] : 0;
        __syncthreads();
        sd[tid] += t;
        __syncthreads();
    }
    if (tid < NB) blocksum[s * NB + tid] = sd[tid] - v;
}

// grid (NB_R, S, 2)
__global__ __launch_bounds__(256)
void finalize2_kernel(int* __restrict__ rpR, const int* __restrict__ bsR,
                      int* __restrict__ curR, int NR, int np1R, int NBR,
                      int* __restrict__ rpP, const int* __restrict__ bsP,
                      int* __restrict__ curP, int NP, int np1P, int NBP, int E)
{
    const int side = blockIdx.z;
    const int NB = side ? NBP : NBR;
    if ((int)blockIdx.x >= NB) return;
    const int N = side ? NP : NR;
    const int np1 = side ? np1P : np1R;
    int* rowptr = side ? rpP : rpR;
    const int* blocksum = side ? bsP : bsR;
    int* cursor = side ? curP : curR;

    int s = blockIdx.y;
    int i = blockIdx.x * 256 + threadIdx.x;
    if (i < N) {
        int v = rowptr[s * np1 + i] + blocksum[s * NB + blockIdx.x];
        rowptr[s * np1 + i] = v;
        cursor[s * N + i] = v;
    }
    if (i == N) rowptr[s * np1 + N] = E;
}

__global__ __launch_bounds__(256)
void fill2_kernel(const int* __restrict__ rowsR, const int* __restrict__ colsR,
                  const float* __restrict__ valsR,
                  const int* __restrict__ rowsP, const int* __restrict__ colsP,
                  const float* __restrict__ valsP,
                  int* __restrict__ curR, int* __restrict__ curP,
                  int2* __restrict__ evR, int2* __restrict__ evP,
                  int NR, int NP, int E)
{
    int s = blockIdx.y;
    int e = blockIdx.x * 256 + threadIdx.x;
    if (e >= E) return;
    size_t idx = (size_t)s * E + e;
    if (blockIdx.z == 0) {
        int pos = atomicAdd(curR + s * NR + rowsR[idx], 1);
        evR[(size_t)s * E + pos] = make_int2(colsR[idx], __float_as_int(valsR[idx]));
    } else {
        int pos = atomicAdd(curP + s * NP + rowsP[idx], 1);
        evP[(size_t)s * E + pos] = make_int2(colsP[idx], __float_as_int(valsP[idx]));
    }
}

// ---------------------------------------------------------------------------
// CSR SpMM over bf16 tmp, both sides in one grid. 4 waves = 4 relations.
// MODE 0: Base[r][col] += acc                          (fallback L1)
// MODE 1: OutH/OutL[r][col] = split(relu(Base+acc))    (L0 -> layer-1 A)
// MODE 2: OutF[r][col]      = relu(Base+acc)           (L1 -> d_out)
// ---------------------------------------------------------------------------
template<int KCH, int MODE>
__global__ __launch_bounds__(256)
void spmm2_kernel(const int* __restrict__ rpR, const int* __restrict__ rpP,
                  int np1R, int np1P,
                  const int2* __restrict__ evRg, const int2* __restrict__ evPg,
                  const u16* __restrict__ InR, const u16* __restrict__ InP, int ldi,
                  float* __restrict__ BaseR, float* __restrict__ BaseP, int ldb,
                  u16* __restrict__ OHR, u16* __restrict__ OLR,
                  u16* __restrict__ OHP, u16* __restrict__ OLP,
                  float* __restrict__ OFR, float* __restrict__ OFP, int ldo,
                  int NR, int E)
{
    int r = blockIdx.x;
    const int s    = threadIdx.x >> 6;
    const int lane = threadIdx.x & 63;
    const int* rp; const int2* ev; const u16* In; float* Base; int np1;
    u16* OH; u16* OL; float* OF;
    if (r < NR) { rp = rpR; ev = evRg; In = InR; Base = BaseR; np1 = np1R;
                  OH = OHR; OL = OLR; OF = OFR; }
    else { r -= NR; rp = rpP; ev = evPg; In = InP; Base = BaseP; np1 = np1P;
           OH = OHP; OL = OLP; OF = OFP; }
    int e0 = rp[s * np1 + r];
    int e1 = rp[s * np1 + r + 1];
    if (MODE == 0 && e0 == e1) return;
    ev += (size_t)s * E;

    if (KCH == 128) {
        const int col = s * 128 + lane * 2;
        float ax = 0.f, ay = 0.f;
        int e = e0;
        for (; e + 3 < e1; e += 4) {
            int2 pa = ev[e], pb = ev[e+1], pc = ev[e+2], pd = ev[e+3];
            float va = __int_as_float(pa.y), vb = __int_as_float(pb.y);
            float vc = __int_as_float(pc.y), vd = __int_as_float(pd.y);
            u16x2 xa = *(const u16x2*)(In + (size_t)pa.x * ldi + col);
            u16x2 xb = *(const u16x2*)(In + (size_t)pb.x * ldi + col);
            u16x2 xc = *(const u16x2*)(In + (size_t)pc.x * ldi + col);
            u16x2 xd = *(const u16x2*)(In + (size_t)pd.x * ldi + col);
            ax += va * bf2f(xa[0]) + vb * bf2f(xb[0]) + vc * bf2f(xc[0]) + vd * bf2f(xd[0]);
            ay += va * bf2f(xa[1]) + vb * bf2f(xb[1]) + vc * bf2f(xc[1]) + vd * bf2f(xd[1]);
        }
        for (; e < e1; ++e) {
            int2 p = ev[e];
            float v = __int_as_float(p.y);
            u16x2 x = *(const u16x2*)(In + (size_t)p.x * ldi + col);
            ax += v * bf2f(x[0]);  ay += v * bf2f(x[1]);
        }
        if (MODE == 0) {
            float2* o = (float2*)(Base + (size_t)r * ldb + col);
            float2 cv = *o; cv.x += ax; cv.y += ay; *o = cv;
        } else if (MODE == 1) {
            const float2 b = *(const float2*)(Base + (size_t)r * ldb + col);
            float fx = fmaxf(b.x + ax, 0.f), fy = fmaxf(b.y + ay, 0.f);
            u16 hx = f2bf(fx), hy = f2bf(fy);
            u16x2 h = {hx, hy};
            u16x2 l = {f2bf(fx - bf2f(hx)), f2bf(fy - bf2f(hy))};
            *(u16x2*)(OH + (size_t)r * ldo + col) = h;
            *(u16x2*)(OL + (size_t)r * ldo + col) = l;
        } else {
            const float2 b = *(const float2*)(Base + (size_t)r * ldb + col);
            float2 o; o.x = fmaxf(b.x + ax, 0.f); o.y = fmaxf(b.y + ay, 0.f);
            *(float2*)(OF + (size_t)r * ldo + col) = o;
        }
    } else {   // KCH == 64
        const int col = s * 64 + lane;
        float acc = 0.f;
        int e = e0;
        for (; e + 3 < e1; e += 4) {
            int2 pa = ev[e], pb = ev[e+1], pc = ev[e+2], pd = ev[e+3];
            acc += __int_as_float(pa.y) * bf2f(In[(size_t)pa.x * ldi + col])
                 + __int_as_float(pb.y) * bf2f(In[(size_t)pb.x * ldi + col])
                 + __int_as_float(pc.y) * bf2f(In[(size_t)pc.x * ldi + col])
                 + __int_as_float(pd.y) * bf2f(In[(size_t)pd.x * ldi + col]);
        }
        for (; e < e1; ++e) {
            int2 p = ev[e];
            acc += __int_as_float(p.y) * bf2f(In[(size_t)p.x * ldi + col]);
        }
        if (MODE == 0) {
            Base[(size_t)r * ldb + col] += acc;
        } else {
            OF[(size_t)r * ldo + col] = fmaxf(Base[(size_t)r * ldb + col] + acc, 0.f);
        }
    }
}

// fallback-only final relu (Base ld 256, rows contiguous)
__global__ __launch_bounds__(256)
void relu_out_kernel(const float* __restrict__ Z, float* __restrict__ out, int M)
{
    int g = blockIdx.x * 256 + threadIdx.x;
    if (g >= M * 256) return;
    out[g] = fmaxf(Z[g], 0.f);
}

// ---------------------------------------------------------------------------
// weight packing (transposed [N][K], hi only — Bl no longer used)
// ---------------------------------------------------------------------------
__global__ __launch_bounds__(256)
void pack_b0_kernel(const float* __restrict__ w0, const float* __restrict__ sw0,
                    u16* __restrict__ Bh)
{
    int g = blockIdx.x * 256 + threadIdx.x;
    int j = g >> 10, d = g & 1023;
    float v;
    if (j < 512) v = w0[((size_t)(j >> 7) * 1024 + d) * 128 + (j & 127)];
    else         v = sw0[(size_t)d * 512 + (j - 512)];
    Bh[g] = f2bf(v);
}

__global__ __launch_bounds__(256)
void pack_b1_kernel(const float* __restrict__ w1, const float* __restrict__ sw1,
                    u16* __restrict__ Bh)
{
    int g = blockIdx.x * 256 + threadIdx.x;
    int j = g >> 9, d = g & 511;
    float v;
    if (j < 256) v = w1[((size_t)(j >> 6) * 512 + d) * 64 + (j & 63)];
    else         v = sw1[(size_t)d * 256 + (j - 256)];
    Bh[g] = f2bf(v);
}

extern "C" void kernel_launch(void* const* d_in, const int* in_sizes, int n_in,
                              void* d_out, int out_size, void* d_ws, size_t ws_size,
                              hipStream_t stream)
{
    const int*   rna_rows  = (const int*)  d_in[0];
    const int*   rna_cols  = (const int*)  d_in[1];
    const float* rna_vals  = (const float*)d_in[2];
    const int*   prot_rows = (const int*)  d_in[3];
    const int*   prot_cols = (const int*)  d_in[4];
    const float* prot_vals = (const float*)d_in[5];
    const float* H_rna     = (const float*)d_in[6];
    const float* H_prot    = (const float*)d_in[7];
    const float* w0        = (const float*)d_in[8];
    const float* sw0       = (const float*)d_in[9];
    const float* w1        = (const float*)d_in[10];
    const float* sw1       = (const float*)d_in[11];

    const int NRNA = 50000, NPROT = 20000, S = 4, E = 500000;
    const int MP_RNA = 50048, MP_PROT = 20096;
    const int MP_ALL = MP_RNA + MP_PROT;           // 70144 = 548 * 128
    const int NP1_R = NRNA + 1, NP1_P = NPROT + 1;
    const int NB_R = (NRNA + 255) / 256;
    const int NB_P = (NPROT + 255) / 256;
    const int EB   = (E + 255) / 256;

    // --- ws layout ---
    char* ws = (char*)d_ws;
    size_t off = 0;
    float* Ybase = (float*)(ws + off); off += (size_t)MP_ALL * 512 * 4;   // L0 ld512 / L1 ld256
    u16*   Tmp0  = (u16*)  (ws + off); off += (size_t)MP_ALL * 512 * 2;   // L0 ld512; L1 ld256 alias
    u16*   Ahbig = (u16*)  (ws + off); off += (size_t)MP_ALL * 1024 * 2;
    u16*   Albig = (u16*)  (ws + off); off += (size_t)MP_ALL * 1024 * 2;
    u16*   B0h   = (u16*)  (ws + off); off += (size_t)1024 * 1024 * 2;
    u16*   B1h   = (u16*)  (ws + off); off += (size_t)512 * 512 * 2;
    size_t base_bytes = off;

    u16* AhR = Ahbig;                               // layer-1 A views [MP_ALL][512]
    u16* AlR = Albig;
    u16* AhP = Ahbig + (size_t)MP_RNA * 512;
    u16* AlP = Albig + (size_t)MP_RNA * 512;

    // CSR scratch size (ev packed int2)
    size_t csr_bytes = 0;
    csr_bytes += (size_t)S * E * 8 * 2;                       // evR + evP
    csr_bytes += ((size_t)S * (NRNA * 2 + NP1_R + NB_R)) * 4;
    csr_bytes += ((size_t)S * (NPROT * 2 + NP1_P + NB_P)) * 4;
    const bool csr_in_ws = (ws_size >= base_bytes + csr_bytes);

    char* csr = csr_in_ws ? (ws + base_bytes) : (char*)d_out;
    size_t coff = 0;
    int2*  evR     = (int2*) (csr + coff); coff += (size_t)S * E * 8;
    int2*  evP     = (int2*) (csr + coff); coff += (size_t)S * E * 8;
    int*   countsR = (int*)  (csr + coff); coff += (size_t)S * NRNA * 4;
    int*   rowptrR = (int*)  (csr + coff); coff += (size_t)S * NP1_R * 4;
    int*   cursorR = (int*)  (csr + coff); coff += (size_t)S * NRNA * 4;
    int*   bsumR   = (int*)  (csr + coff); coff += (size_t)S * NB_R * 4;
    int*   countsP = (int*)  (csr + coff); coff += (size_t)S * NPROT * 4;
    int*   rowptrP = (int*)  (csr + coff); coff += (size_t)S * NP1_P * 4;
    int*   cursorP = (int*)  (csr + coff); coff += (size_t)S * NPROT * 4;
    int*   bsumP   = (int*)  (csr + coff); coff += (size_t)S * NB_P * 4;

    dim3 blk(256);
    float* out = (float*)d_out;

    // --- pack weights (hi only) ---
    pack_b0_kernel<<<(1024 * 1024) / 256, blk, 0, stream>>>(w0, sw0, B0h);
    pack_b1_kernel<<<(512 * 512) / 256, blk, 0, stream>>>(w1, sw1, B1h);

    // --- CSR build (once; reused by both layers) ---
    zero2_i32_kernel<<<(S * NRNA + 255) / 256, blk, 0, stream>>>(countsR, S * NRNA,
                                                                 countsP, S * NPROT);
    hist2_kernel<<<dim3(EB, S, 2), blk, 0, stream>>>(rna_rows, prot_rows,
                                                     countsR, countsP, NRNA, NPROT, E);
    scan_block2_kernel<<<dim3(NB_R, S, 2), blk, 0, stream>>>(
        countsR, rowptrR, bsumR, NRNA, NP1_R, NB_R,
        countsP, rowptrP, bsumP, NPROT, NP1_P, NB_P);
    scan_aux2_kernel<<<8, blk, 0, stream>>>(bsumR, NB_R, bsumP, NB_P);
    finalize2_kernel<<<dim3(NB_R, S, 2), blk, 0, stream>>>(
        rowptrR, bsumR, cursorR, NRNA, NP1_R, NB_R,
        rowptrP, bsumP, cursorP, NPROT, NP1_P, NB_P, E);
    fill2_kernel<<<dim3(EB, S, 2), blk, 0, stream>>>(rna_rows, rna_cols, rna_vals,
                                                     prot_rows, prot_cols, prot_vals,
                                                     cursorR, cursorP, evR, evP, NRNA, NPROT, E);

    // --- layer 0: split (RNA + PROT concatenated over M) + one GEMM ---
    split_kernel<<<MP_RNA, blk, 0, stream>>>(H_rna, Ahbig, Albig, NRNA, 10);
    split_kernel<<<MP_PROT, blk, 0, stream>>>(H_prot, Ahbig + (size_t)MP_RNA * 1024,
                                              Albig + (size_t)MP_RNA * 1024, NPROT, 10);
    gemm_mixed_kernel<<<8 * (MP_ALL / 128), blk, 0, stream>>>(
        Ahbig, Albig, B0h, Tmp0, 512, Ybase, 512, 512, 1024, 7, 3);

    // --- layer 0 SpMM (merged sides): Ah/Al = split(relu(Ybase + agg)) ---
    spmm2_kernel<128, 1><<<NRNA + NPROT, blk, 0, stream>>>(
        rowptrR, rowptrP, NP1_R, NP1_P, evR, evP,
        Tmp0 + (size_t)MP_RNA * 512,      // RNA gathers prot tmp
        Tmp0,                             // PROT gathers rna tmp
        512,
        Ybase, Ybase + (size_t)MP_RNA * 512, 512,
        AhR, AlR, AhP, AlP, nullptr, nullptr, 512,
        NRNA, E);

    // --- zero layer-1 A pad rows ---
    zero2_u16_kernel<<<(48 * 512 + 255) / 256, blk, 0, stream>>>(
        AhR + (size_t)NRNA * 512, AlR + (size_t)NRNA * 512, 48 * 512);
    zero2_u16_kernel<<<(96 * 512 + 255) / 256, blk, 0, stream>>>(
        AhP + (size_t)NPROT * 512, AlP + (size_t)NPROT * 512, 96 * 512);

    // --- layer 1: one merged GEMM (N=K=512) ---
    gemm_mixed_kernel<<<4 * (MP_ALL / 128), blk, 0, stream>>>(
        Ahbig, Albig, B1h, Tmp0, 256, Ybase, 256, 256, 512, 3, 2);

    // --- layer 1 SpMM ---
    if (csr_in_ws) {
        spmm2_kernel<64, 2><<<NRNA + NPROT, blk, 0, stream>>>(
            rowptrR, rowptrP, NP1_R, NP1_P, evR, evP,
            Tmp0 + (size_t)MP_RNA * 256, Tmp0, 256,
            Ybase, Ybase + (size_t)MP_RNA * 256, 256,
            nullptr, nullptr, nullptr, nullptr,
            out, out + (size_t)NRNA * 256, 256,
            NRNA, E);
    } else {
        spmm2_kernel<64, 0><<<NRNA + NPROT, blk, 0, stream>>>(
            rowptrR, rowptrP, NP1_R, NP1_P, evR, evP,
            Tmp0 + (size_t)MP_RNA * 256, Tmp0, 256,
            Ybase, Ybase + (size_t)MP_RNA * 256, 256,
            nullptr, nullptr, nullptr, nullptr,
            nullptr, nullptr, 0,
            NRNA, E);
        relu_out_kernel<<<(NRNA * 256) / 256, blk, 0, stream>>>(Ybase, out, NRNA);
        relu_out_kernel<<<(NPROT * 256) / 256, blk, 0, stream>>>(
            Ybase + (size_t)MP_RNA * 256, out + (size_t)NRNA * 256, NPROT);
    }
}

// Round 11
// 1257.305 us; speedup vs baseline: 1.2721x; 1.0368x over previous
//
#include <hip/hip_runtime.h>
#include <hip/hip_bf16.h>

// ---------------------------------------------------------------------------
// StackGCNEncoder on MI355X — round 11:
//   fill2 -> fill_sliced: row-sliced XCD-affine CSR fill. slice = bx&7 pins
//   each row-range's writes to one XCD's L2 -> full-line writebacks
//   (WRITE 249 MB -> ~payload). Edges re-scanned 8x (sequential, L3-cached).
//   Everything else identical to round 10 (mixed 2-term/1-term GEMM, merged
//   spmm, counted-vmcnt, XOR swizzle).
// ---------------------------------------------------------------------------

typedef unsigned short u16;
typedef short s16x8 __attribute__((ext_vector_type(8)));
typedef float f32x4 __attribute__((ext_vector_type(4)));
typedef __attribute__((ext_vector_type(4))) unsigned short u16x4;
typedef __attribute__((ext_vector_type(2))) unsigned short u16x2;

__device__ __forceinline__ u16 f2bf(float x) {            // RNE f32->bf16
    unsigned u = __float_as_uint(x);
    return (u16)((u + 0x7fff + ((u >> 16) & 1)) >> 16);
}
__device__ __forceinline__ float bf2f(u16 h) {
    return __uint_as_float(((unsigned)h) << 16);
}

__device__ __forceinline__ void gload16(const u16* g, u16* l) {
    __builtin_amdgcn_global_load_lds(
        (const __attribute__((address_space(1))) unsigned int*)g,
        (__attribute__((address_space(3))) unsigned int*)l,
        16, 0, 0);
}

// ---------------------------------------------------------------------------
// Mixed-precision GEMM (round 10, unchanged): [T16|Yb] = A x B^T[N][K].
// 128x128 tile, BK=32, LDS [Ah|Al|Bh] dbuf 48 KB, XOR chunk-swizzle.
// bn0 < tmpw -> 1-term (Ah,Bh) -> bf16;  else 2-term (Ah+Al, Bh) -> f32.
// ---------------------------------------------------------------------------
__global__ __launch_bounds__(256)
void gemm_mixed_kernel(const u16* __restrict__ Ah, const u16* __restrict__ Al,
                       const u16* __restrict__ Bh,
                       u16* __restrict__ T16, int ldt,
                       float* __restrict__ Yb, int ldb, int tmpw,
                       int K, int nxmask, int nxshift)
{
    __shared__ u16 lds[2][3][4096];   // 48 KB

    const int nwg = gridDim.x;
    const int q   = nwg >> 3, r8 = nwg & 7;
    const int xcd = blockIdx.x & 7, pos = blockIdx.x >> 3;
    const int lin = (xcd < r8 ? xcd * (q + 1) : r8 * (q + 1) + (xcd - r8) * q) + pos;
    const int bm0 = (lin >> nxshift) * 128;
    const int bn0 = (lin & nxmask) * 128;
    const bool light = (bn0 < tmpw);

    const int tid  = threadIdx.x;
    const int lane = tid & 63;
    const int wid  = tid >> 6;
    const int wr   = wid >> 1;
    const int wc   = wid & 1;

    const int srow = tid >> 2;
    const int scol = ((tid & 3) ^ ((tid >> 3) & 3)) * 8;   // u16 units
    const size_t aoff0 = (size_t)(bm0 + srow) * K + scol;
    const size_t aoff1 = (size_t)(bm0 + srow + 64) * K + scol;
    const size_t boff0 = (size_t)(bn0 + srow) * K + scol;
    const size_t boff1 = (size_t)(bn0 + srow + 64) * K + scol;
    const int c0 = tid * 8;
    const int c1 = 2048 + tid * 8;

    u16* L0 = &lds[0][0][0];              // buffer stride 12288 u16

    f32x4 zero = {0.f, 0.f, 0.f, 0.f};
    f32x4 acc[4][4];
    #pragma unroll
    for (int i = 0; i < 4; ++i)
        #pragma unroll
        for (int j = 0; j < 4; ++j) acc[i][j] = zero;

    const int fchunk = (((lane >> 4) ^ ((lane >> 1) & 3))) * 8;
    const int a_fr = (wr * 64 + (lane & 15)) * 32 + fchunk;
    const int b_fr = (wc * 64 + (lane & 15)) * 32 + fchunk;

    const int nk = K >> 5;

    if (light) {
        {
            u16* L = L0;
            gload16(Ah + aoff0, L + c0);          gload16(Ah + aoff1, L + c1);
            gload16(Bh + boff0, L + 8192 + c0);   gload16(Bh + boff1, L + 8192 + c1);
        }
        int cur = 0;
        for (int t = 0; t < nk; ++t) {
            if (t + 1 < nk) {
                const int k0 = (t + 1) * 32;
                u16* L = L0 + (cur ^ 1) * 12288;
                gload16(Ah + aoff0 + k0, L + c0);         gload16(Ah + aoff1 + k0, L + c1);
                gload16(Bh + boff0 + k0, L + 8192 + c0);  gload16(Bh + boff1 + k0, L + 8192 + c1);
                asm volatile("s_waitcnt vmcnt(4)\n\ts_barrier" ::: "memory");
            } else {
                asm volatile("s_waitcnt vmcnt(0)\n\ts_barrier" ::: "memory");
            }
            const u16* L = L0 + cur * 12288;
            s16x8 bh[4];
            #pragma unroll
            for (int nf = 0; nf < 4; ++nf)
                bh[nf] = *(const s16x8*)(L + 8192 + b_fr + nf * 512);
            #pragma unroll
            for (int mf = 0; mf < 4; ++mf) {
                s16x8 ahv = *(const s16x8*)(L + a_fr + mf * 512);
                #pragma unroll
                for (int nf = 0; nf < 4; ++nf)
                    acc[mf][nf] = __builtin_amdgcn_mfma_f32_16x16x32_bf16(ahv, bh[nf], acc[mf][nf], 0, 0, 0);
            }
            asm volatile("s_barrier" ::: "memory");
            cur ^= 1;
        }
        #pragma unroll
        for (int mf = 0; mf < 4; ++mf) {
            const int row0 = bm0 + wr * 64 + mf * 16 + (lane >> 4) * 4;
            #pragma unroll
            for (int nf = 0; nf < 4; ++nf) {
                const int col = bn0 + wc * 64 + nf * 16 + (lane & 15);
                #pragma unroll
                for (int r = 0; r < 4; ++r)
                    T16[(size_t)(row0 + r) * ldt + col] = f2bf(acc[mf][nf][r]);
            }
        }
    } else {
        {
            u16* L = L0;
            gload16(Ah + aoff0, L + c0);          gload16(Ah + aoff1, L + c1);
            gload16(Al + aoff0, L + 4096 + c0);   gload16(Al + aoff1, L + 4096 + c1);
            gload16(Bh + boff0, L + 8192 + c0);   gload16(Bh + boff1, L + 8192 + c1);
        }
        int cur = 0;
        for (int t = 0; t < nk; ++t) {
            if (t + 1 < nk) {
                const int k0 = (t + 1) * 32;
                u16* L = L0 + (cur ^ 1) * 12288;
                gload16(Ah + aoff0 + k0, L + c0);         gload16(Ah + aoff1 + k0, L + c1);
                gload16(Al + aoff0 + k0, L + 4096 + c0);  gload16(Al + aoff1 + k0, L + 4096 + c1);
                gload16(Bh + boff0 + k0, L + 8192 + c0);  gload16(Bh + boff1 + k0, L + 8192 + c1);
                asm volatile("s_waitcnt vmcnt(6)\n\ts_barrier" ::: "memory");
            } else {
                asm volatile("s_waitcnt vmcnt(0)\n\ts_barrier" ::: "memory");
            }
            const u16* L = L0 + cur * 12288;
            s16x8 bh[4];
            #pragma unroll
            for (int nf = 0; nf < 4; ++nf)
                bh[nf] = *(const s16x8*)(L + 8192 + b_fr + nf * 512);
            #pragma unroll
            for (int mf = 0; mf < 4; ++mf) {
                s16x8 ahv = *(const s16x8*)(L + a_fr + mf * 512);
                s16x8 alv = *(const s16x8*)(L + 4096 + a_fr + mf * 512);
                #pragma unroll
                for (int nf = 0; nf < 4; ++nf) {
                    acc[mf][nf] = __builtin_amdgcn_mfma_f32_16x16x32_bf16(ahv, bh[nf], acc[mf][nf], 0, 0, 0);
                    acc[mf][nf] = __builtin_amdgcn_mfma_f32_16x16x32_bf16(alv, bh[nf], acc[mf][nf], 0, 0, 0);
                }
            }
            asm volatile("s_barrier" ::: "memory");
            cur ^= 1;
        }
        #pragma unroll
        for (int mf = 0; mf < 4; ++mf) {
            const int row0 = bm0 + wr * 64 + mf * 16 + (lane >> 4) * 4;
            #pragma unroll
            for (int nf = 0; nf < 4; ++nf) {
                const int col = bn0 + wc * 64 + nf * 16 + (lane & 15) - tmpw;
                #pragma unroll
                for (int r = 0; r < 4; ++r)
                    Yb[(size_t)(row0 + r) * ldb + col] = acc[mf][nf][r];
            }
        }
    }
}

// ---------------------------------------------------------------------------
// f32 [M][K] -> hi/lo bf16 [Mpad][K], zero-padded rows. 4 elems/thread.
// ---------------------------------------------------------------------------
__global__ __launch_bounds__(256)
void split_kernel(const float* __restrict__ A, u16* __restrict__ Hh,
                  u16* __restrict__ Hl, int M, int kshift)
{
    const size_t g  = (size_t)blockIdx.x * 256 + threadIdx.x;
    const size_t i4 = g * 4;
    const int row   = (int)(i4 >> kshift);
    f32x4 v = {0.f, 0.f, 0.f, 0.f};
    if (row < M) v = *(const f32x4*)(A + i4);
    u16x4 h, l;
    #pragma unroll
    for (int j = 0; j < 4; ++j) {
        u16 hb = f2bf(v[j]);
        h[j] = hb;
        l[j] = f2bf(v[j] - bf2f(hb));
    }
    *(u16x4*)(Hh + i4) = h;
    *(u16x4*)(Hl + i4) = l;
}

__global__ __launch_bounds__(256)
void zero2_u16_kernel(u16* __restrict__ a, u16* __restrict__ b, int n)
{
    int i = blockIdx.x * 256 + threadIdx.x;
    if (i < n) { a[i] = 0; b[i] = 0; }
}

// ---------------------------------------------------------------------------
// CSR build
// ---------------------------------------------------------------------------
__global__ __launch_bounds__(256)
void zero2_i32_kernel(int* __restrict__ a, int na, int* __restrict__ b, int nb)
{
    int i = blockIdx.x * 256 + threadIdx.x;
    if (i < na) a[i] = 0;
    if (i < nb) b[i] = 0;
}

__global__ __launch_bounds__(256)
void hist2_kernel(const int* __restrict__ rowsR, const int* __restrict__ rowsP,
                  int* __restrict__ cntR, int* __restrict__ cntP,
                  int NR, int NP, int E)
{
    int s = blockIdx.y;
    int e = blockIdx.x * 256 + threadIdx.x;
    if (e >= E) return;
    if (blockIdx.z == 0) atomicAdd(cntR + s * NR + rowsR[(size_t)s * E + e], 1);
    else                 atomicAdd(cntP + s * NP + rowsP[(size_t)s * E + e], 1);
}

// grid (NB_R, S, 2); z=1 -> P side (extra x-blocks return)
__global__ __launch_bounds__(256)
void scan_block2_kernel(const int* __restrict__ cR, int* __restrict__ rpR,
                        int* __restrict__ bsR, int NR, int np1R, int NBR,
                        const int* __restrict__ cP, int* __restrict__ rpP,
                        int* __restrict__ bsP, int NP, int np1P, int NBP)
{
    const int side = blockIdx.z;
    const int NB = side ? NBP : NBR;
    if ((int)blockIdx.x >= NB) return;
    const int N = side ? NP : NR;
    const int np1 = side ? np1P : np1R;
    const int* counts = side ? cP : cR;
    int* rowptr = side ? rpP : rpR;
    int* blocksum = side ? bsP : bsR;

    __shared__ int sd[256];
    int s = blockIdx.y;
    int i = blockIdx.x * 256 + threadIdx.x;
    int tid = threadIdx.x;
    int v = (i < N) ? counts[s * N + i] : 0;
    sd[tid] = v;
    __syncthreads();
    #pragma unroll
    for (int off = 1; off < 256; off <<= 1) {
        int t = (tid >= off) ? sd[tid - off] : 0;
        __syncthreads();
        sd[tid] += t;
        __syncthreads();
    }
    if (i < N) rowptr[s * np1 + i] = sd[tid] - v;
    if (tid == 255) blocksum[s * NB + blockIdx.x] = sd[255];
}

// grid (8): side = bi>>2, s = bi&3
__global__ __launch_bounds__(256)
void scan_aux2_kernel(int* __restrict__ bsR, int NBR, int* __restrict__ bsP, int NBP)
{
    const int side = blockIdx.x >> 2;
    const int s = blockIdx.x & 3;
    int* blocksum = side ? bsP : bsR;
    const int NB = side ? NBP : NBR;

    __shared__ int sd[256];
    int tid = threadIdx.x;
    int v = (tid < NB) ? blocksum[s * NB + tid] : 0;
    sd[tid] = v;
    __syncthreads();
    #pragma unroll
    for (int off = 1; off < 256; off <<= 1) {
        int t = (tid >= off) ? sd[tid - off] : 0;
        __syncthreads();
        sd[tid] += t;
        __syncthreads();
    }
    if (tid < NB) blocksum[s * NB + tid] = sd[tid] - v;
}

// grid (NB_R, S, 2)
__global__ __launch_bounds__(256)
void finalize2_kernel(int* __restrict__ rpR, const int* __restrict__ bsR,
                      int* __restrict__ curR, int NR, int np1R, int NBR,
                      int* __restrict__ rpP, const int* __restrict__ bsP,
                      int* __restrict__ curP, int NP, int np1P, int NBP, int E)
{
    const int side = blockIdx.z;
    const int NB = side ? NBP : NBR;
    if ((int)blockIdx.x >= NB) return;
    const int N = side ? NP : NR;
    const int np1 = side ? np1P : np1R;
    int* rowptr = side ? rpP : rpR;
    const int* blocksum = side ? bsP : bsR;
    int* cursor = side ? curP : curR;

    int s = blockIdx.y;
    int i = blockIdx.x * 256 + threadIdx.x;
    if (i < N) {
        int v = rowptr[s * np1 + i] + blocksum[s * NB + blockIdx.x];
        rowptr[s * np1 + i] = v;
        cursor[s * N + i] = v;
    }
    if (i == N) rowptr[s * np1 + N] = E;
}

// ---------------------------------------------------------------------------
// Row-sliced XCD-affine fill: grid (ceil(E/1024)*8, S, 2), 4 edges/thread.
// slice = bx&7 owns rows [slice*Nsl, slice*Nsl+Nsl); its ev writes land in a
// contiguous ~4 MB region -> full-line writebacks from one XCD's L2.
// Every edge matches exactly one slice -> correct under any XCD mapping.
// ---------------------------------------------------------------------------
__global__ __launch_bounds__(256)
void fill_sliced_kernel(const int* __restrict__ rowsR, const int* __restrict__ colsR,
                        const float* __restrict__ valsR,
                        const int* __restrict__ rowsP, const int* __restrict__ colsP,
                        const float* __restrict__ valsP,
                        int* __restrict__ curR, int* __restrict__ curP,
                        int2* __restrict__ evR, int2* __restrict__ evP,
                        int NR, int NP, int E)
{
    const int slice = blockIdx.x & 7;
    const int chunk = blockIdx.x >> 3;
    const int s     = blockIdx.y;
    const int side  = blockIdx.z;
    const int N          = side ? NP : NR;
    const int* rows      = side ? rowsP : rowsR;
    const int* cols      = side ? colsP : colsR;
    const float* vals    = side ? valsP : valsR;
    int* cursor          = side ? curP : curR;
    int2* ev             = side ? evP : evR;

    const int Nsl = (N + 7) >> 3;
    const int r0 = slice * Nsl;
    const int r1 = min(N, r0 + Nsl);

    const int e0 = chunk * 1024 + threadIdx.x * 4;
    if (e0 >= E) return;
    const size_t base = (size_t)s * E;

    if (e0 + 4 <= E) {
        int4   r4 = *(const int4*)(rows + base + e0);
        int4   c4 = *(const int4*)(cols + base + e0);
        float4 v4 = *(const float4*)(vals + base + e0);
        int   rr[4] = {r4.x, r4.y, r4.z, r4.w};
        int   cc[4] = {c4.x, c4.y, c4.z, c4.w};
        float vv[4] = {v4.x, v4.y, v4.z, v4.w};
        #pragma unroll
        for (int j = 0; j < 4; ++j) {
            if (rr[j] >= r0 && rr[j] < r1) {
                int pos = atomicAdd(cursor + s * N + rr[j], 1);
                ev[base + pos] = make_int2(cc[j], __float_as_int(vv[j]));
            }
        }
    } else {
        for (int j = 0; j < 4 && e0 + j < E; ++j) {
            int r = rows[base + e0 + j];
            if (r >= r0 && r < r1) {
                int pos = atomicAdd(cursor + s * N + r, 1);
                ev[base + pos] = make_int2(cols[base + e0 + j],
                                           __float_as_int(vals[base + e0 + j]));
            }
        }
    }
}

// ---------------------------------------------------------------------------
// CSR SpMM over bf16 tmp, both sides in one grid. 4 waves = 4 relations.
// MODE 0: Base[r][col] += acc                          (fallback L1)
// MODE 1: OutH/OutL[r][col] = split(relu(Base+acc))    (L0 -> layer-1 A)
// MODE 2: OutF[r][col]      = relu(Base+acc)           (L1 -> d_out)
// ---------------------------------------------------------------------------
template<int KCH, int MODE>
__global__ __launch_bounds__(256)
void spmm2_kernel(const int* __restrict__ rpR, const int* __restrict__ rpP,
                  int np1R, int np1P,
                  const int2* __restrict__ evRg, const int2* __restrict__ evPg,
                  const u16* __restrict__ InR, const u16* __restrict__ InP, int ldi,
                  float* __restrict__ BaseR, float* __restrict__ BaseP, int ldb,
                  u16* __restrict__ OHR, u16* __restrict__ OLR,
                  u16* __restrict__ OHP, u16* __restrict__ OLP,
                  float* __restrict__ OFR, float* __restrict__ OFP, int ldo,
                  int NR, int E)
{
    int r = blockIdx.x;
    const int s    = threadIdx.x >> 6;
    const int lane = threadIdx.x & 63;
    const int* rp; const int2* ev; const u16* In; float* Base; int np1;
    u16* OH; u16* OL; float* OF;
    if (r < NR) { rp = rpR; ev = evRg; In = InR; Base = BaseR; np1 = np1R;
                  OH = OHR; OL = OLR; OF = OFR; }
    else { r -= NR; rp = rpP; ev = evPg; In = InP; Base = BaseP; np1 = np1P;
           OH = OHP; OL = OLP; OF = OFP; }
    int e0 = rp[s * np1 + r];
    int e1 = rp[s * np1 + r + 1];
    if (MODE == 0 && e0 == e1) return;
    ev += (size_t)s * E;

    if (KCH == 128) {
        const int col = s * 128 + lane * 2;
        float ax = 0.f, ay = 0.f;
        int e = e0;
        for (; e + 3 < e1; e += 4) {
            int2 pa = ev[e], pb = ev[e+1], pc = ev[e+2], pd = ev[e+3];
            float va = __int_as_float(pa.y), vb = __int_as_float(pb.y);
            float vc = __int_as_float(pc.y), vd = __int_as_float(pd.y);
            u16x2 xa = *(const u16x2*)(In + (size_t)pa.x * ldi + col);
            u16x2 xb = *(const u16x2*)(In + (size_t)pb.x * ldi + col);
            u16x2 xc = *(const u16x2*)(In + (size_t)pc.x * ldi + col);
            u16x2 xd = *(const u16x2*)(In + (size_t)pd.x * ldi + col);
            ax += va * bf2f(xa[0]) + vb * bf2f(xb[0]) + vc * bf2f(xc[0]) + vd * bf2f(xd[0]);
            ay += va * bf2f(xa[1]) + vb * bf2f(xb[1]) + vc * bf2f(xc[1]) + vd * bf2f(xd[1]);
        }
        for (; e < e1; ++e) {
            int2 p = ev[e];
            float v = __int_as_float(p.y);
            u16x2 x = *(const u16x2*)(In + (size_t)p.x * ldi + col);
            ax += v * bf2f(x[0]);  ay += v * bf2f(x[1]);
        }
        if (MODE == 0) {
            float2* o = (float2*)(Base + (size_t)r * ldb + col);
            float2 cv = *o; cv.x += ax; cv.y += ay; *o = cv;
        } else if (MODE == 1) {
            const float2 b = *(const float2*)(Base + (size_t)r * ldb + col);
            float fx = fmaxf(b.x + ax, 0.f), fy = fmaxf(b.y + ay, 0.f);
            u16 hx = f2bf(fx), hy = f2bf(fy);
            u16x2 h = {hx, hy};
            u16x2 l = {f2bf(fx - bf2f(hx)), f2bf(fy - bf2f(hy))};
            *(u16x2*)(OH + (size_t)r * ldo + col) = h;
            *(u16x2*)(OL + (size_t)r * ldo + col) = l;
        } else {
            const float2 b = *(const float2*)(Base + (size_t)r * ldb + col);
            float2 o; o.x = fmaxf(b.x + ax, 0.f); o.y = fmaxf(b.y + ay, 0.f);
            *(float2*)(OF + (size_t)r * ldo + col) = o;
        }
    } else {   // KCH == 64
        const int col = s * 64 + lane;
        float acc = 0.f;
        int e = e0;
        for (; e + 3 < e1; e += 4) {
            int2 pa = ev[e], pb = ev[e+1], pc = ev[e+2], pd = ev[e+3];
            acc += __int_as_float(pa.y) * bf2f(In[(size_t)pa.x * ldi + col])
                 + __int_as_float(pb.y) * bf2f(In[(size_t)pb.x * ldi + col])
                 + __int_as_float(pc.y) * bf2f(In[(size_t)pc.x * ldi + col])
                 + __int_as_float(pd.y) * bf2f(In[(size_t)pd.x * ldi + col]);
        }
        for (; e < e1; ++e) {
            int2 p = ev[e];
            acc += __int_as_float(p.y) * bf2f(In[(size_t)p.x * ldi + col]);
        }
        if (MODE == 0) {
            Base[(size_t)r * ldb + col] += acc;
        } else {
            OF[(size_t)r * ldo + col] = fmaxf(Base[(size_t)r * ldb + col] + acc, 0.f);
        }
    }
}

// fallback-only final relu (Base ld 256, rows contiguous)
__global__ __launch_bounds__(256)
void relu_out_kernel(const float* __restrict__ Z, float* __restrict__ out, int M)
{
    int g = blockIdx.x * 256 + threadIdx.x;
    if (g >= M * 256) return;
    out[g] = fmaxf(Z[g], 0.f);
}

// ---------------------------------------------------------------------------
// weight packing (transposed [N][K], hi only)
// ---------------------------------------------------------------------------
__global__ __launch_bounds__(256)
void pack_b0_kernel(const float* __restrict__ w0, const float* __restrict__ sw0,
                    u16* __restrict__ Bh)
{
    int g = blockIdx.x * 256 + threadIdx.x;
    int j = g >> 10, d = g & 1023;
    float v;
    if (j < 512) v = w0[((size_t)(j >> 7) * 1024 + d) * 128 + (j & 127)];
    else         v = sw0[(size_t)d * 512 + (j - 512)];
    Bh[g] = f2bf(v);
}

__global__ __launch_bounds__(256)
void pack_b1_kernel(const float* __restrict__ w1, const float* __restrict__ sw1,
                    u16* __restrict__ Bh)
{
    int g = blockIdx.x * 256 + threadIdx.x;
    int j = g >> 9, d = g & 511;
    float v;
    if (j < 256) v = w1[((size_t)(j >> 6) * 512 + d) * 64 + (j & 63)];
    else         v = sw1[(size_t)d * 256 + (j - 256)];
    Bh[g] = f2bf(v);
}

extern "C" void kernel_launch(void* const* d_in, const int* in_sizes, int n_in,
                              void* d_out, int out_size, void* d_ws, size_t ws_size,
                              hipStream_t stream)
{
    const int*   rna_rows  = (const int*)  d_in[0];
    const int*   rna_cols  = (const int*)  d_in[1];
    const float* rna_vals  = (const float*)d_in[2];
    const int*   prot_rows = (const int*)  d_in[3];
    const int*   prot_cols = (const int*)  d_in[4];
    const float* prot_vals = (const float*)d_in[5];
    const float* H_rna     = (const float*)d_in[6];
    const float* H_prot    = (const float*)d_in[7];
    const float* w0        = (const float*)d_in[8];
    const float* sw0       = (const float*)d_in[9];
    const float* w1        = (const float*)d_in[10];
    const float* sw1       = (const float*)d_in[11];

    const int NRNA = 50000, NPROT = 20000, S = 4, E = 500000;
    const int MP_RNA = 50048, MP_PROT = 20096;
    const int MP_ALL = MP_RNA + MP_PROT;           // 70144 = 548 * 128
    const int NP1_R = NRNA + 1, NP1_P = NPROT + 1;
    const int NB_R = (NRNA + 255) / 256;
    const int NB_P = (NPROT + 255) / 256;
    const int EB   = (E + 255) / 256;
    const int EB4  = (E + 1023) / 1024;            // 4 edges/thread chunks

    // --- ws layout ---
    char* ws = (char*)d_ws;
    size_t off = 0;
    float* Ybase = (float*)(ws + off); off += (size_t)MP_ALL * 512 * 4;   // L0 ld512 / L1 ld256
    u16*   Tmp0  = (u16*)  (ws + off); off += (size_t)MP_ALL * 512 * 2;   // L0 ld512; L1 ld256 alias
    u16*   Ahbig = (u16*)  (ws + off); off += (size_t)MP_ALL * 1024 * 2;
    u16*   Albig = (u16*)  (ws + off); off += (size_t)MP_ALL * 1024 * 2;
    u16*   B0h   = (u16*)  (ws + off); off += (size_t)1024 * 1024 * 2;
    u16*   B1h   = (u16*)  (ws + off); off += (size_t)512 * 512 * 2;
    size_t base_bytes = off;

    u16* AhR = Ahbig;                               // layer-1 A views [MP_ALL][512]
    u16* AlR = Albig;
    u16* AhP = Ahbig + (size_t)MP_RNA * 512;
    u16* AlP = Albig + (size_t)MP_RNA * 512;

    // CSR scratch size (ev packed int2)
    size_t csr_bytes = 0;
    csr_bytes += (size_t)S * E * 8 * 2;                       // evR + evP
    csr_bytes += ((size_t)S * (NRNA * 2 + NP1_R + NB_R)) * 4;
    csr_bytes += ((size_t)S * (NPROT * 2 + NP1_P + NB_P)) * 4;
    const bool csr_in_ws = (ws_size >= base_bytes + csr_bytes);

    char* csr = csr_in_ws ? (ws + base_bytes) : (char*)d_out;
    size_t coff = 0;
    int2*  evR     = (int2*) (csr + coff); coff += (size_t)S * E * 8;
    int2*  evP     = (int2*) (csr + coff); coff += (size_t)S * E * 8;
    int*   countsR = (int*)  (csr + coff); coff += (size_t)S * NRNA * 4;
    int*   rowptrR = (int*)  (csr + coff); coff += (size_t)S * NP1_R * 4;
    int*   cursorR = (int*)  (csr + coff); coff += (size_t)S * NRNA * 4;
    int*   bsumR   = (int*)  (csr + coff); coff += (size_t)S * NB_R * 4;
    int*   countsP = (int*)  (csr + coff); coff += (size_t)S * NPROT * 4;
    int*   rowptrP = (int*)  (csr + coff); coff += (size_t)S * NP1_P * 4;
    int*   cursorP = (int*)  (csr + coff); coff += (size_t)S * NPROT * 4;
    int*   bsumP   = (int*)  (csr + coff); coff += (size_t)S * NB_P * 4;

    dim3 blk(256);
    float* out = (float*)d_out;

    // --- pack weights (hi only) ---
    pack_b0_kernel<<<(1024 * 1024) / 256, blk, 0, stream>>>(w0, sw0, B0h);
    pack_b1_kernel<<<(512 * 512) / 256, blk, 0, stream>>>(w1, sw1, B1h);

    // --- CSR build (once; reused by both layers) ---
    zero2_i32_kernel<<<(S * NRNA + 255) / 256, blk, 0, stream>>>(countsR, S * NRNA,
                                                                 countsP, S * NPROT);
    hist2_kernel<<<dim3(EB, S, 2), blk, 0, stream>>>(rna_rows, prot_rows,
                                                     countsR, countsP, NRNA, NPROT, E);
    scan_block2_kernel<<<dim3(NB_R, S, 2), blk, 0, stream>>>(
        countsR, rowptrR, bsumR, NRNA, NP1_R, NB_R,
        countsP, rowptrP, bsumP, NPROT, NP1_P, NB_P);
    scan_aux2_kernel<<<8, blk, 0, stream>>>(bsumR, NB_R, bsumP, NB_P);
    finalize2_kernel<<<dim3(NB_R, S, 2), blk, 0, stream>>>(
        rowptrR, bsumR, cursorR, NRNA, NP1_R, NB_R,
        rowptrP, bsumP, cursorP, NPROT, NP1_P, NB_P, E);
    fill_sliced_kernel<<<dim3(EB4 * 8, S, 2), blk, 0, stream>>>(
        rna_rows, rna_cols, rna_vals, prot_rows, prot_cols, prot_vals,
        cursorR, cursorP, evR, evP, NRNA, NPROT, E);

    // --- layer 0: split (RNA + PROT concatenated over M) + one GEMM ---
    split_kernel<<<MP_RNA, blk, 0, stream>>>(H_rna, Ahbig, Albig, NRNA, 10);
    split_kernel<<<MP_PROT, blk, 0, stream>>>(H_prot, Ahbig + (size_t)MP_RNA * 1024,
                                              Albig + (size_t)MP_RNA * 1024, NPROT, 10);
    gemm_mixed_kernel<<<8 * (MP_ALL / 128), blk, 0, stream>>>(
        Ahbig, Albig, B0h, Tmp0, 512, Ybase, 512, 512, 1024, 7, 3);

    // --- layer 0 SpMM (merged sides): Ah/Al = split(relu(Ybase + agg)) ---
    spmm2_kernel<128, 1><<<NRNA + NPROT, blk, 0, stream>>>(
        rowptrR, rowptrP, NP1_R, NP1_P, evR, evP,
        Tmp0 + (size_t)MP_RNA * 512,      // RNA gathers prot tmp
        Tmp0,                             // PROT gathers rna tmp
        512,
        Ybase, Ybase + (size_t)MP_RNA * 512, 512,
        AhR, AlR, AhP, AlP, nullptr, nullptr, 512,
        NRNA, E);

    // --- zero layer-1 A pad rows ---
    zero2_u16_kernel<<<(48 * 512 + 255) / 256, blk, 0, stream>>>(
        AhR + (size_t)NRNA * 512, AlR + (size_t)NRNA * 512, 48 * 512);
    zero2_u16_kernel<<<(96 * 512 + 255) / 256, blk, 0, stream>>>(
        AhP + (size_t)NPROT * 512, AlP + (size_t)NPROT * 512, 96 * 512);

    // --- layer 1: one merged GEMM (N=K=512) ---
    gemm_mixed_kernel<<<4 * (MP_ALL / 128), blk, 0, stream>>>(
        Ahbig, Albig, B1h, Tmp0, 256, Ybase, 256, 256, 512, 3, 2);

    // --- layer 1 SpMM ---
    if (csr_in_ws) {
        spmm2_kernel<64, 2><<<NRNA + NPROT, blk, 0, stream>>>(
            rowptrR, rowptrP, NP1_R, NP1_P, evR, evP,
            Tmp0 + (size_t)MP_RNA * 256, Tmp0, 256,
            Ybase, Ybase + (size_t)MP_RNA * 256, 256,
            nullptr, nullptr, nullptr, nullptr,
            out, out + (size_t)NRNA * 256, 256,
            NRNA, E);
    } else {
        spmm2_kernel<64, 0><<<NRNA + NPROT, blk, 0, stream>>>(
            rowptrR, rowptrP, NP1_R, NP1_P, evR, evP,
            Tmp0 + (size_t)MP_RNA * 256, Tmp0, 256,
            Ybase, Ybase + (size_t)MP_RNA * 256, 256,
            nullptr, nullptr, nullptr, nullptr,
            nullptr, nullptr, 0,
            NRNA, E);
        relu_out_kernel<<<(NRNA * 256) / 256, blk, 0, stream>>>(Ybase, out, NRNA);
        relu_out_kernel<<<(NPROT * 256) / 256, blk, 0, stream>>>(
            Ybase + (size_t)MP_RNA * 256, out + (size_t)NRNA * 256, NPROT);
    }
}

// Round 12
// 1157.355 us; speedup vs baseline: 1.3819x; 1.0864x over previous
//
#include <hip/hip_runtime.h>
#include <hip/hip_bf16.h>

// ---------------------------------------------------------------------------
// StackGCNEncoder on MI355X — round 12:
//   ALL-1-term GEMM: A single bf16 everywhere (r10 proved tmp path tolerates
//   it; base path's Al term contributes ~0.003-0.01 abs err vs absmax 0.5).
//   -> uniform light kernel, LDS 32 KB dbuf (5 blocks/CU), split writes hi
//   only, spmm MODE1 writes Ah only, Albig freed.
//   + spmm edge bounds hoisted to SGPR (readfirstlane).
//   Everything else identical to round 11.
// ---------------------------------------------------------------------------

typedef unsigned short u16;
typedef short s16x8 __attribute__((ext_vector_type(8)));
typedef float f32x4 __attribute__((ext_vector_type(4)));
typedef __attribute__((ext_vector_type(8))) unsigned short u16x8;
typedef __attribute__((ext_vector_type(2))) unsigned short u16x2;

__device__ __forceinline__ u16 f2bf(float x) {            // RNE f32->bf16
    unsigned u = __float_as_uint(x);
    return (u16)((u + 0x7fff + ((u >> 16) & 1)) >> 16);
}
__device__ __forceinline__ float bf2f(u16 h) {
    return __uint_as_float(((unsigned)h) << 16);
}

__device__ __forceinline__ void gload16(const u16* g, u16* l) {
    __builtin_amdgcn_global_load_lds(
        (const __attribute__((address_space(1))) unsigned int*)g,
        (__attribute__((address_space(3))) unsigned int*)l,
        16, 0, 0);
}

// ---------------------------------------------------------------------------
// bf16 GEMM: [T16|Yb] = A[Mpad][K] x B^T[N][K]. 128x128 tile, BK=32.
// LDS: [A | B] sections of 128 rows x 32 u16 (8 KB each), dbuf = 32 KB.
// phys chunk = logical ^ ((row>>1)&3); linear gload_lds dest; XOR on ds_read.
// Counted-vmcnt barriers (4 loads in flight). Epilogue: bn0<tmpw -> bf16 tmp,
// else f32 base (block-uniform, tmpw%128==0).
// ---------------------------------------------------------------------------
__global__ __launch_bounds__(256)
void gemm_bf16_kernel(const u16* __restrict__ Ah, const u16* __restrict__ Bh,
                      u16* __restrict__ T16, int ldt,
                      float* __restrict__ Yb, int ldb, int tmpw,
                      int K, int nxmask, int nxshift)
{
    __shared__ u16 lds[2][2][4096];   // 32 KB

    const int nwg = gridDim.x;
    const int q   = nwg >> 3, r8 = nwg & 7;
    const int xcd = blockIdx.x & 7, pos = blockIdx.x >> 3;
    const int lin = (xcd < r8 ? xcd * (q + 1) : r8 * (q + 1) + (xcd - r8) * q) + pos;
    const int bm0 = (lin >> nxshift) * 128;
    const int bn0 = (lin & nxmask) * 128;

    const int tid  = threadIdx.x;
    const int lane = tid & 63;
    const int wid  = tid >> 6;
    const int wr   = wid >> 1;
    const int wc   = wid & 1;

    const int srow = tid >> 2;
    const int scol = ((tid & 3) ^ ((tid >> 3) & 3)) * 8;   // u16 units
    const size_t aoff0 = (size_t)(bm0 + srow) * K + scol;
    const size_t aoff1 = (size_t)(bm0 + srow + 64) * K + scol;
    const size_t boff0 = (size_t)(bn0 + srow) * K + scol;
    const size_t boff1 = (size_t)(bn0 + srow + 64) * K + scol;
    const int c0 = tid * 8;
    const int c1 = 2048 + tid * 8;

    u16* L0 = &lds[0][0][0];              // buffer stride 8192 u16

    f32x4 zero = {0.f, 0.f, 0.f, 0.f};
    f32x4 acc[4][4];
    #pragma unroll
    for (int i = 0; i < 4; ++i)
        #pragma unroll
        for (int j = 0; j < 4; ++j) acc[i][j] = zero;

    const int fchunk = (((lane >> 4) ^ ((lane >> 1) & 3))) * 8;
    const int a_fr = (wr * 64 + (lane & 15)) * 32 + fchunk;
    const int b_fr = (wc * 64 + (lane & 15)) * 32 + fchunk;

    const int nk = K >> 5;

    {
        u16* L = L0;
        gload16(Ah + aoff0, L + c0);          gload16(Ah + aoff1, L + c1);
        gload16(Bh + boff0, L + 4096 + c0);   gload16(Bh + boff1, L + 4096 + c1);
    }
    int cur = 0;
    for (int t = 0; t < nk; ++t) {
        if (t + 1 < nk) {
            const int k0 = (t + 1) * 32;
            u16* L = L0 + (cur ^ 1) * 8192;
            gload16(Ah + aoff0 + k0, L + c0);         gload16(Ah + aoff1 + k0, L + c1);
            gload16(Bh + boff0 + k0, L + 4096 + c0);  gload16(Bh + boff1 + k0, L + 4096 + c1);
            asm volatile("s_waitcnt vmcnt(4)\n\ts_barrier" ::: "memory");
        } else {
            asm volatile("s_waitcnt vmcnt(0)\n\ts_barrier" ::: "memory");
        }
        const u16* L = L0 + cur * 8192;
        s16x8 bh[4];
        #pragma unroll
        for (int nf = 0; nf < 4; ++nf)
            bh[nf] = *(const s16x8*)(L + 4096 + b_fr + nf * 512);
        #pragma unroll
        for (int mf = 0; mf < 4; ++mf) {
            s16x8 ahv = *(const s16x8*)(L + a_fr + mf * 512);
            #pragma unroll
            for (int nf = 0; nf < 4; ++nf)
                acc[mf][nf] = __builtin_amdgcn_mfma_f32_16x16x32_bf16(ahv, bh[nf], acc[mf][nf], 0, 0, 0);
        }
        asm volatile("s_barrier" ::: "memory");
        cur ^= 1;
    }

    if (bn0 < tmpw) {
        #pragma unroll
        for (int mf = 0; mf < 4; ++mf) {
            const int row0 = bm0 + wr * 64 + mf * 16 + (lane >> 4) * 4;
            #pragma unroll
            for (int nf = 0; nf < 4; ++nf) {
                const int col = bn0 + wc * 64 + nf * 16 + (lane & 15);
                #pragma unroll
                for (int r = 0; r < 4; ++r)
                    T16[(size_t)(row0 + r) * ldt + col] = f2bf(acc[mf][nf][r]);
            }
        }
    } else {
        #pragma unroll
        for (int mf = 0; mf < 4; ++mf) {
            const int row0 = bm0 + wr * 64 + mf * 16 + (lane >> 4) * 4;
            #pragma unroll
            for (int nf = 0; nf < 4; ++nf) {
                const int col = bn0 + wc * 64 + nf * 16 + (lane & 15) - tmpw;
                #pragma unroll
                for (int r = 0; r < 4; ++r)
                    Yb[(size_t)(row0 + r) * ldb + col] = acc[mf][nf][r];
            }
        }
    }
}

// ---------------------------------------------------------------------------
// f32 [M][K] -> bf16 [Mpad][K] (hi only), zero-padded rows. 8 elems/thread.
// ---------------------------------------------------------------------------
__global__ __launch_bounds__(256)
void cvt_bf16_kernel(const float* __restrict__ A, u16* __restrict__ Hh,
                     int M, int kshift)
{
    const size_t g  = (size_t)blockIdx.x * 256 + threadIdx.x;
    const size_t i8 = g * 8;
    const int row   = (int)(i8 >> kshift);
    f32x4 a = {0.f, 0.f, 0.f, 0.f}, b = {0.f, 0.f, 0.f, 0.f};
    if (row < M) {
        a = *(const f32x4*)(A + i8);
        b = *(const f32x4*)(A + i8 + 4);
    }
    u16x8 h;
    #pragma unroll
    for (int j = 0; j < 4; ++j) { h[j] = f2bf(a[j]); h[4 + j] = f2bf(b[j]); }
    *(u16x8*)(Hh + i8) = h;
}

__global__ __launch_bounds__(256)
void zero_u16_kernel(u16* __restrict__ a, int n)
{
    int i = blockIdx.x * 256 + threadIdx.x;
    if (i < n) a[i] = 0;
}

// ---------------------------------------------------------------------------
// CSR build
// ---------------------------------------------------------------------------
__global__ __launch_bounds__(256)
void zero2_i32_kernel(int* __restrict__ a, int na, int* __restrict__ b, int nb)
{
    int i = blockIdx.x * 256 + threadIdx.x;
    if (i < na) a[i] = 0;
    if (i < nb) b[i] = 0;
}

__global__ __launch_bounds__(256)
void hist2_kernel(const int* __restrict__ rowsR, const int* __restrict__ rowsP,
                  int* __restrict__ cntR, int* __restrict__ cntP,
                  int NR, int NP, int E)
{
    int s = blockIdx.y;
    int e = blockIdx.x * 256 + threadIdx.x;
    if (e >= E) return;
    if (blockIdx.z == 0) atomicAdd(cntR + s * NR + rowsR[(size_t)s * E + e], 1);
    else                 atomicAdd(cntP + s * NP + rowsP[(size_t)s * E + e], 1);
}

__global__ __launch_bounds__(256)
void scan_block2_kernel(const int* __restrict__ cR, int* __restrict__ rpR,
                        int* __restrict__ bsR, int NR, int np1R, int NBR,
                        const int* __restrict__ cP, int* __restrict__ rpP,
                        int* __restrict__ bsP, int NP, int np1P, int NBP)
{
    const int side = blockIdx.z;
    const int NB = side ? NBP : NBR;
    if ((int)blockIdx.x >= NB) return;
    const int N = side ? NP : NR;
    const int np1 = side ? np1P : np1R;
    const int* counts = side ? cP : cR;
    int* rowptr = side ? rpP : rpR;
    int* blocksum = side ? bsP : bsR;

    __shared__ int sd[256];
    int s = blockIdx.y;
    int i = blockIdx.x * 256 + threadIdx.x;
    int tid = threadIdx.x;
    int v = (i < N) ? counts[s * N + i] : 0;
    sd[tid] = v;
    __syncthreads();
    #pragma unroll
    for (int off = 1; off < 256; off <<= 1) {
        int t = (tid >= off) ? sd[tid - off] : 0;
        __syncthreads();
        sd[tid] += t;
        __syncthreads();
    }
    if (i < N) rowptr[s * np1 + i] = sd[tid] - v;
    if (tid == 255) blocksum[s * NB + blockIdx.x] = sd[255];
}

__global__ __launch_bounds__(256)
void scan_aux2_kernel(int* __restrict__ bsR, int NBR, int* __restrict__ bsP, int NBP)
{
    const int side = blockIdx.x >> 2;
    const int s = blockIdx.x & 3;
    int* blocksum = side ? bsP : bsR;
    const int NB = side ? NBP : NBR;

    __shared__ int sd[256];
    int tid = threadIdx.x;
    int v = (tid < NB) ? blocksum[s * NB + tid] : 0;
    sd[tid] = v;
    __syncthreads();
    #pragma unroll
    for (int off = 1; off < 256; off <<= 1) {
        int t = (tid >= off) ? sd[tid - off] : 0;
        __syncthreads();
        sd[tid] += t;
        __syncthreads();
    }
    if (tid < NB) blocksum[s * NB + tid] = sd[tid] - v;
}

__global__ __launch_bounds__(256)
void finalize2_kernel(int* __restrict__ rpR, const int* __restrict__ bsR,
                      int* __restrict__ curR, int NR, int np1R, int NBR,
                      int* __restrict__ rpP, const int* __restrict__ bsP,
                      int* __restrict__ curP, int NP, int np1P, int NBP, int E)
{
    const int side = blockIdx.z;
    const int NB = side ? NBP : NBR;
    if ((int)blockIdx.x >= NB) return;
    const int N = side ? NP : NR;
    const int np1 = side ? np1P : np1R;
    int* rowptr = side ? rpP : rpR;
    const int* blocksum = side ? bsP : bsR;
    int* cursor = side ? curP : curR;

    int s = blockIdx.y;
    int i = blockIdx.x * 256 + threadIdx.x;
    if (i < N) {
        int v = rowptr[s * np1 + i] + blocksum[s * NB + blockIdx.x];
        rowptr[s * np1 + i] = v;
        cursor[s * N + i] = v;
    }
    if (i == N) rowptr[s * np1 + N] = E;
}

// Row-sliced XCD-affine fill (round 11, unchanged)
__global__ __launch_bounds__(256)
void fill_sliced_kernel(const int* __restrict__ rowsR, const int* __restrict__ colsR,
                        const float* __restrict__ valsR,
                        const int* __restrict__ rowsP, const int* __restrict__ colsP,
                        const float* __restrict__ valsP,
                        int* __restrict__ curR, int* __restrict__ curP,
                        int2* __restrict__ evR, int2* __restrict__ evP,
                        int NR, int NP, int E)
{
    const int slice = blockIdx.x & 7;
    const int chunk = blockIdx.x >> 3;
    const int s     = blockIdx.y;
    const int side  = blockIdx.z;
    const int N          = side ? NP : NR;
    const int* rows      = side ? rowsP : rowsR;
    const int* cols      = side ? colsP : colsR;
    const float* vals    = side ? valsP : valsR;
    int* cursor          = side ? curP : curR;
    int2* ev             = side ? evP : evR;

    const int Nsl = (N + 7) >> 3;
    const int r0 = slice * Nsl;
    const int r1 = min(N, r0 + Nsl);

    const int e0 = chunk * 1024 + threadIdx.x * 4;
    if (e0 >= E) return;
    const size_t base = (size_t)s * E;

    if (e0 + 4 <= E) {
        int4   r4 = *(const int4*)(rows + base + e0);
        int4   c4 = *(const int4*)(cols + base + e0);
        float4 v4 = *(const float4*)(vals + base + e0);
        int   rr[4] = {r4.x, r4.y, r4.z, r4.w};
        int   cc[4] = {c4.x, c4.y, c4.z, c4.w};
        float vv[4] = {v4.x, v4.y, v4.z, v4.w};
        #pragma unroll
        for (int j = 0; j < 4; ++j) {
            if (rr[j] >= r0 && rr[j] < r1) {
                int pos = atomicAdd(cursor + s * N + rr[j], 1);
                ev[base + pos] = make_int2(cc[j], __float_as_int(vv[j]));
            }
        }
    } else {
        for (int j = 0; j < 4 && e0 + j < E; ++j) {
            int r = rows[base + e0 + j];
            if (r >= r0 && r < r1) {
                int pos = atomicAdd(cursor + s * N + r, 1);
                ev[base + pos] = make_int2(cols[base + e0 + j],
                                           __float_as_int(vals[base + e0 + j]));
            }
        }
    }
}

// ---------------------------------------------------------------------------
// CSR SpMM over bf16 tmp, both sides in one grid. 4 waves = 4 relations.
// MODE 0: Base[r][col] += acc                  (fallback L1)
// MODE 1: OH[r][col] = bf16(relu(Base+acc))    (L0 -> layer-1 A, hi only)
// MODE 2: OF[r][col] = relu(Base+acc)          (L1 -> d_out)
// ---------------------------------------------------------------------------
template<int KCH, int MODE>
__global__ __launch_bounds__(256)
void spmm2_kernel(const int* __restrict__ rpR, const int* __restrict__ rpP,
                  int np1R, int np1P,
                  const int2* __restrict__ evRg, const int2* __restrict__ evPg,
                  const u16* __restrict__ InR, const u16* __restrict__ InP, int ldi,
                  float* __restrict__ BaseR, float* __restrict__ BaseP, int ldb,
                  u16* __restrict__ OHR, u16* __restrict__ OHP,
                  float* __restrict__ OFR, float* __restrict__ OFP, int ldo,
                  int NR, int E)
{
    int r = blockIdx.x;
    const int s    = threadIdx.x >> 6;
    const int lane = threadIdx.x & 63;
    const int* rp; const int2* ev; const u16* In; float* Base; int np1;
    u16* OH; float* OF;
    if (r < NR) { rp = rpR; ev = evRg; In = InR; Base = BaseR; np1 = np1R;
                  OH = OHR; OF = OFR; }
    else { r -= NR; rp = rpP; ev = evPg; In = InP; Base = BaseP; np1 = np1P;
           OH = OHP; OF = OFP; }
    // wave-uniform bounds -> SGPR
    int e0 = __builtin_amdgcn_readfirstlane(rp[s * np1 + r]);
    int e1 = __builtin_amdgcn_readfirstlane(rp[s * np1 + r + 1]);
    if (MODE == 0 && e0 == e1) return;
    ev += (size_t)s * E;

    if (KCH == 128) {
        const int col = s * 128 + lane * 2;
        float ax = 0.f, ay = 0.f;
        int e = e0;
        for (; e + 3 < e1; e += 4) {
            int2 pa = ev[e], pb = ev[e+1], pc = ev[e+2], pd = ev[e+3];
            float va = __int_as_float(pa.y), vb = __int_as_float(pb.y);
            float vc = __int_as_float(pc.y), vd = __int_as_float(pd.y);
            u16x2 xa = *(const u16x2*)(In + (size_t)pa.x * ldi + col);
            u16x2 xb = *(const u16x2*)(In + (size_t)pb.x * ldi + col);
            u16x2 xc = *(const u16x2*)(In + (size_t)pc.x * ldi + col);
            u16x2 xd = *(const u16x2*)(In + (size_t)pd.x * ldi + col);
            ax += va * bf2f(xa[0]) + vb * bf2f(xb[0]) + vc * bf2f(xc[0]) + vd * bf2f(xd[0]);
            ay += va * bf2f(xa[1]) + vb * bf2f(xb[1]) + vc * bf2f(xc[1]) + vd * bf2f(xd[1]);
        }
        for (; e < e1; ++e) {
            int2 p = ev[e];
            float v = __int_as_float(p.y);
            u16x2 x = *(const u16x2*)(In + (size_t)p.x * ldi + col);
            ax += v * bf2f(x[0]);  ay += v * bf2f(x[1]);
        }
        if (MODE == 0) {
            float2* o = (float2*)(Base + (size_t)r * ldb + col);
            float2 cv = *o; cv.x += ax; cv.y += ay; *o = cv;
        } else if (MODE == 1) {
            const float2 b = *(const float2*)(Base + (size_t)r * ldb + col);
            float fx = fmaxf(b.x + ax, 0.f), fy = fmaxf(b.y + ay, 0.f);
            u16x2 h = {f2bf(fx), f2bf(fy)};
            *(u16x2*)(OH + (size_t)r * ldo + col) = h;
        } else {
            const float2 b = *(const float2*)(Base + (size_t)r * ldb + col);
            float2 o; o.x = fmaxf(b.x + ax, 0.f); o.y = fmaxf(b.y + ay, 0.f);
            *(float2*)(OF + (size_t)r * ldo + col) = o;
        }
    } else {   // KCH == 64
        const int col = s * 64 + lane;
        float acc = 0.f;
        int e = e0;
        for (; e + 3 < e1; e += 4) {
            int2 pa = ev[e], pb = ev[e+1], pc = ev[e+2], pd = ev[e+3];
            acc += __int_as_float(pa.y) * bf2f(In[(size_t)pa.x * ldi + col])
                 + __int_as_float(pb.y) * bf2f(In[(size_t)pb.x * ldi + col])
                 + __int_as_float(pc.y) * bf2f(In[(size_t)pc.x * ldi + col])
                 + __int_as_float(pd.y) * bf2f(In[(size_t)pd.x * ldi + col]);
        }
        for (; e < e1; ++e) {
            int2 p = ev[e];
            acc += __int_as_float(p.y) * bf2f(In[(size_t)p.x * ldi + col]);
        }
        if (MODE == 0) {
            Base[(size_t)r * ldb + col] += acc;
        } else {
            OF[(size_t)r * ldo + col] = fmaxf(Base[(size_t)r * ldb + col] + acc, 0.f);
        }
    }
}

// fallback-only final relu
__global__ __launch_bounds__(256)
void relu_out_kernel(const float* __restrict__ Z, float* __restrict__ out, int M)
{
    int g = blockIdx.x * 256 + threadIdx.x;
    if (g >= M * 256) return;
    out[g] = fmaxf(Z[g], 0.f);
}

// ---------------------------------------------------------------------------
// weight packing (transposed [N][K], bf16)
// ---------------------------------------------------------------------------
__global__ __launch_bounds__(256)
void pack_b0_kernel(const float* __restrict__ w0, const float* __restrict__ sw0,
                    u16* __restrict__ Bh)
{
    int g = blockIdx.x * 256 + threadIdx.x;
    int j = g >> 10, d = g & 1023;
    float v;
    if (j < 512) v = w0[((size_t)(j >> 7) * 1024 + d) * 128 + (j & 127)];
    else         v = sw0[(size_t)d * 512 + (j - 512)];
    Bh[g] = f2bf(v);
}

__global__ __launch_bounds__(256)
void pack_b1_kernel(const float* __restrict__ w1, const float* __restrict__ sw1,
                    u16* __restrict__ Bh)
{
    int g = blockIdx.x * 256 + threadIdx.x;
    int j = g >> 9, d = g & 511;
    float v;
    if (j < 256) v = w1[((size_t)(j >> 6) * 512 + d) * 64 + (j & 63)];
    else         v = sw1[(size_t)d * 256 + (j - 256)];
    Bh[g] = f2bf(v);
}

extern "C" void kernel_launch(void* const* d_in, const int* in_sizes, int n_in,
                              void* d_out, int out_size, void* d_ws, size_t ws_size,
                              hipStream_t stream)
{
    const int*   rna_rows  = (const int*)  d_in[0];
    const int*   rna_cols  = (const int*)  d_in[1];
    const float* rna_vals  = (const float*)d_in[2];
    const int*   prot_rows = (const int*)  d_in[3];
    const int*   prot_cols = (const int*)  d_in[4];
    const float* prot_vals = (const float*)d_in[5];
    const float* H_rna     = (const float*)d_in[6];
    const float* H_prot    = (const float*)d_in[7];
    const float* w0        = (const float*)d_in[8];
    const float* sw0       = (const float*)d_in[9];
    const float* w1        = (const float*)d_in[10];
    const float* sw1       = (const float*)d_in[11];

    const int NRNA = 50000, NPROT = 20000, S = 4, E = 500000;
    const int MP_RNA = 50048, MP_PROT = 20096;
    const int MP_ALL = MP_RNA + MP_PROT;           // 70144 = 548 * 128
    const int NP1_R = NRNA + 1, NP1_P = NPROT + 1;
    const int NB_R = (NRNA + 255) / 256;
    const int NB_P = (NPROT + 255) / 256;
    const int EB   = (E + 255) / 256;
    const int EB4  = (E + 1023) / 1024;

    // --- ws layout ---
    char* ws = (char*)d_ws;
    size_t off = 0;
    float* Ybase = (float*)(ws + off); off += (size_t)MP_ALL * 512 * 4;   // L0 ld512 / L1 ld256
    u16*   Tmp0  = (u16*)  (ws + off); off += (size_t)MP_ALL * 512 * 2;   // L0 ld512; L1 ld256 alias
    u16*   Ahbig = (u16*)  (ws + off); off += (size_t)MP_ALL * 1024 * 2;
    u16*   B0h   = (u16*)  (ws + off); off += (size_t)1024 * 1024 * 2;
    u16*   B1h   = (u16*)  (ws + off); off += (size_t)512 * 512 * 2;
    size_t base_bytes = off;

    u16* AhR = Ahbig;                               // layer-1 A views [MP_ALL][512]
    u16* AhP = Ahbig + (size_t)MP_RNA * 512;

    // CSR scratch size (ev packed int2)
    size_t csr_bytes = 0;
    csr_bytes += (size_t)S * E * 8 * 2;                       // evR + evP
    csr_bytes += ((size_t)S * (NRNA * 2 + NP1_R + NB_R)) * 4;
    csr_bytes += ((size_t)S * (NPROT * 2 + NP1_P + NB_P)) * 4;
    const bool csr_in_ws = (ws_size >= base_bytes + csr_bytes);

    char* csr = csr_in_ws ? (ws + base_bytes) : (char*)d_out;
    size_t coff = 0;
    int2*  evR     = (int2*) (csr + coff); coff += (size_t)S * E * 8;
    int2*  evP     = (int2*) (csr + coff); coff += (size_t)S * E * 8;
    int*   countsR = (int*)  (csr + coff); coff += (size_t)S * NRNA * 4;
    int*   rowptrR = (int*)  (csr + coff); coff += (size_t)S * NP1_R * 4;
    int*   cursorR = (int*)  (csr + coff); coff += (size_t)S * NRNA * 4;
    int*   bsumR   = (int*)  (csr + coff); coff += (size_t)S * NB_R * 4;
    int*   countsP = (int*)  (csr + coff); coff += (size_t)S * NPROT * 4;
    int*   rowptrP = (int*)  (csr + coff); coff += (size_t)S * NP1_P * 4;
    int*   cursorP = (int*)  (csr + coff); coff += (size_t)S * NPROT * 4;
    int*   bsumP   = (int*)  (csr + coff); coff += (size_t)S * NB_P * 4;

    dim3 blk(256);
    float* out = (float*)d_out;

    // --- pack weights ---
    pack_b0_kernel<<<(1024 * 1024) / 256, blk, 0, stream>>>(w0, sw0, B0h);
    pack_b1_kernel<<<(512 * 512) / 256, blk, 0, stream>>>(w1, sw1, B1h);

    // --- CSR build (once; reused by both layers) ---
    zero2_i32_kernel<<<(S * NRNA + 255) / 256, blk, 0, stream>>>(countsR, S * NRNA,
                                                                 countsP, S * NPROT);
    hist2_kernel<<<dim3(EB, S, 2), blk, 0, stream>>>(rna_rows, prot_rows,
                                                     countsR, countsP, NRNA, NPROT, E);
    scan_block2_kernel<<<dim3(NB_R, S, 2), blk, 0, stream>>>(
        countsR, rowptrR, bsumR, NRNA, NP1_R, NB_R,
        countsP, rowptrP, bsumP, NPROT, NP1_P, NB_P);
    scan_aux2_kernel<<<8, blk, 0, stream>>>(bsumR, NB_R, bsumP, NB_P);
    finalize2_kernel<<<dim3(NB_R, S, 2), blk, 0, stream>>>(
        rowptrR, bsumR, cursorR, NRNA, NP1_R, NB_R,
        rowptrP, bsumP, cursorP, NPROT, NP1_P, NB_P, E);
    fill_sliced_kernel<<<dim3(EB4 * 8, S, 2), blk, 0, stream>>>(
        rna_rows, rna_cols, rna_vals, prot_rows, prot_cols, prot_vals,
        cursorR, cursorP, evR, evP, NRNA, NPROT, E);

    // --- layer 0: cvt (RNA + PROT concatenated over M) + one GEMM ---
    cvt_bf16_kernel<<<MP_RNA / 2, blk, 0, stream>>>(H_rna, Ahbig, NRNA, 10);
    cvt_bf16_kernel<<<MP_PROT / 2, blk, 0, stream>>>(H_prot, Ahbig + (size_t)MP_RNA * 1024,
                                                     NPROT, 10);
    gemm_bf16_kernel<<<8 * (MP_ALL / 128), blk, 0, stream>>>(
        Ahbig, B0h, Tmp0, 512, Ybase, 512, 512, 1024, 7, 3);

    // --- layer 0 SpMM (merged sides): Ah = bf16(relu(Ybase + agg)) ---
    spmm2_kernel<128, 1><<<NRNA + NPROT, blk, 0, stream>>>(
        rowptrR, rowptrP, NP1_R, NP1_P, evR, evP,
        Tmp0 + (size_t)MP_RNA * 512,      // RNA gathers prot tmp
        Tmp0,                             // PROT gathers rna tmp
        512,
        Ybase, Ybase + (size_t)MP_RNA * 512, 512,
        AhR, AhP, nullptr, nullptr, 512,
        NRNA, E);

    // --- zero layer-1 A pad rows ---
    zero_u16_kernel<<<(48 * 512 + 255) / 256, blk, 0, stream>>>(
        AhR + (size_t)NRNA * 512, 48 * 512);
    zero_u16_kernel<<<(96 * 512 + 255) / 256, blk, 0, stream>>>(
        AhP + (size_t)NPROT * 512, 96 * 512);

    // --- layer 1: one merged GEMM (N=K=512) ---
    gemm_bf16_kernel<<<4 * (MP_ALL / 128), blk, 0, stream>>>(
        Ahbig, B1h, Tmp0, 256, Ybase, 256, 256, 512, 3, 2);

    // --- layer 1 SpMM ---
    if (csr_in_ws) {
        spmm2_kernel<64, 2><<<NRNA + NPROT, blk, 0, stream>>>(
            rowptrR, rowptrP, NP1_R, NP1_P, evR, evP,
            Tmp0 + (size_t)MP_RNA * 256, Tmp0, 256,
            Ybase, Ybase + (size_t)MP_RNA * 256, 256,
            nullptr, nullptr,
            out, out + (size_t)NRNA * 256, 256,
            NRNA, E);
    } else {
        spmm2_kernel<64, 0><<<NRNA + NPROT, blk, 0, stream>>>(
            rowptrR, rowptrP, NP1_R, NP1_P, evR, evP,
            Tmp0 + (size_t)MP_RNA * 256, Tmp0, 256,
            Ybase, Ybase + (size_t)MP_RNA * 256, 256,
            nullptr, nullptr,
            nullptr, nullptr, 0,
            NRNA, E);
        relu_out_kernel<<<(NRNA * 256) / 256, blk, 0, stream>>>(Ybase, out, NRNA);
        relu_out_kernel<<<(NPROT * 256) / 256, blk, 0, stream>>>(
            Ybase + (size_t)MP_RNA * 256, out + (size_t)NRNA * 256, NPROT);
    }
}

// Round 13
// 1103.345 us; speedup vs baseline: 1.4496x; 1.0490x over previous
//
#include <hip/hip_runtime.h>
#include <hip/hip_bf16.h>

// ---------------------------------------------------------------------------
// StackGCNEncoder on MI355X — round 13:
//   + Y unified all-bf16 (base half stored bf16: +0.005 err vs 0.5 budget)
//     -> GEMM single uniform epilogue; spmm base reads halve
//   + fill: cols/vals loaded only on slice row-match (reads 768 -> ~330 MB)
//   GEMM structure = r12 (128x128, 1-term, 32KB dbuf, counted vmcnt, XOR szl).
// ---------------------------------------------------------------------------

typedef unsigned short u16;
typedef short s16x8 __attribute__((ext_vector_type(8)));
typedef float f32x4 __attribute__((ext_vector_type(4)));
typedef __attribute__((ext_vector_type(8))) unsigned short u16x8;
typedef __attribute__((ext_vector_type(2))) unsigned short u16x2;

__device__ __forceinline__ u16 f2bf(float x) {            // RNE f32->bf16
    unsigned u = __float_as_uint(x);
    return (u16)((u + 0x7fff + ((u >> 16) & 1)) >> 16);
}
__device__ __forceinline__ float bf2f(u16 h) {
    return __uint_as_float(((unsigned)h) << 16);
}

__device__ __forceinline__ void gload16(const u16* g, u16* l) {
    __builtin_amdgcn_global_load_lds(
        (const __attribute__((address_space(1))) unsigned int*)g,
        (__attribute__((address_space(3))) unsigned int*)l,
        16, 0, 0);
}

// ---------------------------------------------------------------------------
// bf16 GEMM: Y16 = A[Mpad][K] x B^T[N][K], all-bf16 out. 128x128 tile, BK=32.
// LDS: [A | B] 8 KB sections, dbuf 32 KB. XOR chunk swizzle, counted vmcnt.
// ---------------------------------------------------------------------------
__global__ __launch_bounds__(256)
void gemm_bf16_kernel(const u16* __restrict__ Ah, const u16* __restrict__ Bh,
                      u16* __restrict__ Y, int ldy,
                      int K, int nxmask, int nxshift)
{
    __shared__ u16 lds[2][2][4096];   // 32 KB

    const int nwg = gridDim.x;
    const int q   = nwg >> 3, r8 = nwg & 7;
    const int xcd = blockIdx.x & 7, pos = blockIdx.x >> 3;
    const int lin = (xcd < r8 ? xcd * (q + 1) : r8 * (q + 1) + (xcd - r8) * q) + pos;
    const int bm0 = (lin >> nxshift) * 128;
    const int bn0 = (lin & nxmask) * 128;

    const int tid  = threadIdx.x;
    const int lane = tid & 63;
    const int wid  = tid >> 6;
    const int wr   = wid >> 1;
    const int wc   = wid & 1;

    const int srow = tid >> 2;
    const int scol = ((tid & 3) ^ ((tid >> 3) & 3)) * 8;   // u16 units
    const size_t aoff0 = (size_t)(bm0 + srow) * K + scol;
    const size_t aoff1 = (size_t)(bm0 + srow + 64) * K + scol;
    const size_t boff0 = (size_t)(bn0 + srow) * K + scol;
    const size_t boff1 = (size_t)(bn0 + srow + 64) * K + scol;
    const int c0 = tid * 8;
    const int c1 = 2048 + tid * 8;

    u16* L0 = &lds[0][0][0];              // buffer stride 8192 u16

    f32x4 zero = {0.f, 0.f, 0.f, 0.f};
    f32x4 acc[4][4];
    #pragma unroll
    for (int i = 0; i < 4; ++i)
        #pragma unroll
        for (int j = 0; j < 4; ++j) acc[i][j] = zero;

    const int fchunk = (((lane >> 4) ^ ((lane >> 1) & 3))) * 8;
    const int a_fr = (wr * 64 + (lane & 15)) * 32 + fchunk;
    const int b_fr = (wc * 64 + (lane & 15)) * 32 + fchunk;

    const int nk = K >> 5;

    {
        u16* L = L0;
        gload16(Ah + aoff0, L + c0);          gload16(Ah + aoff1, L + c1);
        gload16(Bh + boff0, L + 4096 + c0);   gload16(Bh + boff1, L + 4096 + c1);
    }
    int cur = 0;
    for (int t = 0; t < nk; ++t) {
        if (t + 1 < nk) {
            const int k0 = (t + 1) * 32;
            u16* L = L0 + (cur ^ 1) * 8192;
            gload16(Ah + aoff0 + k0, L + c0);         gload16(Ah + aoff1 + k0, L + c1);
            gload16(Bh + boff0 + k0, L + 4096 + c0);  gload16(Bh + boff1 + k0, L + 4096 + c1);
            asm volatile("s_waitcnt vmcnt(4)\n\ts_barrier" ::: "memory");
        } else {
            asm volatile("s_waitcnt vmcnt(0)\n\ts_barrier" ::: "memory");
        }
        const u16* L = L0 + cur * 8192;
        s16x8 bh[4];
        #pragma unroll
        for (int nf = 0; nf < 4; ++nf)
            bh[nf] = *(const s16x8*)(L + 4096 + b_fr + nf * 512);
        #pragma unroll
        for (int mf = 0; mf < 4; ++mf) {
            s16x8 ahv = *(const s16x8*)(L + a_fr + mf * 512);
            #pragma unroll
            for (int nf = 0; nf < 4; ++nf)
                acc[mf][nf] = __builtin_amdgcn_mfma_f32_16x16x32_bf16(ahv, bh[nf], acc[mf][nf], 0, 0, 0);
        }
        asm volatile("s_barrier" ::: "memory");
        cur ^= 1;
    }

    #pragma unroll
    for (int mf = 0; mf < 4; ++mf) {
        const int row0 = bm0 + wr * 64 + mf * 16 + (lane >> 4) * 4;
        #pragma unroll
        for (int nf = 0; nf < 4; ++nf) {
            const int col = bn0 + wc * 64 + nf * 16 + (lane & 15);
            #pragma unroll
            for (int r = 0; r < 4; ++r)
                Y[(size_t)(row0 + r) * ldy + col] = f2bf(acc[mf][nf][r]);
        }
    }
}

// ---------------------------------------------------------------------------
// f32 [M][K] -> bf16 [Mpad][K], zero-padded rows. 8 elems/thread.
// ---------------------------------------------------------------------------
__global__ __launch_bounds__(256)
void cvt_bf16_kernel(const float* __restrict__ A, u16* __restrict__ Hh,
                     int M, int kshift)
{
    const size_t g  = (size_t)blockIdx.x * 256 + threadIdx.x;
    const size_t i8 = g * 8;
    const int row   = (int)(i8 >> kshift);
    f32x4 a = {0.f, 0.f, 0.f, 0.f}, b = {0.f, 0.f, 0.f, 0.f};
    if (row < M) {
        a = *(const f32x4*)(A + i8);
        b = *(const f32x4*)(A + i8 + 4);
    }
    u16x8 h;
    #pragma unroll
    for (int j = 0; j < 4; ++j) { h[j] = f2bf(a[j]); h[4 + j] = f2bf(b[j]); }
    *(u16x8*)(Hh + i8) = h;
}

__global__ __launch_bounds__(256)
void zero_u16_kernel(u16* __restrict__ a, int n)
{
    int i = blockIdx.x * 256 + threadIdx.x;
    if (i < n) a[i] = 0;
}

// ---------------------------------------------------------------------------
// CSR build
// ---------------------------------------------------------------------------
__global__ __launch_bounds__(256)
void zero2_i32_kernel(int* __restrict__ a, int na, int* __restrict__ b, int nb)
{
    int i = blockIdx.x * 256 + threadIdx.x;
    if (i < na) a[i] = 0;
    if (i < nb) b[i] = 0;
}

__global__ __launch_bounds__(256)
void hist2_kernel(const int* __restrict__ rowsR, const int* __restrict__ rowsP,
                  int* __restrict__ cntR, int* __restrict__ cntP,
                  int NR, int NP, int E)
{
    int s = blockIdx.y;
    int e = blockIdx.x * 256 + threadIdx.x;
    if (e >= E) return;
    if (blockIdx.z == 0) atomicAdd(cntR + s * NR + rowsR[(size_t)s * E + e], 1);
    else                 atomicAdd(cntP + s * NP + rowsP[(size_t)s * E + e], 1);
}

__global__ __launch_bounds__(256)
void scan_block2_kernel(const int* __restrict__ cR, int* __restrict__ rpR,
                        int* __restrict__ bsR, int NR, int np1R, int NBR,
                        const int* __restrict__ cP, int* __restrict__ rpP,
                        int* __restrict__ bsP, int NP, int np1P, int NBP)
{
    const int side = blockIdx.z;
    const int NB = side ? NBP : NBR;
    if ((int)blockIdx.x >= NB) return;
    const int N = side ? NP : NR;
    const int np1 = side ? np1P : np1R;
    const int* counts = side ? cP : cR;
    int* rowptr = side ? rpP : rpR;
    int* blocksum = side ? bsP : bsR;

    __shared__ int sd[256];
    int s = blockIdx.y;
    int i = blockIdx.x * 256 + threadIdx.x;
    int tid = threadIdx.x;
    int v = (i < N) ? counts[s * N + i] : 0;
    sd[tid] = v;
    __syncthreads();
    #pragma unroll
    for (int off = 1; off < 256; off <<= 1) {
        int t = (tid >= off) ? sd[tid - off] : 0;
        __syncthreads();
        sd[tid] += t;
        __syncthreads();
    }
    if (i < N) rowptr[s * np1 + i] = sd[tid] - v;
    if (tid == 255) blocksum[s * NB + blockIdx.x] = sd[255];
}

__global__ __launch_bounds__(256)
void scan_aux2_kernel(int* __restrict__ bsR, int NBR, int* __restrict__ bsP, int NBP)
{
    const int side = blockIdx.x >> 2;
    const int s = blockIdx.x & 3;
    int* blocksum = side ? bsP : bsR;
    const int NB = side ? NBP : NBR;

    __shared__ int sd[256];
    int tid = threadIdx.x;
    int v = (tid < NB) ? blocksum[s * NB + tid] : 0;
    sd[tid] = v;
    __syncthreads();
    #pragma unroll
    for (int off = 1; off < 256; off <<= 1) {
        int t = (tid >= off) ? sd[tid - off] : 0;
        __syncthreads();
        sd[tid] += t;
        __syncthreads();
    }
    if (tid < NB) blocksum[s * NB + tid] = sd[tid] - v;
}

__global__ __launch_bounds__(256)
void finalize2_kernel(int* __restrict__ rpR, const int* __restrict__ bsR,
                      int* __restrict__ curR, int NR, int np1R, int NBR,
                      int* __restrict__ rpP, const int* __restrict__ bsP,
                      int* __restrict__ curP, int NP, int np1P, int NBP, int E)
{
    const int side = blockIdx.z;
    const int NB = side ? NBP : NBR;
    if ((int)blockIdx.x >= NB) return;
    const int N = side ? NP : NR;
    const int np1 = side ? np1P : np1R;
    int* rowptr = side ? rpP : rpR;
    const int* blocksum = side ? bsP : bsR;
    int* cursor = side ? curP : curR;

    int s = blockIdx.y;
    int i = blockIdx.x * 256 + threadIdx.x;
    if (i < N) {
        int v = rowptr[s * np1 + i] + blocksum[s * NB + blockIdx.x];
        rowptr[s * np1 + i] = v;
        cursor[s * N + i] = v;
    }
    if (i == N) rowptr[s * np1 + N] = E;
}

// Row-sliced XCD-affine fill; cols/vals loaded ONLY on slice match.
__global__ __launch_bounds__(256)
void fill_sliced_kernel(const int* __restrict__ rowsR, const int* __restrict__ colsR,
                        const float* __restrict__ valsR,
                        const int* __restrict__ rowsP, const int* __restrict__ colsP,
                        const float* __restrict__ valsP,
                        int* __restrict__ curR, int* __restrict__ curP,
                        int2* __restrict__ evR, int2* __restrict__ evP,
                        int NR, int NP, int E)
{
    const int slice = blockIdx.x & 7;
    const int chunk = blockIdx.x >> 3;
    const int s     = blockIdx.y;
    const int side  = blockIdx.z;
    const int N          = side ? NP : NR;
    const int* rows      = side ? rowsP : rowsR;
    const int* cols      = side ? colsP : colsR;
    const float* vals    = side ? valsP : valsR;
    int* cursor          = side ? curP : curR;
    int2* ev             = side ? evP : evR;

    const int Nsl = (N + 7) >> 3;
    const int r0 = slice * Nsl;
    const int r1 = min(N, r0 + Nsl);

    const int e0 = chunk * 1024 + threadIdx.x * 4;
    if (e0 >= E) return;
    const size_t base = (size_t)s * E;

    if (e0 + 4 <= E) {
        int4 r4 = *(const int4*)(rows + base + e0);
        int rr[4] = {r4.x, r4.y, r4.z, r4.w};
        #pragma unroll
        for (int j = 0; j < 4; ++j) {
            if (rr[j] >= r0 && rr[j] < r1) {
                int pos = atomicAdd(cursor + s * N + rr[j], 1);
                ev[base + pos] = make_int2(cols[base + e0 + j],
                                           __float_as_int(vals[base + e0 + j]));
            }
        }
    } else {
        for (int j = 0; j < 4 && e0 + j < E; ++j) {
            int r = rows[base + e0 + j];
            if (r >= r0 && r < r1) {
                int pos = atomicAdd(cursor + s * N + r, 1);
                ev[base + pos] = make_int2(cols[base + e0 + j],
                                           __float_as_int(vals[base + e0 + j]));
            }
        }
    }
}

// ---------------------------------------------------------------------------
// CSR SpMM over bf16 tmp + bf16 base, both sides in one grid.
// MODE 0: Base(bf16)[r][col] += acc           (fallback L1)
// MODE 1: OH[r][col] = bf16(relu(Base+acc))   (L0 -> layer-1 A)
// MODE 2: OF[r][col] = relu(Base+acc)         (L1 -> d_out, f32)
// ---------------------------------------------------------------------------
template<int KCH, int MODE>
__global__ __launch_bounds__(256)
void spmm2_kernel(const int* __restrict__ rpR, const int* __restrict__ rpP,
                  int np1R, int np1P,
                  const int2* __restrict__ evRg, const int2* __restrict__ evPg,
                  const u16* __restrict__ InR, const u16* __restrict__ InP, int ldi,
                  u16* __restrict__ BaseR, u16* __restrict__ BaseP, int ldb,
                  u16* __restrict__ OHR, u16* __restrict__ OHP,
                  float* __restrict__ OFR, float* __restrict__ OFP, int ldo,
                  int NR, int E)
{
    int r = blockIdx.x;
    const int s    = threadIdx.x >> 6;
    const int lane = threadIdx.x & 63;
    const int* rp; const int2* ev; const u16* In; u16* Base; int np1;
    u16* OH; float* OF;
    if (r < NR) { rp = rpR; ev = evRg; In = InR; Base = BaseR; np1 = np1R;
                  OH = OHR; OF = OFR; }
    else { r -= NR; rp = rpP; ev = evPg; In = InP; Base = BaseP; np1 = np1P;
           OH = OHP; OF = OFP; }
    int e0 = __builtin_amdgcn_readfirstlane(rp[s * np1 + r]);
    int e1 = __builtin_amdgcn_readfirstlane(rp[s * np1 + r + 1]);
    if (MODE == 0 && e0 == e1) return;
    ev += (size_t)s * E;

    if (KCH == 128) {
        const int col = s * 128 + lane * 2;
        float ax = 0.f, ay = 0.f;
        int e = e0;
        for (; e + 3 < e1; e += 4) {
            int2 pa = ev[e], pb = ev[e+1], pc = ev[e+2], pd = ev[e+3];
            float va = __int_as_float(pa.y), vb = __int_as_float(pb.y);
            float vc = __int_as_float(pc.y), vd = __int_as_float(pd.y);
            u16x2 xa = *(const u16x2*)(In + (size_t)pa.x * ldi + col);
            u16x2 xb = *(const u16x2*)(In + (size_t)pb.x * ldi + col);
            u16x2 xc = *(const u16x2*)(In + (size_t)pc.x * ldi + col);
            u16x2 xd = *(const u16x2*)(In + (size_t)pd.x * ldi + col);
            ax += va * bf2f(xa[0]) + vb * bf2f(xb[0]) + vc * bf2f(xc[0]) + vd * bf2f(xd[0]);
            ay += va * bf2f(xa[1]) + vb * bf2f(xb[1]) + vc * bf2f(xc[1]) + vd * bf2f(xd[1]);
        }
        for (; e < e1; ++e) {
            int2 p = ev[e];
            float v = __int_as_float(p.y);
            u16x2 x = *(const u16x2*)(In + (size_t)p.x * ldi + col);
            ax += v * bf2f(x[0]);  ay += v * bf2f(x[1]);
        }
        u16x2* bp = (u16x2*)(Base + (size_t)r * ldb + col);
        u16x2 b = *bp;
        if (MODE == 0) {
            u16x2 nb = {f2bf(bf2f(b[0]) + ax), f2bf(bf2f(b[1]) + ay)};
            *bp = nb;
        } else if (MODE == 1) {
            u16x2 h = {f2bf(fmaxf(bf2f(b[0]) + ax, 0.f)),
                       f2bf(fmaxf(bf2f(b[1]) + ay, 0.f))};
            *(u16x2*)(OH + (size_t)r * ldo + col) = h;
        } else {
            float2 o;
            o.x = fmaxf(bf2f(b[0]) + ax, 0.f);
            o.y = fmaxf(bf2f(b[1]) + ay, 0.f);
            *(float2*)(OF + (size_t)r * ldo + col) = o;
        }
    } else {   // KCH == 64
        const int col = s * 64 + lane;
        float acc = 0.f;
        int e = e0;
        for (; e + 3 < e1; e += 4) {
            int2 pa = ev[e], pb = ev[e+1], pc = ev[e+2], pd = ev[e+3];
            acc += __int_as_float(pa.y) * bf2f(In[(size_t)pa.x * ldi + col])
                 + __int_as_float(pb.y) * bf2f(In[(size_t)pb.x * ldi + col])
                 + __int_as_float(pc.y) * bf2f(In[(size_t)pc.x * ldi + col])
                 + __int_as_float(pd.y) * bf2f(In[(size_t)pd.x * ldi + col]);
        }
        for (; e < e1; ++e) {
            int2 p = ev[e];
            acc += __int_as_float(p.y) * bf2f(In[(size_t)p.x * ldi + col]);
        }
        u16* bp = Base + (size_t)r * ldb + col;
        if (MODE == 0) {
            *bp = f2bf(bf2f(*bp) + acc);
        } else {
            OF[(size_t)r * ldo + col] = fmaxf(bf2f(*bp) + acc, 0.f);
        }
    }
}

// fallback-only final relu over bf16 base
__global__ __launch_bounds__(256)
void relu_out_kernel(const u16* __restrict__ Z, int ld, int coff,
                     float* __restrict__ out, int M)
{
    int g = blockIdx.x * 256 + threadIdx.x;
    if (g >= M * 256) return;
    int row = g >> 8;
    int col = g & 255;
    out[g] = fmaxf(bf2f(Z[(size_t)row * ld + coff + col]), 0.f);
}

// ---------------------------------------------------------------------------
// weight packing (transposed [N][K], bf16)
// ---------------------------------------------------------------------------
__global__ __launch_bounds__(256)
void pack_b0_kernel(const float* __restrict__ w0, const float* __restrict__ sw0,
                    u16* __restrict__ Bh)
{
    int g = blockIdx.x * 256 + threadIdx.x;
    int j = g >> 10, d = g & 1023;
    float v;
    if (j < 512) v = w0[((size_t)(j >> 7) * 1024 + d) * 128 + (j & 127)];
    else         v = sw0[(size_t)d * 512 + (j - 512)];
    Bh[g] = f2bf(v);
}

__global__ __launch_bounds__(256)
void pack_b1_kernel(const float* __restrict__ w1, const float* __restrict__ sw1,
                    u16* __restrict__ Bh)
{
    int g = blockIdx.x * 256 + threadIdx.x;
    int j = g >> 9, d = g & 511;
    float v;
    if (j < 256) v = w1[((size_t)(j >> 6) * 512 + d) * 64 + (j & 63)];
    else         v = sw1[(size_t)d * 256 + (j - 256)];
    Bh[g] = f2bf(v);
}

extern "C" void kernel_launch(void* const* d_in, const int* in_sizes, int n_in,
                              void* d_out, int out_size, void* d_ws, size_t ws_size,
                              hipStream_t stream)
{
    const int*   rna_rows  = (const int*)  d_in[0];
    const int*   rna_cols  = (const int*)  d_in[1];
    const float* rna_vals  = (const float*)d_in[2];
    const int*   prot_rows = (const int*)  d_in[3];
    const int*   prot_cols = (const int*)  d_in[4];
    const float* prot_vals = (const float*)d_in[5];
    const float* H_rna     = (const float*)d_in[6];
    const float* H_prot    = (const float*)d_in[7];
    const float* w0        = (const float*)d_in[8];
    const float* sw0       = (const float*)d_in[9];
    const float* w1        = (const float*)d_in[10];
    const float* sw1       = (const float*)d_in[11];

    const int NRNA = 50000, NPROT = 20000, S = 4, E = 500000;
    const int MP_RNA = 50048, MP_PROT = 20096;
    const int MP_ALL = MP_RNA + MP_PROT;           // 70144 = 548 * 128
    const int NP1_R = NRNA + 1, NP1_P = NPROT + 1;
    const int NB_R = (NRNA + 255) / 256;
    const int NB_P = (NPROT + 255) / 256;
    const int EB   = (E + 255) / 256;
    const int EB4  = (E + 1023) / 1024;

    // --- ws layout ---
    char* ws = (char*)d_ws;
    size_t off = 0;
    u16*   Y16   = (u16*)  (ws + off); off += (size_t)MP_ALL * 1024 * 2;  // L0 [*,1024]; L1 aliases [*,512]
    u16*   Ahbig = (u16*)  (ws + off); off += (size_t)MP_ALL * 1024 * 2;
    u16*   B0h   = (u16*)  (ws + off); off += (size_t)1024 * 1024 * 2;
    u16*   B1h   = (u16*)  (ws + off); off += (size_t)512 * 512 * 2;
    size_t base_bytes = off;

    u16* AhR = Ahbig;                               // layer-1 A views [MP_ALL][512]
    u16* AhP = Ahbig + (size_t)MP_RNA * 512;

    // CSR scratch
    size_t csr_bytes = 0;
    csr_bytes += (size_t)S * E * 8 * 2;
    csr_bytes += ((size_t)S * (NRNA * 2 + NP1_R + NB_R)) * 4;
    csr_bytes += ((size_t)S * (NPROT * 2 + NP1_P + NB_P)) * 4;
    const bool csr_in_ws = (ws_size >= base_bytes + csr_bytes);

    char* csr = csr_in_ws ? (ws + base_bytes) : (char*)d_out;
    size_t coff = 0;
    int2*  evR     = (int2*) (csr + coff); coff += (size_t)S * E * 8;
    int2*  evP     = (int2*) (csr + coff); coff += (size_t)S * E * 8;
    int*   countsR = (int*)  (csr + coff); coff += (size_t)S * NRNA * 4;
    int*   rowptrR = (int*)  (csr + coff); coff += (size_t)S * NP1_R * 4;
    int*   cursorR = (int*)  (csr + coff); coff += (size_t)S * NRNA * 4;
    int*   bsumR   = (int*)  (csr + coff); coff += (size_t)S * NB_R * 4;
    int*   countsP = (int*)  (csr + coff); coff += (size_t)S * NPROT * 4;
    int*   rowptrP = (int*)  (csr + coff); coff += (size_t)S * NP1_P * 4;
    int*   cursorP = (int*)  (csr + coff); coff += (size_t)S * NPROT * 4;
    int*   bsumP   = (int*)  (csr + coff); coff += (size_t)S * NB_P * 4;

    dim3 blk(256);
    float* out = (float*)d_out;

    // --- pack weights ---
    pack_b0_kernel<<<(1024 * 1024) / 256, blk, 0, stream>>>(w0, sw0, B0h);
    pack_b1_kernel<<<(512 * 512) / 256, blk, 0, stream>>>(w1, sw1, B1h);

    // --- CSR build ---
    zero2_i32_kernel<<<(S * NRNA + 255) / 256, blk, 0, stream>>>(countsR, S * NRNA,
                                                                 countsP, S * NPROT);
    hist2_kernel<<<dim3(EB, S, 2), blk, 0, stream>>>(rna_rows, prot_rows,
                                                     countsR, countsP, NRNA, NPROT, E);
    scan_block2_kernel<<<dim3(NB_R, S, 2), blk, 0, stream>>>(
        countsR, rowptrR, bsumR, NRNA, NP1_R, NB_R,
        countsP, rowptrP, bsumP, NPROT, NP1_P, NB_P);
    scan_aux2_kernel<<<8, blk, 0, stream>>>(bsumR, NB_R, bsumP, NB_P);
    finalize2_kernel<<<dim3(NB_R, S, 2), blk, 0, stream>>>(
        rowptrR, bsumR, cursorR, NRNA, NP1_R, NB_R,
        rowptrP, bsumP, cursorP, NPROT, NP1_P, NB_P, E);
    fill_sliced_kernel<<<dim3(EB4 * 8, S, 2), blk, 0, stream>>>(
        rna_rows, rna_cols, rna_vals, prot_rows, prot_cols, prot_vals,
        cursorR, cursorP, evR, evP, NRNA, NPROT, E);

    // --- layer 0: cvt + one GEMM (N=K=1024, all-bf16 out) ---
    cvt_bf16_kernel<<<MP_RNA / 2, blk, 0, stream>>>(H_rna, Ahbig, NRNA, 10);
    cvt_bf16_kernel<<<MP_PROT / 2, blk, 0, stream>>>(H_prot, Ahbig + (size_t)MP_RNA * 1024,
                                                     NPROT, 10);
    gemm_bf16_kernel<<<8 * (MP_ALL / 128), blk, 0, stream>>>(
        Ahbig, B0h, Y16, 1024, 1024, 7, 3);

    // --- layer 0 SpMM: Ah = bf16(relu(base + agg)) ---
    spmm2_kernel<128, 1><<<NRNA + NPROT, blk, 0, stream>>>(
        rowptrR, rowptrP, NP1_R, NP1_P, evR, evP,
        Y16 + (size_t)MP_RNA * 1024,      // RNA gathers prot tmp (cols 0..511)
        Y16,                              // PROT gathers rna tmp
        1024,
        Y16 + 512, Y16 + (size_t)MP_RNA * 1024 + 512, 1024,   // bf16 base halves
        AhR, AhP, nullptr, nullptr, 512,
        NRNA, E);

    // --- zero layer-1 A pad rows ---
    zero_u16_kernel<<<(48 * 512 + 255) / 256, blk, 0, stream>>>(
        AhR + (size_t)NRNA * 512, 48 * 512);
    zero_u16_kernel<<<(96 * 512 + 255) / 256, blk, 0, stream>>>(
        AhP + (size_t)NPROT * 512, 96 * 512);

    // --- layer 1: one GEMM (N=K=512), Y16_1 aliases Y16 [MP_ALL][512] ---
    gemm_bf16_kernel<<<4 * (MP_ALL / 128), blk, 0, stream>>>(
        Ahbig, B1h, Y16, 512, 512, 3, 2);

    // --- layer 1 SpMM ---
    if (csr_in_ws) {
        spmm2_kernel<64, 2><<<NRNA + NPROT, blk, 0, stream>>>(
            rowptrR, rowptrP, NP1_R, NP1_P, evR, evP,
            Y16 + (size_t)MP_RNA * 512, Y16, 512,
            Y16 + 256, Y16 + (size_t)MP_RNA * 512 + 256, 512,
            nullptr, nullptr,
            out, out + (size_t)NRNA * 256, 256,
            NRNA, E);
    } else {
        spmm2_kernel<64, 0><<<NRNA + NPROT, blk, 0, stream>>>(
            rowptrR, rowptrP, NP1_R, NP1_P, evR, evP,
            Y16 + (size_t)MP_RNA * 512, Y16, 512,
            Y16 + 256, Y16 + (size_t)MP_RNA * 512 + 256, 512,
            nullptr, nullptr,
            nullptr, nullptr, 0,
            NRNA, E);
        relu_out_kernel<<<(NRNA * 256) / 256, blk, 0, stream>>>(Y16, 512, 256, out, NRNA);
        relu_out_kernel<<<(NPROT * 256) / 256, blk, 0, stream>>>(
            Y16 + (size_t)MP_RNA * 512, 512, 256, out + (size_t)NRNA * 256, NPROT);
    }
}

// Round 15
// 1044.975 us; speedup vs baseline: 1.5305x; 1.0559x over previous
//
#include <hip/hip_runtime.h>
#include <hip/hip_bf16.h>

// ---------------------------------------------------------------------------
// StackGCNEncoder on MI355X — round 15 (= round 14 resubmitted; infra failure):
//   spmm: HALF-WAVE EDGE PAIRING. Lanes 0-31 process edge e, lanes 32-63
//   edge e+1 (each lane u16x4/u16x2) -> 2 edges per load issue, 8 gathers in
//   flight with 4-pair unroll (2x MLP vs r13). Cross-half combine via
//   shfl_xor(32); lanes 0-31 do base+write.
//   Everything else identical to round 13 (all-bf16 Y, 1-term GEMM, sliced
//   fill, counted-vmcnt GEMM, XOR swizzle).
// ---------------------------------------------------------------------------

typedef unsigned short u16;
typedef short s16x8 __attribute__((ext_vector_type(8)));
typedef float f32x4 __attribute__((ext_vector_type(4)));
typedef __attribute__((ext_vector_type(8))) unsigned short u16x8;
typedef __attribute__((ext_vector_type(4))) unsigned short u16x4;
typedef __attribute__((ext_vector_type(2))) unsigned short u16x2;

__device__ __forceinline__ u16 f2bf(float x) {            // RNE f32->bf16
    unsigned u = __float_as_uint(x);
    return (u16)((u + 0x7fff + ((u >> 16) & 1)) >> 16);
}
__device__ __forceinline__ float bf2f(u16 h) {
    return __uint_as_float(((unsigned)h) << 16);
}

__device__ __forceinline__ void gload16(const u16* g, u16* l) {
    __builtin_amdgcn_global_load_lds(
        (const __attribute__((address_space(1))) unsigned int*)g,
        (__attribute__((address_space(3))) unsigned int*)l,
        16, 0, 0);
}

// ---------------------------------------------------------------------------
// bf16 GEMM: Y16 = A x B^T, all-bf16 out. 128x128, BK=32, 32 KB dbuf LDS,
// XOR chunk swizzle, counted-vmcnt barriers, bijective XCD swizzle.
// ---------------------------------------------------------------------------
__global__ __launch_bounds__(256)
void gemm_bf16_kernel(const u16* __restrict__ Ah, const u16* __restrict__ Bh,
                      u16* __restrict__ Y, int ldy,
                      int K, int nxmask, int nxshift)
{
    __shared__ u16 lds[2][2][4096];   // 32 KB

    const int nwg = gridDim.x;
    const int q   = nwg >> 3, r8 = nwg & 7;
    const int xcd = blockIdx.x & 7, pos = blockIdx.x >> 3;
    const int lin = (xcd < r8 ? xcd * (q + 1) : r8 * (q + 1) + (xcd - r8) * q) + pos;
    const int bm0 = (lin >> nxshift) * 128;
    const int bn0 = (lin & nxmask) * 128;

    const int tid  = threadIdx.x;
    const int lane = tid & 63;
    const int wid  = tid >> 6;
    const int wr   = wid >> 1;
    const int wc   = wid & 1;

    const int srow = tid >> 2;
    const int scol = ((tid & 3) ^ ((tid >> 3) & 3)) * 8;   // u16 units
    const size_t aoff0 = (size_t)(bm0 + srow) * K + scol;
    const size_t aoff1 = (size_t)(bm0 + srow + 64) * K + scol;
    const size_t boff0 = (size_t)(bn0 + srow) * K + scol;
    const size_t boff1 = (size_t)(bn0 + srow + 64) * K + scol;
    const int c0 = tid * 8;
    const int c1 = 2048 + tid * 8;

    u16* L0 = &lds[0][0][0];              // buffer stride 8192 u16

    f32x4 zero = {0.f, 0.f, 0.f, 0.f};
    f32x4 acc[4][4];
    #pragma unroll
    for (int i = 0; i < 4; ++i)
        #pragma unroll
        for (int j = 0; j < 4; ++j) acc[i][j] = zero;

    const int fchunk = (((lane >> 4) ^ ((lane >> 1) & 3))) * 8;
    const int a_fr = (wr * 64 + (lane & 15)) * 32 + fchunk;
    const int b_fr = (wc * 64 + (lane & 15)) * 32 + fchunk;

    const int nk = K >> 5;

    {
        u16* L = L0;
        gload16(Ah + aoff0, L + c0);          gload16(Ah + aoff1, L + c1);
        gload16(Bh + boff0, L + 4096 + c0);   gload16(Bh + boff1, L + 4096 + c1);
    }
    int cur = 0;
    for (int t = 0; t < nk; ++t) {
        if (t + 1 < nk) {
            const int k0 = (t + 1) * 32;
            u16* L = L0 + (cur ^ 1) * 8192;
            gload16(Ah + aoff0 + k0, L + c0);         gload16(Ah + aoff1 + k0, L + c1);
            gload16(Bh + boff0 + k0, L + 4096 + c0);  gload16(Bh + boff1 + k0, L + 4096 + c1);
            asm volatile("s_waitcnt vmcnt(4)\n\ts_barrier" ::: "memory");
        } else {
            asm volatile("s_waitcnt vmcnt(0)\n\ts_barrier" ::: "memory");
        }
        const u16* L = L0 + cur * 8192;
        s16x8 bh[4];
        #pragma unroll
        for (int nf = 0; nf < 4; ++nf)
            bh[nf] = *(const s16x8*)(L + 4096 + b_fr + nf * 512);
        #pragma unroll
        for (int mf = 0; mf < 4; ++mf) {
            s16x8 ahv = *(const s16x8*)(L + a_fr + mf * 512);
            #pragma unroll
            for (int nf = 0; nf < 4; ++nf)
                acc[mf][nf] = __builtin_amdgcn_mfma_f32_16x16x32_bf16(ahv, bh[nf], acc[mf][nf], 0, 0, 0);
        }
        asm volatile("s_barrier" ::: "memory");
        cur ^= 1;
    }

    #pragma unroll
    for (int mf = 0; mf < 4; ++mf) {
        const int row0 = bm0 + wr * 64 + mf * 16 + (lane >> 4) * 4;
        #pragma unroll
        for (int nf = 0; nf < 4; ++nf) {
            const int col = bn0 + wc * 64 + nf * 16 + (lane & 15);
            #pragma unroll
            for (int r = 0; r < 4; ++r)
                Y[(size_t)(row0 + r) * ldy + col] = f2bf(acc[mf][nf][r]);
        }
    }
}

// ---------------------------------------------------------------------------
// f32 [M][K] -> bf16 [Mpad][K], zero-padded rows. 8 elems/thread.
// ---------------------------------------------------------------------------
__global__ __launch_bounds__(256)
void cvt_bf16_kernel(const float* __restrict__ A, u16* __restrict__ Hh,
                     int M, int kshift)
{
    const size_t g  = (size_t)blockIdx.x * 256 + threadIdx.x;
    const size_t i8 = g * 8;
    const int row   = (int)(i8 >> kshift);
    f32x4 a = {0.f, 0.f, 0.f, 0.f}, b = {0.f, 0.f, 0.f, 0.f};
    if (row < M) {
        a = *(const f32x4*)(A + i8);
        b = *(const f32x4*)(A + i8 + 4);
    }
    u16x8 h;
    #pragma unroll
    for (int j = 0; j < 4; ++j) { h[j] = f2bf(a[j]); h[4 + j] = f2bf(b[j]); }
    *(u16x8*)(Hh + i8) = h;
}

__global__ __launch_bounds__(256)
void zero_u16_kernel(u16* __restrict__ a, int n)
{
    int i = blockIdx.x * 256 + threadIdx.x;
    if (i < n) a[i] = 0;
}

// ---------------------------------------------------------------------------
// CSR build
// ---------------------------------------------------------------------------
__global__ __launch_bounds__(256)
void zero2_i32_kernel(int* __restrict__ a, int na, int* __restrict__ b, int nb)
{
    int i = blockIdx.x * 256 + threadIdx.x;
    if (i < na) a[i] = 0;
    if (i < nb) b[i] = 0;
}

__global__ __launch_bounds__(256)
void hist2_kernel(const int* __restrict__ rowsR, const int* __restrict__ rowsP,
                  int* __restrict__ cntR, int* __restrict__ cntP,
                  int NR, int NP, int E)
{
    int s = blockIdx.y;
    int e = blockIdx.x * 256 + threadIdx.x;
    if (e >= E) return;
    if (blockIdx.z == 0) atomicAdd(cntR + s * NR + rowsR[(size_t)s * E + e], 1);
    else                 atomicAdd(cntP + s * NP + rowsP[(size_t)s * E + e], 1);
}

__global__ __launch_bounds__(256)
void scan_block2_kernel(const int* __restrict__ cR, int* __restrict__ rpR,
                        int* __restrict__ bsR, int NR, int np1R, int NBR,
                        const int* __restrict__ cP, int* __restrict__ rpP,
                        int* __restrict__ bsP, int NP, int np1P, int NBP)
{
    const int side = blockIdx.z;
    const int NB = side ? NBP : NBR;
    if ((int)blockIdx.x >= NB) return;
    const int N = side ? NP : NR;
    const int np1 = side ? np1P : np1R;
    const int* counts = side ? cP : cR;
    int* rowptr = side ? rpP : rpR;
    int* blocksum = side ? bsP : bsR;

    __shared__ int sd[256];
    int s = blockIdx.y;
    int i = blockIdx.x * 256 + threadIdx.x;
    int tid = threadIdx.x;
    int v = (i < N) ? counts[s * N + i] : 0;
    sd[tid] = v;
    __syncthreads();
    #pragma unroll
    for (int off = 1; off < 256; off <<= 1) {
        int t = (tid >= off) ? sd[tid - off] : 0;
        __syncthreads();
        sd[tid] += t;
        __syncthreads();
    }
    if (i < N) rowptr[s * np1 + i] = sd[tid] - v;
    if (tid == 255) blocksum[s * NB + blockIdx.x] = sd[255];
}

__global__ __launch_bounds__(256)
void scan_aux2_kernel(int* __restrict__ bsR, int NBR, int* __restrict__ bsP, int NBP)
{
    const int side = blockIdx.x >> 2;
    const int s = blockIdx.x & 3;
    int* blocksum = side ? bsP : bsR;
    const int NB = side ? NBP : NBR;

    __shared__ int sd[256];
    int tid = threadIdx.x;
    int v = (tid < NB) ? blocksum[s * NB + tid] : 0;
    sd[tid] = v;
    __syncthreads();
    #pragma unroll
    for (int off = 1; off < 256; off <<= 1) {
        int t = (tid >= off) ? sd[tid - off] : 0;
        __syncthreads();
        sd[tid] += t;
        __syncthreads();
    }
    if (tid < NB) blocksum[s * NB + tid] = sd[tid] - v;
}

__global__ __launch_bounds__(256)
void finalize2_kernel(int* __restrict__ rpR, const int* __restrict__ bsR,
                      int* __restrict__ curR, int NR, int np1R, int NBR,
                      int* __restrict__ rpP, const int* __restrict__ bsP,
                      int* __restrict__ curP, int NP, int np1P, int NBP, int E)
{
    const int side = blockIdx.z;
    const int NB = side ? NBP : NBR;
    if ((int)blockIdx.x >= NB) return;
    const int N = side ? NP : NR;
    const int np1 = side ? np1P : np1R;
    int* rowptr = side ? rpP : rpR;
    const int* blocksum = side ? bsP : bsR;
    int* cursor = side ? curP : curR;

    int s = blockIdx.y;
    int i = blockIdx.x * 256 + threadIdx.x;
    if (i < N) {
        int v = rowptr[s * np1 + i] + blocksum[s * NB + blockIdx.x];
        rowptr[s * np1 + i] = v;
        cursor[s * N + i] = v;
    }
    if (i == N) rowptr[s * np1 + N] = E;
}

// Row-sliced XCD-affine fill; cols/vals loaded only on slice match.
__global__ __launch_bounds__(256)
void fill_sliced_kernel(const int* __restrict__ rowsR, const int* __restrict__ colsR,
                        const float* __restrict__ valsR,
                        const int* __restrict__ rowsP, const int* __restrict__ colsP,
                        const float* __restrict__ valsP,
                        int* __restrict__ curR, int* __restrict__ curP,
                        int2* __restrict__ evR, int2* __restrict__ evP,
                        int NR, int NP, int E)
{
    const int slice = blockIdx.x & 7;
    const int chunk = blockIdx.x >> 3;
    const int s     = blockIdx.y;
    const int side  = blockIdx.z;
    const int N          = side ? NP : NR;
    const int* rows      = side ? rowsP : rowsR;
    const int* cols      = side ? colsP : colsR;
    const float* vals    = side ? valsP : valsR;
    int* cursor          = side ? curP : curR;
    int2* ev             = side ? evP : evR;

    const int Nsl = (N + 7) >> 3;
    const int r0 = slice * Nsl;
    const int r1 = min(N, r0 + Nsl);

    const int e0 = chunk * 1024 + threadIdx.x * 4;
    if (e0 >= E) return;
    const size_t base = (size_t)s * E;

    if (e0 + 4 <= E) {
        int4 r4 = *(const int4*)(rows + base + e0);
        int rr[4] = {r4.x, r4.y, r4.z, r4.w};
        #pragma unroll
        for (int j = 0; j < 4; ++j) {
            if (rr[j] >= r0 && rr[j] < r1) {
                int pos = atomicAdd(cursor + s * N + rr[j], 1);
                ev[base + pos] = make_int2(cols[base + e0 + j],
                                           __float_as_int(vals[base + e0 + j]));
            }
        }
    } else {
        for (int j = 0; j < 4 && e0 + j < E; ++j) {
            int r = rows[base + e0 + j];
            if (r >= r0 && r < r1) {
                int pos = atomicAdd(cursor + s * N + r, 1);
                ev[base + pos] = make_int2(cols[base + e0 + j],
                                           __float_as_int(vals[base + e0 + j]));
            }
        }
    }
}

// ---------------------------------------------------------------------------
// CSR SpMM, half-wave edge pairing: lanes 0-31 edge e, lanes 32-63 edge e+1.
// KCH=128: lane covers 4 cols (u16x4); KCH=64: 2 cols (u16x2).
// Cross-half combine via shfl_xor(32); lanes 0-31 write.
// MODE 0: Base(bf16) += acc | MODE 1: OH = bf16(relu(Base+acc))
// MODE 2: OF = relu(Base+acc) (f32)
// ---------------------------------------------------------------------------
template<int KCH, int MODE>
__global__ __launch_bounds__(256)
void spmm2_kernel(const int* __restrict__ rpR, const int* __restrict__ rpP,
                  int np1R, int np1P,
                  const int2* __restrict__ evRg, const int2* __restrict__ evPg,
                  const u16* __restrict__ InR, const u16* __restrict__ InP, int ldi,
                  u16* __restrict__ BaseR, u16* __restrict__ BaseP, int ldb,
                  u16* __restrict__ OHR, u16* __restrict__ OHP,
                  float* __restrict__ OFR, float* __restrict__ OFP, int ldo,
                  int NR, int E)
{
    int r = blockIdx.x;
    const int s    = threadIdx.x >> 6;
    const int lane = threadIdx.x & 63;
    const int half = lane >> 5;
    const int hl   = lane & 31;
    const int* rp; const int2* ev; const u16* In; u16* Base; int np1;
    u16* OH; float* OF;
    if (r < NR) { rp = rpR; ev = evRg; In = InR; Base = BaseR; np1 = np1R;
                  OH = OHR; OF = OFR; }
    else { r -= NR; rp = rpP; ev = evPg; In = InP; Base = BaseP; np1 = np1P;
           OH = OHP; OF = OFP; }
    int e0 = __builtin_amdgcn_readfirstlane(rp[s * np1 + r]);
    int e1 = __builtin_amdgcn_readfirstlane(rp[s * np1 + r + 1]);
    if (MODE == 0 && e0 == e1) return;
    ev += (size_t)s * E;

    if (KCH == 128) {
        const int col = s * 128 + hl * 4;     // 4 cols/lane, 32 lanes = 128 cols
        f32x4 acc = {0.f, 0.f, 0.f, 0.f};
        int e = e0;
        for (; e + 7 < e1; e += 8) {          // 4 pairs -> 8 gathers in flight
            #pragma unroll
            for (int p = 0; p < 4; ++p) {
                int2 pv = ev[e + 2 * p + half];
                float v = __int_as_float(pv.y);
                u16x4 x = *(const u16x4*)(In + (size_t)pv.x * ldi + col);
                acc[0] += v * bf2f(x[0]); acc[1] += v * bf2f(x[1]);
                acc[2] += v * bf2f(x[2]); acc[3] += v * bf2f(x[3]);
            }
        }
        for (; e + 1 < e1; e += 2) {
            int2 pv = ev[e + half];
            float v = __int_as_float(pv.y);
            u16x4 x = *(const u16x4*)(In + (size_t)pv.x * ldi + col);
            acc[0] += v * bf2f(x[0]); acc[1] += v * bf2f(x[1]);
            acc[2] += v * bf2f(x[2]); acc[3] += v * bf2f(x[3]);
        }
        if (e < e1 && half == 0) {            // odd leftover: lo half only
            int2 pv = ev[e];
            float v = __int_as_float(pv.y);
            u16x4 x = *(const u16x4*)(In + (size_t)pv.x * ldi + col);
            acc[0] += v * bf2f(x[0]); acc[1] += v * bf2f(x[1]);
            acc[2] += v * bf2f(x[2]); acc[3] += v * bf2f(x[3]);
        }
        #pragma unroll
        for (int j = 0; j < 4; ++j)
            acc[j] += __shfl_xor(acc[j], 32);
        if (half == 0) {
            u16x4* bp = (u16x4*)(Base + (size_t)r * ldb + col);
            u16x4 b = *bp;
            if (MODE == 0) {
                u16x4 nb;
                #pragma unroll
                for (int j = 0; j < 4; ++j) nb[j] = f2bf(bf2f(b[j]) + acc[j]);
                *bp = nb;
            } else if (MODE == 1) {
                u16x4 h;
                #pragma unroll
                for (int j = 0; j < 4; ++j) h[j] = f2bf(fmaxf(bf2f(b[j]) + acc[j], 0.f));
                *(u16x4*)(OH + (size_t)r * ldo + col) = h;
            } else {
                f32x4 o;
                #pragma unroll
                for (int j = 0; j < 4; ++j) o[j] = fmaxf(bf2f(b[j]) + acc[j], 0.f);
                *(f32x4*)(OF + (size_t)r * ldo + col) = o;
            }
        }
    } else {   // KCH == 64
        const int col = s * 64 + hl * 2;      // 2 cols/lane, 32 lanes = 64 cols
        float a0 = 0.f, a1 = 0.f;
        int e = e0;
        for (; e + 7 < e1; e += 8) {
            #pragma unroll
            for (int p = 0; p < 4; ++p) {
                int2 pv = ev[e + 2 * p + half];
                float v = __int_as_float(pv.y);
                u16x2 x = *(const u16x2*)(In + (size_t)pv.x * ldi + col);
                a0 += v * bf2f(x[0]); a1 += v * bf2f(x[1]);
            }
        }
        for (; e + 1 < e1; e += 2) {
            int2 pv = ev[e + half];
            float v = __int_as_float(pv.y);
            u16x2 x = *(const u16x2*)(In + (size_t)pv.x * ldi + col);
            a0 += v * bf2f(x[0]); a1 += v * bf2f(x[1]);
        }
        if (e < e1 && half == 0) {
            int2 pv = ev[e];
            float v = __int_as_float(pv.y);
            u16x2 x = *(const u16x2*)(In + (size_t)pv.x * ldi + col);
            a0 += v * bf2f(x[0]); a1 += v * bf2f(x[1]);
        }
        a0 += __shfl_xor(a0, 32);
        a1 += __shfl_xor(a1, 32);
        if (half == 0) {
            u16x2* bp = (u16x2*)(Base + (size_t)r * ldb + col);
            u16x2 b = *bp;
            if (MODE == 0) {
                u16x2 nb = {f2bf(bf2f(b[0]) + a0), f2bf(bf2f(b[1]) + a1)};
                *bp = nb;
            } else {
                float2 o;
                o.x = fmaxf(bf2f(b[0]) + a0, 0.f);
                o.y = fmaxf(bf2f(b[1]) + a1, 0.f);
                *(float2*)(OF + (size_t)r * ldo + col) = o;
            }
        }
    }
}

// fallback-only final relu over bf16 base
__global__ __launch_bounds__(256)
void relu_out_kernel(const u16* __restrict__ Z, int ld, int coff,
                     float* __restrict__ out, int M)
{
    int g = blockIdx.x * 256 + threadIdx.x;
    if (g >= M * 256) return;
    int row = g >> 8;
    int col = g & 255;
    out[g] = fmaxf(bf2f(Z[(size_t)row * ld + coff + col]), 0.f);
}

// ---------------------------------------------------------------------------
// weight packing (transposed [N][K], bf16)
// ---------------------------------------------------------------------------
__global__ __launch_bounds__(256)
void pack_b0_kernel(const float* __restrict__ w0, const float* __restrict__ sw0,
                    u16* __restrict__ Bh)
{
    int g = blockIdx.x * 256 + threadIdx.x;
    int j = g >> 10, d = g & 1023;
    float v;
    if (j < 512) v = w0[((size_t)(j >> 7) * 1024 + d) * 128 + (j & 127)];
    else         v = sw0[(size_t)d * 512 + (j - 512)];
    Bh[g] = f2bf(v);
}

__global__ __launch_bounds__(256)
void pack_b1_kernel(const float* __restrict__ w1, const float* __restrict__ sw1,
                    u16* __restrict__ Bh)
{
    int g = blockIdx.x * 256 + threadIdx.x;
    int j = g >> 9, d = g & 511;
    float v;
    if (j < 256) v = w1[((size_t)(j >> 6) * 512 + d) * 64 + (j & 63)];
    else         v = sw1[(size_t)d * 256 + (j - 256)];
    Bh[g] = f2bf(v);
}

extern "C" void kernel_launch(void* const* d_in, const int* in_sizes, int n_in,
                              void* d_out, int out_size, void* d_ws, size_t ws_size,
                              hipStream_t stream)
{
    const int*   rna_rows  = (const int*)  d_in[0];
    const int*   rna_cols  = (const int*)  d_in[1];
    const float* rna_vals  = (const float*)d_in[2];
    const int*   prot_rows = (const int*)  d_in[3];
    const int*   prot_cols = (const int*)  d_in[4];
    const float* prot_vals = (const float*)d_in[5];
    const float* H_rna     = (const float*)d_in[6];
    const float* H_prot    = (const float*)d_in[7];
    const float* w0        = (const float*)d_in[8];
    const float* sw0       = (const float*)d_in[9];
    const float* w1        = (const float*)d_in[10];
    const float* sw1       = (const float*)d_in[11];

    const int NRNA = 50000, NPROT = 20000, S = 4, E = 500000;
    const int MP_RNA = 50048, MP_PROT = 20096;
    const int MP_ALL = MP_RNA + MP_PROT;           // 70144 = 548 * 128
    const int NP1_R = NRNA + 1, NP1_P = NPROT + 1;
    const int NB_R = (NRNA + 255) / 256;
    const int NB_P = (NPROT + 255) / 256;
    const int EB   = (E + 255) / 256;
    const int EB4  = (E + 1023) / 1024;

    // --- ws layout ---
    char* ws = (char*)d_ws;
    size_t off = 0;
    u16*   Y16   = (u16*)  (ws + off); off += (size_t)MP_ALL * 1024 * 2;  // L0 [*,1024]; L1 aliases [*,512]
    u16*   Ahbig = (u16*)  (ws + off); off += (size_t)MP_ALL * 1024 * 2;
    u16*   B0h   = (u16*)  (ws + off); off += (size_t)1024 * 1024 * 2;
    u16*   B1h   = (u16*)  (ws + off); off += (size_t)512 * 512 * 2;
    size_t base_bytes = off;

    u16* AhR = Ahbig;                               // layer-1 A views [MP_ALL][512]
    u16* AhP = Ahbig + (size_t)MP_RNA * 512;

    // CSR scratch
    size_t csr_bytes = 0;
    csr_bytes += (size_t)S * E * 8 * 2;
    csr_bytes += ((size_t)S * (NRNA * 2 + NP1_R + NB_R)) * 4;
    csr_bytes += ((size_t)S * (NPROT * 2 + NP1_P + NB_P)) * 4;
    const bool csr_in_ws = (ws_size >= base_bytes + csr_bytes);

    char* csr = csr_in_ws ? (ws + base_bytes) : (char*)d_out;
    size_t coff = 0;
    int2*  evR     = (int2*) (csr + coff); coff += (size_t)S * E * 8;
    int2*  evP     = (int2*) (csr + coff); coff += (size_t)S * E * 8;
    int*   countsR = (int*)  (csr + coff); coff += (size_t)S * NRNA * 4;
    int*   rowptrR = (int*)  (csr + coff); coff += (size_t)S * NP1_R * 4;
    int*   cursorR = (int*)  (csr + coff); coff += (size_t)S * NRNA * 4;
    int*   bsumR   = (int*)  (csr + coff); coff += (size_t)S * NB_R * 4;
    int*   countsP = (int*)  (csr + coff); coff += (size_t)S * NPROT * 4;
    int*   rowptrP = (int*)  (csr + coff); coff += (size_t)S * NP1_P * 4;
    int*   cursorP = (int*)  (csr + coff); coff += (size_t)S * NPROT * 4;
    int*   bsumP   = (int*)  (csr + coff); coff += (size_t)S * NB_P * 4;

    dim3 blk(256);
    float* out = (float*)d_out;

    // --- pack weights ---
    pack_b0_kernel<<<(1024 * 1024) / 256, blk, 0, stream>>>(w0, sw0, B0h);
    pack_b1_kernel<<<(512 * 512) / 256, blk, 0, stream>>>(w1, sw1, B1h);

    // --- CSR build ---
    zero2_i32_kernel<<<(S * NRNA + 255) / 256, blk, 0, stream>>>(countsR, S * NRNA,
                                                                 countsP, S * NPROT);
    hist2_kernel<<<dim3(EB, S, 2), blk, 0, stream>>>(rna_rows, prot_rows,
                                                     countsR, countsP, NRNA, NPROT, E);
    scan_block2_kernel<<<dim3(NB_R, S, 2), blk, 0, stream>>>(
        countsR, rowptrR, bsumR, NRNA, NP1_R, NB_R,
        countsP, rowptrP, bsumP, NPROT, NP1_P, NB_P);
    scan_aux2_kernel<<<8, blk, 0, stream>>>(bsumR, NB_R, bsumP, NB_P);
    finalize2_kernel<<<dim3(NB_R, S, 2), blk, 0, stream>>>(
        rowptrR, bsumR, cursorR, NRNA, NP1_R, NB_R,
        rowptrP, bsumP, cursorP, NPROT, NP1_P, NB_P, E);
    fill_sliced_kernel<<<dim3(EB4 * 8, S, 2), blk, 0, stream>>>(
        rna_rows, rna_cols, rna_vals, prot_rows, prot_cols, prot_vals,
        cursorR, cursorP, evR, evP, NRNA, NPROT, E);

    // --- layer 0: cvt + one GEMM (N=K=1024, all-bf16 out) ---
    cvt_bf16_kernel<<<MP_RNA / 2, blk, 0, stream>>>(H_rna, Ahbig, NRNA, 10);
    cvt_bf16_kernel<<<MP_PROT / 2, blk, 0, stream>>>(H_prot, Ahbig + (size_t)MP_RNA * 1024,
                                                     NPROT, 10);
    gemm_bf16_kernel<<<8 * (MP_ALL / 128), blk, 0, stream>>>(
        Ahbig, B0h, Y16, 1024, 1024, 7, 3);

    // --- layer 0 SpMM: Ah = bf16(relu(base + agg)) ---
    spmm2_kernel<128, 1><<<NRNA + NPROT, blk, 0, stream>>>(
        rowptrR, rowptrP, NP1_R, NP1_P, evR, evP,
        Y16 + (size_t)MP_RNA * 1024,      // RNA gathers prot tmp (cols 0..511)
        Y16,                              // PROT gathers rna tmp
        1024,
        Y16 + 512, Y16 + (size_t)MP_RNA * 1024 + 512, 1024,   // bf16 base halves
        AhR, AhP, nullptr, nullptr, 512,
        NRNA, E);

    // --- zero layer-1 A pad rows ---
    zero_u16_kernel<<<(48 * 512 + 255) / 256, blk, 0, stream>>>(
        AhR + (size_t)NRNA * 512, 48 * 512);
    zero_u16_kernel<<<(96 * 512 + 255) / 256, blk, 0, stream>>>(
        AhP + (size_t)NPROT * 512, 96 * 512);

    // --- layer 1: one GEMM (N=K=512), Y16_1 aliases Y16 [MP_ALL][512] ---
    gemm_bf16_kernel<<<4 * (MP_ALL / 128), blk, 0, stream>>>(
        Ahbig, B1h, Y16, 512, 512, 3, 2);

    // --- layer 1 SpMM ---
    if (csr_in_ws) {
        spmm2_kernel<64, 2><<<NRNA + NPROT, blk, 0, stream>>>(
            rowptrR, rowptrP, NP1_R, NP1_P, evR, evP,
            Y16 + (size_t)MP_RNA * 512, Y16, 512,
            Y16 + 256, Y16 + (size_t)MP_RNA * 512 + 256, 512,
            nullptr, nullptr,
            out, out + (size_t)NRNA * 256, 256,
            NRNA, E);
    } else {
        spmm2_kernel<64, 0><<<NRNA + NPROT, blk, 0, stream>>>(
            rowptrR, rowptrP, NP1_R, NP1_P, evR, evP,
            Y16 + (size_t)MP_RNA * 512, Y16, 512,
            Y16 + 256, Y16 + (size_t)MP_RNA * 512 + 256, 512,
            nullptr, nullptr,
            nullptr, nullptr, 0,
            NRNA, E);
        relu_out_kernel<<<(NRNA * 256) / 256, blk, 0, stream>>>(Y16, 512, 256, out, NRNA);
        relu_out_kernel<<<(NPROT * 256) / 256, blk, 0, stream>>>(
            Y16 + (size_t)MP_RNA * 512, 512, 256, out + (size_t)NRNA * 256, NPROT);
    }
}

// Round 17
// 992.802 us; speedup vs baseline: 1.6110x; 1.0526x over previous
//
#include <hip/hip_runtime.h>
#include <hip/hip_bf16.h>

// ---------------------------------------------------------------------------
// StackGCNEncoder on MI355X — round 17 (= round 16 resubmitted; infra failure):
//   spmm: QUARTER-WAVE (KCH=128: 16 lanes/edge, u16x8/lane, 4 edges/instr)
//   and EIGHTH-WAVE (KCH=64: 8 lanes/edge, 8 edges/instr) edge parallelism.
//   Unroll-2 keeps 8 gathers in flight with half (quarter) the instruction
//   count of r15's half-wave scheme. Combine via shfl_xor(8/16/32).
//   Everything else identical to round 15.
// ---------------------------------------------------------------------------

typedef unsigned short u16;
typedef short s16x8 __attribute__((ext_vector_type(8)));
typedef float f32x4 __attribute__((ext_vector_type(4)));
typedef __attribute__((ext_vector_type(8))) unsigned short u16x8;
typedef __attribute__((ext_vector_type(4))) unsigned short u16x4;
typedef __attribute__((ext_vector_type(2))) unsigned short u16x2;

__device__ __forceinline__ u16 f2bf(float x) {            // RNE f32->bf16
    unsigned u = __float_as_uint(x);
    return (u16)((u + 0x7fff + ((u >> 16) & 1)) >> 16);
}
__device__ __forceinline__ float bf2f(u16 h) {
    return __uint_as_float(((unsigned)h) << 16);
}

__device__ __forceinline__ void gload16(const u16* g, u16* l) {
    __builtin_amdgcn_global_load_lds(
        (const __attribute__((address_space(1))) unsigned int*)g,
        (__attribute__((address_space(3))) unsigned int*)l,
        16, 0, 0);
}

// ---------------------------------------------------------------------------
// bf16 GEMM (unchanged): Y16 = A x B^T, all-bf16 out. 128x128, BK=32.
// ---------------------------------------------------------------------------
__global__ __launch_bounds__(256)
void gemm_bf16_kernel(const u16* __restrict__ Ah, const u16* __restrict__ Bh,
                      u16* __restrict__ Y, int ldy,
                      int K, int nxmask, int nxshift)
{
    __shared__ u16 lds[2][2][4096];   // 32 KB

    const int nwg = gridDim.x;
    const int q   = nwg >> 3, r8 = nwg & 7;
    const int xcd = blockIdx.x & 7, pos = blockIdx.x >> 3;
    const int lin = (xcd < r8 ? xcd * (q + 1) : r8 * (q + 1) + (xcd - r8) * q) + pos;
    const int bm0 = (lin >> nxshift) * 128;
    const int bn0 = (lin & nxmask) * 128;

    const int tid  = threadIdx.x;
    const int lane = tid & 63;
    const int wid  = tid >> 6;
    const int wr   = wid >> 1;
    const int wc   = wid & 1;

    const int srow = tid >> 2;
    const int scol = ((tid & 3) ^ ((tid >> 3) & 3)) * 8;   // u16 units
    const size_t aoff0 = (size_t)(bm0 + srow) * K + scol;
    const size_t aoff1 = (size_t)(bm0 + srow + 64) * K + scol;
    const size_t boff0 = (size_t)(bn0 + srow) * K + scol;
    const size_t boff1 = (size_t)(bn0 + srow + 64) * K + scol;
    const int c0 = tid * 8;
    const int c1 = 2048 + tid * 8;

    u16* L0 = &lds[0][0][0];              // buffer stride 8192 u16

    f32x4 zero = {0.f, 0.f, 0.f, 0.f};
    f32x4 acc[4][4];
    #pragma unroll
    for (int i = 0; i < 4; ++i)
        #pragma unroll
        for (int j = 0; j < 4; ++j) acc[i][j] = zero;

    const int fchunk = (((lane >> 4) ^ ((lane >> 1) & 3))) * 8;
    const int a_fr = (wr * 64 + (lane & 15)) * 32 + fchunk;
    const int b_fr = (wc * 64 + (lane & 15)) * 32 + fchunk;

    const int nk = K >> 5;

    {
        u16* L = L0;
        gload16(Ah + aoff0, L + c0);          gload16(Ah + aoff1, L + c1);
        gload16(Bh + boff0, L + 4096 + c0);   gload16(Bh + boff1, L + 4096 + c1);
    }
    int cur = 0;
    for (int t = 0; t < nk; ++t) {
        if (t + 1 < nk) {
            const int k0 = (t + 1) * 32;
            u16* L = L0 + (cur ^ 1) * 8192;
            gload16(Ah + aoff0 + k0, L + c0);         gload16(Ah + aoff1 + k0, L + c1);
            gload16(Bh + boff0 + k0, L + 4096 + c0);  gload16(Bh + boff1 + k0, L + 4096 + c1);
            asm volatile("s_waitcnt vmcnt(4)\n\ts_barrier" ::: "memory");
        } else {
            asm volatile("s_waitcnt vmcnt(0)\n\ts_barrier" ::: "memory");
        }
        const u16* L = L0 + cur * 8192;
        s16x8 bh[4];
        #pragma unroll
        for (int nf = 0; nf < 4; ++nf)
            bh[nf] = *(const s16x8*)(L + 4096 + b_fr + nf * 512);
        #pragma unroll
        for (int mf = 0; mf < 4; ++mf) {
            s16x8 ahv = *(const s16x8*)(L + a_fr + mf * 512);
            #pragma unroll
            for (int nf = 0; nf < 4; ++nf)
                acc[mf][nf] = __builtin_amdgcn_mfma_f32_16x16x32_bf16(ahv, bh[nf], acc[mf][nf], 0, 0, 0);
        }
        asm volatile("s_barrier" ::: "memory");
        cur ^= 1;
    }

    #pragma unroll
    for (int mf = 0; mf < 4; ++mf) {
        const int row0 = bm0 + wr * 64 + mf * 16 + (lane >> 4) * 4;
        #pragma unroll
        for (int nf = 0; nf < 4; ++nf) {
            const int col = bn0 + wc * 64 + nf * 16 + (lane & 15);
            #pragma unroll
            for (int r = 0; r < 4; ++r)
                Y[(size_t)(row0 + r) * ldy + col] = f2bf(acc[mf][nf][r]);
        }
    }
}

// ---------------------------------------------------------------------------
// f32 [M][K] -> bf16 [Mpad][K], zero-padded rows. 8 elems/thread.
// ---------------------------------------------------------------------------
__global__ __launch_bounds__(256)
void cvt_bf16_kernel(const float* __restrict__ A, u16* __restrict__ Hh,
                     int M, int kshift)
{
    const size_t g  = (size_t)blockIdx.x * 256 + threadIdx.x;
    const size_t i8 = g * 8;
    const int row   = (int)(i8 >> kshift);
    f32x4 a = {0.f, 0.f, 0.f, 0.f}, b = {0.f, 0.f, 0.f, 0.f};
    if (row < M) {
        a = *(const f32x4*)(A + i8);
        b = *(const f32x4*)(A + i8 + 4);
    }
    u16x8 h;
    #pragma unroll
    for (int j = 0; j < 4; ++j) { h[j] = f2bf(a[j]); h[4 + j] = f2bf(b[j]); }
    *(u16x8*)(Hh + i8) = h;
}

__global__ __launch_bounds__(256)
void zero_u16_kernel(u16* __restrict__ a, int n)
{
    int i = blockIdx.x * 256 + threadIdx.x;
    if (i < n) a[i] = 0;
}

// ---------------------------------------------------------------------------
// CSR build (unchanged)
// ---------------------------------------------------------------------------
__global__ __launch_bounds__(256)
void zero2_i32_kernel(int* __restrict__ a, int na, int* __restrict__ b, int nb)
{
    int i = blockIdx.x * 256 + threadIdx.x;
    if (i < na) a[i] = 0;
    if (i < nb) b[i] = 0;
}

__global__ __launch_bounds__(256)
void hist2_kernel(const int* __restrict__ rowsR, const int* __restrict__ rowsP,
                  int* __restrict__ cntR, int* __restrict__ cntP,
                  int NR, int NP, int E)
{
    int s = blockIdx.y;
    int e = blockIdx.x * 256 + threadIdx.x;
    if (e >= E) return;
    if (blockIdx.z == 0) atomicAdd(cntR + s * NR + rowsR[(size_t)s * E + e], 1);
    else                 atomicAdd(cntP + s * NP + rowsP[(size_t)s * E + e], 1);
}

__global__ __launch_bounds__(256)
void scan_block2_kernel(const int* __restrict__ cR, int* __restrict__ rpR,
                        int* __restrict__ bsR, int NR, int np1R, int NBR,
                        const int* __restrict__ cP, int* __restrict__ rpP,
                        int* __restrict__ bsP, int NP, int np1P, int NBP)
{
    const int side = blockIdx.z;
    const int NB = side ? NBP : NBR;
    if ((int)blockIdx.x >= NB) return;
    const int N = side ? NP : NR;
    const int np1 = side ? np1P : np1R;
    const int* counts = side ? cP : cR;
    int* rowptr = side ? rpP : rpR;
    int* blocksum = side ? bsP : bsR;

    __shared__ int sd[256];
    int s = blockIdx.y;
    int i = blockIdx.x * 256 + threadIdx.x;
    int tid = threadIdx.x;
    int v = (i < N) ? counts[s * N + i] : 0;
    sd[tid] = v;
    __syncthreads();
    #pragma unroll
    for (int off = 1; off < 256; off <<= 1) {
        int t = (tid >= off) ? sd[tid - off] : 0;
        __syncthreads();
        sd[tid] += t;
        __syncthreads();
    }
    if (i < N) rowptr[s * np1 + i] = sd[tid] - v;
    if (tid == 255) blocksum[s * NB + blockIdx.x] = sd[255];
}

__global__ __launch_bounds__(256)
void scan_aux2_kernel(int* __restrict__ bsR, int NBR, int* __restrict__ bsP, int NBP)
{
    const int side = blockIdx.x >> 2;
    const int s = blockIdx.x & 3;
    int* blocksum = side ? bsP : bsR;
    const int NB = side ? NBP : NBR;

    __shared__ int sd[256];
    int tid = threadIdx.x;
    int v = (tid < NB) ? blocksum[s * NB + tid] : 0;
    sd[tid] = v;
    __syncthreads();
    #pragma unroll
    for (int off = 1; off < 256; off <<= 1) {
        int t = (tid >= off) ? sd[tid - off] : 0;
        __syncthreads();
        sd[tid] += t;
        __syncthreads();
    }
    if (tid < NB) blocksum[s * NB + tid] = sd[tid] - v;
}

__global__ __launch_bounds__(256)
void finalize2_kernel(int* __restrict__ rpR, const int* __restrict__ bsR,
                      int* __restrict__ curR, int NR, int np1R, int NBR,
                      int* __restrict__ rpP, const int* __restrict__ bsP,
                      int* __restrict__ curP, int NP, int np1P, int NBP, int E)
{
    const int side = blockIdx.z;
    const int NB = side ? NBP : NBR;
    if ((int)blockIdx.x >= NB) return;
    const int N = side ? NP : NR;
    const int np1 = side ? np1P : np1R;
    int* rowptr = side ? rpP : rpR;
    const int* blocksum = side ? bsP : bsR;
    int* cursor = side ? curP : curR;

    int s = blockIdx.y;
    int i = blockIdx.x * 256 + threadIdx.x;
    if (i < N) {
        int v = rowptr[s * np1 + i] + blocksum[s * NB + blockIdx.x];
        rowptr[s * np1 + i] = v;
        cursor[s * N + i] = v;
    }
    if (i == N) rowptr[s * np1 + N] = E;
}

// Row-sliced XCD-affine fill; cols/vals loaded only on slice match.
__global__ __launch_bounds__(256)
void fill_sliced_kernel(const int* __restrict__ rowsR, const int* __restrict__ colsR,
                        const float* __restrict__ valsR,
                        const int* __restrict__ rowsP, const int* __restrict__ colsP,
                        const float* __restrict__ valsP,
                        int* __restrict__ curR, int* __restrict__ curP,
                        int2* __restrict__ evR, int2* __restrict__ evP,
                        int NR, int NP, int E)
{
    const int slice = blockIdx.x & 7;
    const int chunk = blockIdx.x >> 3;
    const int s     = blockIdx.y;
    const int side  = blockIdx.z;
    const int N          = side ? NP : NR;
    const int* rows      = side ? rowsP : rowsR;
    const int* cols      = side ? colsP : colsR;
    const float* vals    = side ? valsP : valsR;
    int* cursor          = side ? curP : curR;
    int2* ev             = side ? evP : evR;

    const int Nsl = (N + 7) >> 3;
    const int r0 = slice * Nsl;
    const int r1 = min(N, r0 + Nsl);

    const int e0 = chunk * 1024 + threadIdx.x * 4;
    if (e0 >= E) return;
    const size_t base = (size_t)s * E;

    if (e0 + 4 <= E) {
        int4 r4 = *(const int4*)(rows + base + e0);
        int rr[4] = {r4.x, r4.y, r4.z, r4.w};
        #pragma unroll
        for (int j = 0; j < 4; ++j) {
            if (rr[j] >= r0 && rr[j] < r1) {
                int pos = atomicAdd(cursor + s * N + rr[j], 1);
                ev[base + pos] = make_int2(cols[base + e0 + j],
                                           __float_as_int(vals[base + e0 + j]));
            }
        }
    } else {
        for (int j = 0; j < 4 && e0 + j < E; ++j) {
            int r = rows[base + e0 + j];
            if (r >= r0 && r < r1) {
                int pos = atomicAdd(cursor + s * N + r, 1);
                ev[base + pos] = make_int2(cols[base + e0 + j],
                                           __float_as_int(vals[base + e0 + j]));
            }
        }
    }
}

// ---------------------------------------------------------------------------
// CSR SpMM, quarter/eighth-wave edge parallelism.
// KCH=128: 16 lanes/edge (u16x8), 4 edges per load instruction, unroll 2.
// KCH=64 :  8 lanes/edge (u16x8), 8 edges per load instruction, unroll 2.
// Combine via shfl_xor(8/16/32); low lanes write.
// MODE 0: Base(bf16) += acc | MODE 1: OH = bf16(relu(Base+acc))
// MODE 2: OF = relu(Base+acc) (f32)
// ---------------------------------------------------------------------------
template<int KCH, int MODE>
__global__ __launch_bounds__(256)
void spmm2_kernel(const int* __restrict__ rpR, const int* __restrict__ rpP,
                  int np1R, int np1P,
                  const int2* __restrict__ evRg, const int2* __restrict__ evPg,
                  const u16* __restrict__ InR, const u16* __restrict__ InP, int ldi,
                  u16* __restrict__ BaseR, u16* __restrict__ BaseP, int ldb,
                  u16* __restrict__ OHR, u16* __restrict__ OHP,
                  float* __restrict__ OFR, float* __restrict__ OFP, int ldo,
                  int NR, int E)
{
    int r = blockIdx.x;
    const int s    = threadIdx.x >> 6;
    const int lane = threadIdx.x & 63;
    const int* rp; const int2* ev; const u16* In; u16* Base; int np1;
    u16* OH; float* OF;
    if (r < NR) { rp = rpR; ev = evRg; In = InR; Base = BaseR; np1 = np1R;
                  OH = OHR; OF = OFR; }
    else { r -= NR; rp = rpP; ev = evPg; In = InP; Base = BaseP; np1 = np1P;
           OH = OHP; OF = OFP; }
    int e0 = __builtin_amdgcn_readfirstlane(rp[s * np1 + r]);
    int e1 = __builtin_amdgcn_readfirstlane(rp[s * np1 + r + 1]);
    if (MODE == 0 && e0 == e1) return;
    ev += (size_t)s * E;

    if (KCH == 128) {
        const int qg = lane >> 4;             // edge within group (0..3)
        const int ql = lane & 15;
        const int col = s * 128 + ql * 8;     // 8 cols/lane, 16 lanes = 128
        float a[8] = {0.f, 0.f, 0.f, 0.f, 0.f, 0.f, 0.f, 0.f};
        int e = e0;
        for (; e + 7 < e1; e += 8) {          // 2 groups -> 8 gathers in flight
            int2 p0 = ev[e + qg];
            int2 p1 = ev[e + 4 + qg];
            float v0 = __int_as_float(p0.y);
            float v1 = __int_as_float(p1.y);
            u16x8 x0 = *(const u16x8*)(In + (size_t)p0.x * ldi + col);
            u16x8 x1 = *(const u16x8*)(In + (size_t)p1.x * ldi + col);
            #pragma unroll
            for (int j = 0; j < 8; ++j)
                a[j] += v0 * bf2f(x0[j]) + v1 * bf2f(x1[j]);
        }
        for (; e < e1; e += 4) {              // guarded tail groups
            if (e + qg < e1) {
                int2 pv = ev[e + qg];
                float v = __int_as_float(pv.y);
                u16x8 x = *(const u16x8*)(In + (size_t)pv.x * ldi + col);
                #pragma unroll
                for (int j = 0; j < 8; ++j)
                    a[j] += v * bf2f(x[j]);
            }
        }
        #pragma unroll
        for (int j = 0; j < 8; ++j) {
            a[j] += __shfl_xor(a[j], 16);
            a[j] += __shfl_xor(a[j], 32);
        }
        if (lane < 16) {
            u16x8* bp = (u16x8*)(Base + (size_t)r * ldb + col);
            u16x8 b = *bp;
            if (MODE == 0) {
                u16x8 nb;
                #pragma unroll
                for (int j = 0; j < 8; ++j) nb[j] = f2bf(bf2f(b[j]) + a[j]);
                *bp = nb;
            } else if (MODE == 1) {
                u16x8 h;
                #pragma unroll
                for (int j = 0; j < 8; ++j) h[j] = f2bf(fmaxf(bf2f(b[j]) + a[j], 0.f));
                *(u16x8*)(OH + (size_t)r * ldo + col) = h;
            } else {
                f32x4 o0, o1;
                #pragma unroll
                for (int j = 0; j < 4; ++j) {
                    o0[j] = fmaxf(bf2f(b[j]) + a[j], 0.f);
                    o1[j] = fmaxf(bf2f(b[4 + j]) + a[4 + j], 0.f);
                }
                *(f32x4*)(OF + (size_t)r * ldo + col) = o0;
                *(f32x4*)(OF + (size_t)r * ldo + col + 4) = o1;
            }
        }
    } else {   // KCH == 64
        const int og = lane >> 3;             // edge within group (0..7)
        const int ol = lane & 7;
        const int col = s * 64 + ol * 8;      // 8 cols/lane, 8 lanes = 64
        float a[8] = {0.f, 0.f, 0.f, 0.f, 0.f, 0.f, 0.f, 0.f};
        int e = e0;
        for (; e + 15 < e1; e += 16) {        // 2 groups -> 16 edges in flight
            int2 p0 = ev[e + og];
            int2 p1 = ev[e + 8 + og];
            float v0 = __int_as_float(p0.y);
            float v1 = __int_as_float(p1.y);
            u16x8 x0 = *(const u16x8*)(In + (size_t)p0.x * ldi + col);
            u16x8 x1 = *(const u16x8*)(In + (size_t)p1.x * ldi + col);
            #pragma unroll
            for (int j = 0; j < 8; ++j)
                a[j] += v0 * bf2f(x0[j]) + v1 * bf2f(x1[j]);
        }
        for (; e < e1; e += 8) {              // guarded tail groups
            if (e + og < e1) {
                int2 pv = ev[e + og];
                float v = __int_as_float(pv.y);
                u16x8 x = *(const u16x8*)(In + (size_t)pv.x * ldi + col);
                #pragma unroll
                for (int j = 0; j < 8; ++j)
                    a[j] += v * bf2f(x[j]);
            }
        }
        #pragma unroll
        for (int j = 0; j < 8; ++j) {
            a[j] += __shfl_xor(a[j], 8);
            a[j] += __shfl_xor(a[j], 16);
            a[j] += __shfl_xor(a[j], 32);
        }
        if (lane < 8) {
            u16x8* bp = (u16x8*)(Base + (size_t)r * ldb + col);
            u16x8 b = *bp;
            if (MODE == 0) {
                u16x8 nb;
                #pragma unroll
                for (int j = 0; j < 8; ++j) nb[j] = f2bf(bf2f(b[j]) + a[j]);
                *bp = nb;
            } else {
                f32x4 o0, o1;
                #pragma unroll
                for (int j = 0; j < 4; ++j) {
                    o0[j] = fmaxf(bf2f(b[j]) + a[j], 0.f);
                    o1[j] = fmaxf(bf2f(b[4 + j]) + a[4 + j], 0.f);
                }
                *(f32x4*)(OF + (size_t)r * ldo + col) = o0;
                *(f32x4*)(OF + (size_t)r * ldo + col + 4) = o1;
            }
        }
    }
}

// fallback-only final relu over bf16 base
__global__ __launch_bounds__(256)
void relu_out_kernel(const u16* __restrict__ Z, int ld, int coff,
                     float* __restrict__ out, int M)
{
    int g = blockIdx.x * 256 + threadIdx.x;
    if (g >= M * 256) return;
    int row = g >> 8;
    int col = g & 255;
    out[g] = fmaxf(bf2f(Z[(size_t)row * ld + coff + col]), 0.f);
}

// ---------------------------------------------------------------------------
// weight packing (transposed [N][K], bf16)
// ---------------------------------------------------------------------------
__global__ __launch_bounds__(256)
void pack_b0_kernel(const float* __restrict__ w0, const float* __restrict__ sw0,
                    u16* __restrict__ Bh)
{
    int g = blockIdx.x * 256 + threadIdx.x;
    int j = g >> 10, d = g & 1023;
    float v;
    if (j < 512) v = w0[((size_t)(j >> 7) * 1024 + d) * 128 + (j & 127)];
    else         v = sw0[(size_t)d * 512 + (j - 512)];
    Bh[g] = f2bf(v);
}

__global__ __launch_bounds__(256)
void pack_b1_kernel(const float* __restrict__ w1, const float* __restrict__ sw1,
                    u16* __restrict__ Bh)
{
    int g = blockIdx.x * 256 + threadIdx.x;
    int j = g >> 9, d = g & 511;
    float v;
    if (j < 256) v = w1[((size_t)(j >> 6) * 512 + d) * 64 + (j & 63)];
    else         v = sw1[(size_t)d * 256 + (j - 256)];
    Bh[g] = f2bf(v);
}

extern "C" void kernel_launch(void* const* d_in, const int* in_sizes, int n_in,
                              void* d_out, int out_size, void* d_ws, size_t ws_size,
                              hipStream_t stream)
{
    const int*   rna_rows  = (const int*)  d_in[0];
    const int*   rna_cols  = (const int*)  d_in[1];
    const float* rna_vals  = (const float*)d_in[2];
    const int*   prot_rows = (const int*)  d_in[3];
    const int*   prot_cols = (const int*)  d_in[4];
    const float* prot_vals = (const float*)d_in[5];
    const float* H_rna     = (const float*)d_in[6];
    const float* H_prot    = (const float*)d_in[7];
    const float* w0        = (const float*)d_in[8];
    const float* sw0       = (const float*)d_in[9];
    const float* w1        = (const float*)d_in[10];
    const float* sw1       = (const float*)d_in[11];

    const int NRNA = 50000, NPROT = 20000, S = 4, E = 500000;
    const int MP_RNA = 50048, MP_PROT = 20096;
    const int MP_ALL = MP_RNA + MP_PROT;           // 70144 = 548 * 128
    const int NP1_R = NRNA + 1, NP1_P = NPROT + 1;
    const int NB_R = (NRNA + 255) / 256;
    const int NB_P = (NPROT + 255) / 256;
    const int EB   = (E + 255) / 256;
    const int EB4  = (E + 1023) / 1024;

    // --- ws layout ---
    char* ws = (char*)d_ws;
    size_t off = 0;
    u16*   Y16   = (u16*)  (ws + off); off += (size_t)MP_ALL * 1024 * 2;  // L0 [*,1024]; L1 aliases [*,512]
    u16*   Ahbig = (u16*)  (ws + off); off += (size_t)MP_ALL * 1024 * 2;
    u16*   B0h   = (u16*)  (ws + off); off += (size_t)1024 * 1024 * 2;
    u16*   B1h   = (u16*)  (ws + off); off += (size_t)512 * 512 * 2;
    size_t base_bytes = off;

    u16* AhR = Ahbig;                               // layer-1 A views [MP_ALL][512]
    u16* AhP = Ahbig + (size_t)MP_RNA * 512;

    // CSR scratch
    size_t csr_bytes = 0;
    csr_bytes += (size_t)S * E * 8 * 2;
    csr_bytes += ((size_t)S * (NRNA * 2 + NP1_R + NB_R)) * 4;
    csr_bytes += ((size_t)S * (NPROT * 2 + NP1_P + NB_P)) * 4;
    const bool csr_in_ws = (ws_size >= base_bytes + csr_bytes);

    char* csr = csr_in_ws ? (ws + base_bytes) : (char*)d_out;
    size_t coff = 0;
    int2*  evR     = (int2*) (csr + coff); coff += (size_t)S * E * 8;
    int2*  evP     = (int2*) (csr + coff); coff += (size_t)S * E * 8;
    int*   countsR = (int*)  (csr + coff); coff += (size_t)S * NRNA * 4;
    int*   rowptrR = (int*)  (csr + coff); coff += (size_t)S * NP1_R * 4;
    int*   cursorR = (int*)  (csr + coff); coff += (size_t)S * NRNA * 4;
    int*   bsumR   = (int*)  (csr + coff); coff += (size_t)S * NB_R * 4;
    int*   countsP = (int*)  (csr + coff); coff += (size_t)S * NPROT * 4;
    int*   rowptrP = (int*)  (csr + coff); coff += (size_t)S * NP1_P * 4;
    int*   cursorP = (int*)  (csr + coff); coff += (size_t)S * NPROT * 4;
    int*   bsumP   = (int*)  (csr + coff); coff += (size_t)S * NB_P * 4;

    dim3 blk(256);
    float* out = (float*)d_out;

    // --- pack weights ---
    pack_b0_kernel<<<(1024 * 1024) / 256, blk, 0, stream>>>(w0, sw0, B0h);
    pack_b1_kernel<<<(512 * 512) / 256, blk, 0, stream>>>(w1, sw1, B1h);

    // --- CSR build ---
    zero2_i32_kernel<<<(S * NRNA + 255) / 256, blk, 0, stream>>>(countsR, S * NRNA,
                                                                 countsP, S * NPROT);
    hist2_kernel<<<dim3(EB, S, 2), blk, 0, stream>>>(rna_rows, prot_rows,
                                                     countsR, countsP, NRNA, NPROT, E);
    scan_block2_kernel<<<dim3(NB_R, S, 2), blk, 0, stream>>>(
        countsR, rowptrR, bsumR, NRNA, NP1_R, NB_R,
        countsP, rowptrP, bsumP, NPROT, NP1_P, NB_P);
    scan_aux2_kernel<<<8, blk, 0, stream>>>(bsumR, NB_R, bsumP, NB_P);
    finalize2_kernel<<<dim3(NB_R, S, 2), blk, 0, stream>>>(
        rowptrR, bsumR, cursorR, NRNA, NP1_R, NB_R,
        rowptrP, bsumP, cursorP, NPROT, NP1_P, NB_P, E);
    fill_sliced_kernel<<<dim3(EB4 * 8, S, 2), blk, 0, stream>>>(
        rna_rows, rna_cols, rna_vals, prot_rows, prot_cols, prot_vals,
        cursorR, cursorP, evR, evP, NRNA, NPROT, E);

    // --- layer 0: cvt + one GEMM (N=K=1024, all-bf16 out) ---
    cvt_bf16_kernel<<<MP_RNA / 2, blk, 0, stream>>>(H_rna, Ahbig, NRNA, 10);
    cvt_bf16_kernel<<<MP_PROT / 2, blk, 0, stream>>>(H_prot, Ahbig + (size_t)MP_RNA * 1024,
                                                     NPROT, 10);
    gemm_bf16_kernel<<<8 * (MP_ALL / 128), blk, 0, stream>>>(
        Ahbig, B0h, Y16, 1024, 1024, 7, 3);

    // --- layer 0 SpMM: Ah = bf16(relu(base + agg)) ---
    spmm2_kernel<128, 1><<<NRNA + NPROT, blk, 0, stream>>>(
        rowptrR, rowptrP, NP1_R, NP1_P, evR, evP,
        Y16 + (size_t)MP_RNA * 1024,      // RNA gathers prot tmp (cols 0..511)
        Y16,                              // PROT gathers rna tmp
        1024,
        Y16 + 512, Y16 + (size_t)MP_RNA * 1024 + 512, 1024,   // bf16 base halves
        AhR, AhP, nullptr, nullptr, 512,
        NRNA, E);

    // --- zero layer-1 A pad rows ---
    zero_u16_kernel<<<(48 * 512 + 255) / 256, blk, 0, stream>>>(
        AhR + (size_t)NRNA * 512, 48 * 512);
    zero_u16_kernel<<<(96 * 512 + 255) / 256, blk, 0, stream>>>(
        AhP + (size_t)NPROT * 512, 96 * 512);

    // --- layer 1: one GEMM (N=K=512), Y16_1 aliases Y16 [MP_ALL][512] ---
    gemm_bf16_kernel<<<4 * (MP_ALL / 128), blk, 0, stream>>>(
        Ahbig, B1h, Y16, 512, 512, 3, 2);

    // --- layer 1 SpMM ---
    if (csr_in_ws) {
        spmm2_kernel<64, 2><<<NRNA + NPROT, blk, 0, stream>>>(
            rowptrR, rowptrP, NP1_R, NP1_P, evR, evP,
            Y16 + (size_t)MP_RNA * 512, Y16, 512,
            Y16 + 256, Y16 + (size_t)MP_RNA * 512 + 256, 512,
            nullptr, nullptr,
            out, out + (size_t)NRNA * 256, 256,
            NRNA, E);
    } else {
        spmm2_kernel<64, 0><<<NRNA + NPROT, blk, 0, stream>>>(
            rowptrR, rowptrP, NP1_R, NP1_P, evR, evP,
            Y16 + (size_t)MP_RNA * 512, Y16, 512,
            Y16 + 256, Y16 + (size_t)MP_RNA * 512 + 256, 512,
            nullptr, nullptr,
            nullptr, nullptr, 0,
            NRNA, E);
        relu_out_kernel<<<(NRNA * 256) / 256, blk, 0, stream>>>(Y16, 512, 256, out, NRNA);
        relu_out_kernel<<<(NPROT * 256) / 256, blk, 0, stream>>>(
            Y16 + (size_t)MP_RNA * 512, 512, 256, out + (size_t)NRNA * 256, NPROT);
    }
}

// Round 18
// 990.279 us; speedup vs baseline: 1.6151x; 1.0025x over previous
//
#include <hip/hip_runtime.h>
#include <hip/hip_bf16.h>

// ---------------------------------------------------------------------------
// StackGCNEncoder on MI355X — round 18:
//   fill: (1) NON-TEMPORAL loads for streamed edge arrays (rows/cols/vals)
//         -> streams stop evicting partially-written ev lines from L2,
//         write amplification drops toward payload;
//         (2) rows packed to u16 once (ids < 65536) -> 8x re-scan reads
//         half the bytes; hist reads packed rows too.
//   Everything else identical to round 17 (quarter/eighth-wave spmm,
//   all-bf16 Y, 1-term GEMM, counted-vmcnt, XOR swizzle).
// ---------------------------------------------------------------------------

typedef unsigned short u16;
typedef short s16x8 __attribute__((ext_vector_type(8)));
typedef float f32x4 __attribute__((ext_vector_type(4)));
typedef __attribute__((ext_vector_type(8))) unsigned short u16x8;
typedef __attribute__((ext_vector_type(2))) unsigned short u16x2;
typedef unsigned long long u64;

__device__ __forceinline__ u16 f2bf(float x) {            // RNE f32->bf16
    unsigned u = __float_as_uint(x);
    return (u16)((u + 0x7fff + ((u >> 16) & 1)) >> 16);
}
__device__ __forceinline__ float bf2f(u16 h) {
    return __uint_as_float(((unsigned)h) << 16);
}

__device__ __forceinline__ void gload16(const u16* g, u16* l) {
    __builtin_amdgcn_global_load_lds(
        (const __attribute__((address_space(1))) unsigned int*)g,
        (__attribute__((address_space(3))) unsigned int*)l,
        16, 0, 0);
}

// ---------------------------------------------------------------------------
// bf16 GEMM (unchanged): Y16 = A x B^T, all-bf16 out. 128x128, BK=32.
// ---------------------------------------------------------------------------
__global__ __launch_bounds__(256)
void gemm_bf16_kernel(const u16* __restrict__ Ah, const u16* __restrict__ Bh,
                      u16* __restrict__ Y, int ldy,
                      int K, int nxmask, int nxshift)
{
    __shared__ u16 lds[2][2][4096];   // 32 KB

    const int nwg = gridDim.x;
    const int q   = nwg >> 3, r8 = nwg & 7;
    const int xcd = blockIdx.x & 7, pos = blockIdx.x >> 3;
    const int lin = (xcd < r8 ? xcd * (q + 1) : r8 * (q + 1) + (xcd - r8) * q) + pos;
    const int bm0 = (lin >> nxshift) * 128;
    const int bn0 = (lin & nxmask) * 128;

    const int tid  = threadIdx.x;
    const int lane = tid & 63;
    const int wid  = tid >> 6;
    const int wr   = wid >> 1;
    const int wc   = wid & 1;

    const int srow = tid >> 2;
    const int scol = ((tid & 3) ^ ((tid >> 3) & 3)) * 8;   // u16 units
    const size_t aoff0 = (size_t)(bm0 + srow) * K + scol;
    const size_t aoff1 = (size_t)(bm0 + srow + 64) * K + scol;
    const size_t boff0 = (size_t)(bn0 + srow) * K + scol;
    const size_t boff1 = (size_t)(bn0 + srow + 64) * K + scol;
    const int c0 = tid * 8;
    const int c1 = 2048 + tid * 8;

    u16* L0 = &lds[0][0][0];              // buffer stride 8192 u16

    f32x4 zero = {0.f, 0.f, 0.f, 0.f};
    f32x4 acc[4][4];
    #pragma unroll
    for (int i = 0; i < 4; ++i)
        #pragma unroll
        for (int j = 0; j < 4; ++j) acc[i][j] = zero;

    const int fchunk = (((lane >> 4) ^ ((lane >> 1) & 3))) * 8;
    const int a_fr = (wr * 64 + (lane & 15)) * 32 + fchunk;
    const int b_fr = (wc * 64 + (lane & 15)) * 32 + fchunk;

    const int nk = K >> 5;

    {
        u16* L = L0;
        gload16(Ah + aoff0, L + c0);          gload16(Ah + aoff1, L + c1);
        gload16(Bh + boff0, L + 4096 + c0);   gload16(Bh + boff1, L + 4096 + c1);
    }
    int cur = 0;
    for (int t = 0; t < nk; ++t) {
        if (t + 1 < nk) {
            const int k0 = (t + 1) * 32;
            u16* L = L0 + (cur ^ 1) * 8192;
            gload16(Ah + aoff0 + k0, L + c0);         gload16(Ah + aoff1 + k0, L + c1);
            gload16(Bh + boff0 + k0, L + 4096 + c0);  gload16(Bh + boff1 + k0, L + 4096 + c1);
            asm volatile("s_waitcnt vmcnt(4)\n\ts_barrier" ::: "memory");
        } else {
            asm volatile("s_waitcnt vmcnt(0)\n\ts_barrier" ::: "memory");
        }
        const u16* L = L0 + cur * 8192;
        s16x8 bh[4];
        #pragma unroll
        for (int nf = 0; nf < 4; ++nf)
            bh[nf] = *(const s16x8*)(L + 4096 + b_fr + nf * 512);
        #pragma unroll
        for (int mf = 0; mf < 4; ++mf) {
            s16x8 ahv = *(const s16x8*)(L + a_fr + mf * 512);
            #pragma unroll
            for (int nf = 0; nf < 4; ++nf)
                acc[mf][nf] = __builtin_amdgcn_mfma_f32_16x16x32_bf16(ahv, bh[nf], acc[mf][nf], 0, 0, 0);
        }
        asm volatile("s_barrier" ::: "memory");
        cur ^= 1;
    }

    #pragma unroll
    for (int mf = 0; mf < 4; ++mf) {
        const int row0 = bm0 + wr * 64 + mf * 16 + (lane >> 4) * 4;
        #pragma unroll
        for (int nf = 0; nf < 4; ++nf) {
            const int col = bn0 + wc * 64 + nf * 16 + (lane & 15);
            #pragma unroll
            for (int r = 0; r < 4; ++r)
                Y[(size_t)(row0 + r) * ldy + col] = f2bf(acc[mf][nf][r]);
        }
    }
}

// ---------------------------------------------------------------------------
// f32 [M][K] -> bf16 [Mpad][K], zero-padded rows. 8 elems/thread.
// ---------------------------------------------------------------------------
__global__ __launch_bounds__(256)
void cvt_bf16_kernel(const float* __restrict__ A, u16* __restrict__ Hh,
                     int M, int kshift)
{
    const size_t g  = (size_t)blockIdx.x * 256 + threadIdx.x;
    const size_t i8 = g * 8;
    const int row   = (int)(i8 >> kshift);
    f32x4 a = {0.f, 0.f, 0.f, 0.f}, b = {0.f, 0.f, 0.f, 0.f};
    if (row < M) {
        a = *(const f32x4*)(A + i8);
        b = *(const f32x4*)(A + i8 + 4);
    }
    u16x8 h;
    #pragma unroll
    for (int j = 0; j < 4; ++j) { h[j] = f2bf(a[j]); h[4 + j] = f2bf(b[j]); }
    *(u16x8*)(Hh + i8) = h;
}

__global__ __launch_bounds__(256)
void zero_u16_kernel(u16* __restrict__ a, int n)
{
    int i = blockIdx.x * 256 + threadIdx.x;
    if (i < n) a[i] = 0;
}

// ---------------------------------------------------------------------------
// CSR build
// ---------------------------------------------------------------------------
__global__ __launch_bounds__(256)
void zero2_i32_kernel(int* __restrict__ a, int na, int* __restrict__ b, int nb)
{
    int i = blockIdx.x * 256 + threadIdx.x;
    if (i < na) a[i] = 0;
    if (i < nb) b[i] = 0;
}

// pack rows int32 -> u16 (ids < 65536), both sides via z
__global__ __launch_bounds__(256)
void pack_rows2_kernel(const int* __restrict__ rowsR, const int* __restrict__ rowsP,
                       u16* __restrict__ r16R, u16* __restrict__ r16P, int E)
{
    int s = blockIdx.y;
    int e = (blockIdx.x * 256 + threadIdx.x) * 4;
    if (e >= E) return;
    const int* rows = blockIdx.z ? rowsP : rowsR;
    u16* r16 = blockIdx.z ? r16P : r16R;
    size_t base = (size_t)s * E;
    if (e + 4 <= E) {
        int4 r4 = *(const int4*)(rows + base + e);
        u16 p[4] = {(u16)r4.x, (u16)r4.y, (u16)r4.z, (u16)r4.w};
        *(u64*)(r16 + base + e) = *(const u64*)p;
    } else {
        for (int j = 0; j < 4 && e + j < E; ++j)
            r16[base + e + j] = (u16)rows[base + e + j];
    }
}

__global__ __launch_bounds__(256)
void hist2_kernel(const u16* __restrict__ rowsR, const u16* __restrict__ rowsP,
                  int* __restrict__ cntR, int* __restrict__ cntP,
                  int NR, int NP, int E)
{
    int s = blockIdx.y;
    int e = blockIdx.x * 256 + threadIdx.x;
    if (e >= E) return;
    if (blockIdx.z == 0) atomicAdd(cntR + s * NR + (int)rowsR[(size_t)s * E + e], 1);
    else                 atomicAdd(cntP + s * NP + (int)rowsP[(size_t)s * E + e], 1);
}

__global__ __launch_bounds__(256)
void scan_block2_kernel(const int* __restrict__ cR, int* __restrict__ rpR,
                        int* __restrict__ bsR, int NR, int np1R, int NBR,
                        const int* __restrict__ cP, int* __restrict__ rpP,
                        int* __restrict__ bsP, int NP, int np1P, int NBP)
{
    const int side = blockIdx.z;
    const int NB = side ? NBP : NBR;
    if ((int)blockIdx.x >= NB) return;
    const int N = side ? NP : NR;
    const int np1 = side ? np1P : np1R;
    const int* counts = side ? cP : cR;
    int* rowptr = side ? rpP : rpR;
    int* blocksum = side ? bsP : bsR;

    __shared__ int sd[256];
    int s = blockIdx.y;
    int i = blockIdx.x * 256 + threadIdx.x;
    int tid = threadIdx.x;
    int v = (i < N) ? counts[s * N + i] : 0;
    sd[tid] = v;
    __syncthreads();
    #pragma unroll
    for (int off = 1; off < 256; off <<= 1) {
        int t = (tid >= off) ? sd[tid - off] : 0;
        __syncthreads();
        sd[tid] += t;
        __syncthreads();
    }
    if (i < N) rowptr[s * np1 + i] = sd[tid] - v;
    if (tid == 255) blocksum[s * NB + blockIdx.x] = sd[255];
}

__global__ __launch_bounds__(256)
void scan_aux2_kernel(int* __restrict__ bsR, int NBR, int* __restrict__ bsP, int NBP)
{
    const int side = blockIdx.x >> 2;
    const int s = blockIdx.x & 3;
    int* blocksum = side ? bsP : bsR;
    const int NB = side ? NBP : NBR;

    __shared__ int sd[256];
    int tid = threadIdx.x;
    int v = (tid < NB) ? blocksum[s * NB + tid] : 0;
    sd[tid] = v;
    __syncthreads();
    #pragma unroll
    for (int off = 1; off < 256; off <<= 1) {
        int t = (tid >= off) ? sd[tid - off] : 0;
        __syncthreads();
        sd[tid] += t;
        __syncthreads();
    }
    if (tid < NB) blocksum[s * NB + tid] = sd[tid] - v;
}

__global__ __launch_bounds__(256)
void finalize2_kernel(int* __restrict__ rpR, const int* __restrict__ bsR,
                      int* __restrict__ curR, int NR, int np1R, int NBR,
                      int* __restrict__ rpP, const int* __restrict__ bsP,
                      int* __restrict__ curP, int NP, int np1P, int NBP, int E)
{
    const int side = blockIdx.z;
    const int NB = side ? NBP : NBR;
    if ((int)blockIdx.x >= NB) return;
    const int N = side ? NP : NR;
    const int np1 = side ? np1P : np1R;
    int* rowptr = side ? rpP : rpR;
    const int* blocksum = side ? bsP : bsR;
    int* cursor = side ? curP : curR;

    int s = blockIdx.y;
    int i = blockIdx.x * 256 + threadIdx.x;
    if (i < N) {
        int v = rowptr[s * np1 + i] + blocksum[s * NB + blockIdx.x];
        rowptr[s * np1 + i] = v;
        cursor[s * N + i] = v;
    }
    if (i == N) rowptr[s * np1 + N] = E;
}

// Row-sliced XCD-affine fill; u16 rows + non-temporal streamed loads.
__global__ __launch_bounds__(256)
void fill_sliced_kernel(const u16* __restrict__ r16R, const int* __restrict__ colsR,
                        const float* __restrict__ valsR,
                        const u16* __restrict__ r16P, const int* __restrict__ colsP,
                        const float* __restrict__ valsP,
                        int* __restrict__ curR, int* __restrict__ curP,
                        int2* __restrict__ evR, int2* __restrict__ evP,
                        int NR, int NP, int E)
{
    const int slice = blockIdx.x & 7;
    const int chunk = blockIdx.x >> 3;
    const int s     = blockIdx.y;
    const int side  = blockIdx.z;
    const int N          = side ? NP : NR;
    const u16* r16       = side ? r16P : r16R;
    const int* cols      = side ? colsP : colsR;
    const float* vals    = side ? valsP : valsR;
    int* cursor          = side ? curP : curR;
    int2* ev             = side ? evP : evR;

    const int Nsl = (N + 7) >> 3;
    const int r0 = slice * Nsl;
    const int r1 = min(N, r0 + Nsl);

    const int e0 = chunk * 1024 + threadIdx.x * 4;
    if (e0 >= E) return;
    const size_t base = (size_t)s * E;

    if (e0 + 4 <= E) {
        u64 rq = __builtin_nontemporal_load((const u64*)(r16 + base + e0));
        int rr[4] = {(int)(u16)rq, (int)(u16)(rq >> 16),
                     (int)(u16)(rq >> 32), (int)(u16)(rq >> 48)};
        #pragma unroll
        for (int j = 0; j < 4; ++j) {
            if (rr[j] >= r0 && rr[j] < r1) {
                int   c = __builtin_nontemporal_load(cols + base + e0 + j);
                float v = __builtin_nontemporal_load(vals + base + e0 + j);
                int pos = atomicAdd(cursor + s * N + rr[j], 1);
                ev[base + pos] = make_int2(c, __float_as_int(v));
            }
        }
    } else {
        for (int j = 0; j < 4 && e0 + j < E; ++j) {
            int r = (int)r16[base + e0 + j];
            if (r >= r0 && r < r1) {
                int pos = atomicAdd(cursor + s * N + r, 1);
                ev[base + pos] = make_int2(cols[base + e0 + j],
                                           __float_as_int(vals[base + e0 + j]));
            }
        }
    }
}

// ---------------------------------------------------------------------------
// CSR SpMM, quarter/eighth-wave edge parallelism (round 17, unchanged).
// ---------------------------------------------------------------------------
template<int KCH, int MODE>
__global__ __launch_bounds__(256)
void spmm2_kernel(const int* __restrict__ rpR, const int* __restrict__ rpP,
                  int np1R, int np1P,
                  const int2* __restrict__ evRg, const int2* __restrict__ evPg,
                  const u16* __restrict__ InR, const u16* __restrict__ InP, int ldi,
                  u16* __restrict__ BaseR, u16* __restrict__ BaseP, int ldb,
                  u16* __restrict__ OHR, u16* __restrict__ OHP,
                  float* __restrict__ OFR, float* __restrict__ OFP, int ldo,
                  int NR, int E)
{
    int r = blockIdx.x;
    const int s    = threadIdx.x >> 6;
    const int lane = threadIdx.x & 63;
    const int* rp; const int2* ev; const u16* In; u16* Base; int np1;
    u16* OH; float* OF;
    if (r < NR) { rp = rpR; ev = evRg; In = InR; Base = BaseR; np1 = np1R;
                  OH = OHR; OF = OFR; }
    else { r -= NR; rp = rpP; ev = evPg; In = InP; Base = BaseP; np1 = np1P;
           OH = OHP; OF = OFP; }
    int e0 = __builtin_amdgcn_readfirstlane(rp[s * np1 + r]);
    int e1 = __builtin_amdgcn_readfirstlane(rp[s * np1 + r + 1]);
    if (MODE == 0 && e0 == e1) return;
    ev += (size_t)s * E;

    if (KCH == 128) {
        const int qg = lane >> 4;             // edge within group (0..3)
        const int ql = lane & 15;
        const int col = s * 128 + ql * 8;     // 8 cols/lane, 16 lanes = 128
        float a[8] = {0.f, 0.f, 0.f, 0.f, 0.f, 0.f, 0.f, 0.f};
        int e = e0;
        for (; e + 7 < e1; e += 8) {          // 2 groups -> 8 gathers in flight
            int2 p0 = ev[e + qg];
            int2 p1 = ev[e + 4 + qg];
            float v0 = __int_as_float(p0.y);
            float v1 = __int_as_float(p1.y);
            u16x8 x0 = *(const u16x8*)(In + (size_t)p0.x * ldi + col);
            u16x8 x1 = *(const u16x8*)(In + (size_t)p1.x * ldi + col);
            #pragma unroll
            for (int j = 0; j < 8; ++j)
                a[j] += v0 * bf2f(x0[j]) + v1 * bf2f(x1[j]);
        }
        for (; e < e1; e += 4) {              // guarded tail groups
            if (e + qg < e1) {
                int2 pv = ev[e + qg];
                float v = __int_as_float(pv.y);
                u16x8 x = *(const u16x8*)(In + (size_t)pv.x * ldi + col);
                #pragma unroll
                for (int j = 0; j < 8; ++j)
                    a[j] += v * bf2f(x[j]);
            }
        }
        #pragma unroll
        for (int j = 0; j < 8; ++j) {
            a[j] += __shfl_xor(a[j], 16);
            a[j] += __shfl_xor(a[j], 32);
        }
        if (lane < 16) {
            u16x8* bp = (u16x8*)(Base + (size_t)r * ldb + col);
            u16x8 b = *bp;
            if (MODE == 0) {
                u16x8 nb;
                #pragma unroll
                for (int j = 0; j < 8; ++j) nb[j] = f2bf(bf2f(b[j]) + a[j]);
                *bp = nb;
            } else if (MODE == 1) {
                u16x8 h;
                #pragma unroll
                for (int j = 0; j < 8; ++j) h[j] = f2bf(fmaxf(bf2f(b[j]) + a[j], 0.f));
                *(u16x8*)(OH + (size_t)r * ldo + col) = h;
            } else {
                f32x4 o0, o1;
                #pragma unroll
                for (int j = 0; j < 4; ++j) {
                    o0[j] = fmaxf(bf2f(b[j]) + a[j], 0.f);
                    o1[j] = fmaxf(bf2f(b[4 + j]) + a[4 + j], 0.f);
                }
                *(f32x4*)(OF + (size_t)r * ldo + col) = o0;
                *(f32x4*)(OF + (size_t)r * ldo + col + 4) = o1;
            }
        }
    } else {   // KCH == 64
        const int og = lane >> 3;             // edge within group (0..7)
        const int ol = lane & 7;
        const int col = s * 64 + ol * 8;      // 8 cols/lane, 8 lanes = 64
        float a[8] = {0.f, 0.f, 0.f, 0.f, 0.f, 0.f, 0.f, 0.f};
        int e = e0;
        for (; e + 15 < e1; e += 16) {        // 2 groups -> 16 edges in flight
            int2 p0 = ev[e + og];
            int2 p1 = ev[e + 8 + og];
            float v0 = __int_as_float(p0.y);
            float v1 = __int_as_float(p1.y);
            u16x8 x0 = *(const u16x8*)(In + (size_t)p0.x * ldi + col);
            u16x8 x1 = *(const u16x8*)(In + (size_t)p1.x * ldi + col);
            #pragma unroll
            for (int j = 0; j < 8; ++j)
                a[j] += v0 * bf2f(x0[j]) + v1 * bf2f(x1[j]);
        }
        for (; e < e1; e += 8) {              // guarded tail groups
            if (e + og < e1) {
                int2 pv = ev[e + og];
                float v = __int_as_float(pv.y);
                u16x8 x = *(const u16x8*)(In + (size_t)pv.x * ldi + col);
                #pragma unroll
                for (int j = 0; j < 8; ++j)
                    a[j] += v * bf2f(x[j]);
            }
        }
        #pragma unroll
        for (int j = 0; j < 8; ++j) {
            a[j] += __shfl_xor(a[j], 8);
            a[j] += __shfl_xor(a[j], 16);
            a[j] += __shfl_xor(a[j], 32);
        }
        if (lane < 8) {
            u16x8* bp = (u16x8*)(Base + (size_t)r * ldb + col);
            u16x8 b = *bp;
            if (MODE == 0) {
                u16x8 nb;
                #pragma unroll
                for (int j = 0; j < 8; ++j) nb[j] = f2bf(bf2f(b[j]) + a[j]);
                *bp = nb;
            } else {
                f32x4 o0, o1;
                #pragma unroll
                for (int j = 0; j < 4; ++j) {
                    o0[j] = fmaxf(bf2f(b[j]) + a[j], 0.f);
                    o1[j] = fmaxf(bf2f(b[4 + j]) + a[4 + j], 0.f);
                }
                *(f32x4*)(OF + (size_t)r * ldo + col) = o0;
                *(f32x4*)(OF + (size_t)r * ldo + col + 4) = o1;
            }
        }
    }
}

// fallback-only final relu over bf16 base
__global__ __launch_bounds__(256)
void relu_out_kernel(const u16* __restrict__ Z, int ld, int coff,
                     float* __restrict__ out, int M)
{
    int g = blockIdx.x * 256 + threadIdx.x;
    if (g >= M * 256) return;
    int row = g >> 8;
    int col = g & 255;
    out[g] = fmaxf(bf2f(Z[(size_t)row * ld + coff + col]), 0.f);
}

// ---------------------------------------------------------------------------
// weight packing (transposed [N][K], bf16)
// ---------------------------------------------------------------------------
__global__ __launch_bounds__(256)
void pack_b0_kernel(const float* __restrict__ w0, const float* __restrict__ sw0,
                    u16* __restrict__ Bh)
{
    int g = blockIdx.x * 256 + threadIdx.x;
    int j = g >> 10, d = g & 1023;
    float v;
    if (j < 512) v = w0[((size_t)(j >> 7) * 1024 + d) * 128 + (j & 127)];
    else         v = sw0[(size_t)d * 512 + (j - 512)];
    Bh[g] = f2bf(v);
}

__global__ __launch_bounds__(256)
void pack_b1_kernel(const float* __restrict__ w1, const float* __restrict__ sw1,
                    u16* __restrict__ Bh)
{
    int g = blockIdx.x * 256 + threadIdx.x;
    int j = g >> 9, d = g & 511;
    float v;
    if (j < 256) v = w1[((size_t)(j >> 6) * 512 + d) * 64 + (j & 63)];
    else         v = sw1[(size_t)d * 256 + (j - 256)];
    Bh[g] = f2bf(v);
}

extern "C" void kernel_launch(void* const* d_in, const int* in_sizes, int n_in,
                              void* d_out, int out_size, void* d_ws, size_t ws_size,
                              hipStream_t stream)
{
    const int*   rna_rows  = (const int*)  d_in[0];
    const int*   rna_cols  = (const int*)  d_in[1];
    const float* rna_vals  = (const float*)d_in[2];
    const int*   prot_rows = (const int*)  d_in[3];
    const int*   prot_cols = (const int*)  d_in[4];
    const float* prot_vals = (const float*)d_in[5];
    const float* H_rna     = (const float*)d_in[6];
    const float* H_prot    = (const float*)d_in[7];
    const float* w0        = (const float*)d_in[8];
    const float* sw0       = (const float*)d_in[9];
    const float* w1        = (const float*)d_in[10];
    const float* sw1       = (const float*)d_in[11];

    const int NRNA = 50000, NPROT = 20000, S = 4, E = 500000;
    const int MP_RNA = 50048, MP_PROT = 20096;
    const int MP_ALL = MP_RNA + MP_PROT;           // 70144 = 548 * 128
    const int NP1_R = NRNA + 1, NP1_P = NPROT + 1;
    const int NB_R = (NRNA + 255) / 256;
    const int NB_P = (NPROT + 255) / 256;
    const int EB   = (E + 255) / 256;
    const int EB4  = (E + 1023) / 1024;

    // --- ws layout ---
    char* ws = (char*)d_ws;
    size_t off = 0;
    u16*   Y16   = (u16*)  (ws + off); off += (size_t)MP_ALL * 1024 * 2;  // L0 [*,1024]; L1 aliases [*,512]
    u16*   Ahbig = (u16*)  (ws + off); off += (size_t)MP_ALL * 1024 * 2;
    u16*   B0h   = (u16*)  (ws + off); off += (size_t)1024 * 1024 * 2;
    u16*   B1h   = (u16*)  (ws + off); off += (size_t)512 * 512 * 2;
    size_t base_bytes = off;

    u16* AhR = Ahbig;                               // layer-1 A views [MP_ALL][512]
    u16* AhP = Ahbig + (size_t)MP_RNA * 512;

    // CSR scratch (ev + packed rows + meta)
    size_t csr_bytes = 0;
    csr_bytes += (size_t)S * E * 8 * 2;                       // evR + evP
    csr_bytes += (size_t)S * E * 2 * 2;                       // r16R + r16P
    csr_bytes += ((size_t)S * (NRNA * 2 + NP1_R + NB_R)) * 4;
    csr_bytes += ((size_t)S * (NPROT * 2 + NP1_P + NB_P)) * 4;
    const bool csr_in_ws = (ws_size >= base_bytes + csr_bytes);

    char* csr = csr_in_ws ? (ws + base_bytes) : (char*)d_out;
    size_t coff = 0;
    int2*  evR     = (int2*) (csr + coff); coff += (size_t)S * E * 8;
    int2*  evP     = (int2*) (csr + coff); coff += (size_t)S * E * 8;
    u16*   r16R    = (u16*)  (csr + coff); coff += (size_t)S * E * 2;
    u16*   r16P    = (u16*)  (csr + coff); coff += (size_t)S * E * 2;
    int*   countsR = (int*)  (csr + coff); coff += (size_t)S * NRNA * 4;
    int*   rowptrR = (int*)  (csr + coff); coff += (size_t)S * NP1_R * 4;
    int*   cursorR = (int*)  (csr + coff); coff += (size_t)S * NRNA * 4;
    int*   bsumR   = (int*)  (csr + coff); coff += (size_t)S * NB_R * 4;
    int*   countsP = (int*)  (csr + coff); coff += (size_t)S * NPROT * 4;
    int*   rowptrP = (int*)  (csr + coff); coff += (size_t)S * NP1_P * 4;
    int*   cursorP = (int*)  (csr + coff); coff += (size_t)S * NPROT * 4;
    int*   bsumP   = (int*)  (csr + coff); coff += (size_t)S * NB_P * 4;

    dim3 blk(256);
    float* out = (float*)d_out;

    // --- pack weights ---
    pack_b0_kernel<<<(1024 * 1024) / 256, blk, 0, stream>>>(w0, sw0, B0h);
    pack_b1_kernel<<<(512 * 512) / 256, blk, 0, stream>>>(w1, sw1, B1h);

    // --- CSR build ---
    pack_rows2_kernel<<<dim3(EB4, S, 2), blk, 0, stream>>>(rna_rows, prot_rows,
                                                           r16R, r16P, E);
    zero2_i32_kernel<<<(S * NRNA + 255) / 256, blk, 0, stream>>>(countsR, S * NRNA,
                                                                 countsP, S * NPROT);
    hist2_kernel<<<dim3(EB, S, 2), blk, 0, stream>>>(r16R, r16P,
                                                     countsR, countsP, NRNA, NPROT, E);
    scan_block2_kernel<<<dim3(NB_R, S, 2), blk, 0, stream>>>(
        countsR, rowptrR, bsumR, NRNA, NP1_R, NB_R,
        countsP, rowptrP, bsumP, NPROT, NP1_P, NB_P);
    scan_aux2_kernel<<<8, blk, 0, stream>>>(bsumR, NB_R, bsumP, NB_P);
    finalize2_kernel<<<dim3(NB_R, S, 2), blk, 0, stream>>>(
        rowptrR, bsumR, cursorR, NRNA, NP1_R, NB_R,
        rowptrP, bsumP, cursorP, NPROT, NP1_P, NB_P, E);
    fill_sliced_kernel<<<dim3(EB4 * 8, S, 2), blk, 0, stream>>>(
        r16R, rna_cols, rna_vals, r16P, prot_cols, prot_vals,
        cursorR, cursorP, evR, evP, NRNA, NPROT, E);

    // --- layer 0: cvt + one GEMM (N=K=1024, all-bf16 out) ---
    cvt_bf16_kernel<<<MP_RNA / 2, blk, 0, stream>>>(H_rna, Ahbig, NRNA, 10);
    cvt_bf16_kernel<<<MP_PROT / 2, blk, 0, stream>>>(H_prot, Ahbig + (size_t)MP_RNA * 1024,
                                                     NPROT, 10);
    gemm_bf16_kernel<<<8 * (MP_ALL / 128), blk, 0, stream>>>(
        Ahbig, B0h, Y16, 1024, 1024, 7, 3);

    // --- layer 0 SpMM: Ah = bf16(relu(base + agg)) ---
    spmm2_kernel<128, 1><<<NRNA + NPROT, blk, 0, stream>>>(
        rowptrR, rowptrP, NP1_R, NP1_P, evR, evP,
        Y16 + (size_t)MP_RNA * 1024,      // RNA gathers prot tmp (cols 0..511)
        Y16,                              // PROT gathers rna tmp
        1024,
        Y16 + 512, Y16 + (size_t)MP_RNA * 1024 + 512, 1024,   // bf16 base halves
        AhR, AhP, nullptr, nullptr, 512,
        NRNA, E);

    // --- zero layer-1 A pad rows ---
    zero_u16_kernel<<<(48 * 512 + 255) / 256, blk, 0, stream>>>(
        AhR + (size_t)NRNA * 512, 48 * 512);
    zero_u16_kernel<<<(96 * 512 + 255) / 256, blk, 0, stream>>>(
        AhP + (size_t)NPROT * 512, 96 * 512);

    // --- layer 1: one GEMM (N=K=512), Y16_1 aliases Y16 [MP_ALL][512] ---
    gemm_bf16_kernel<<<4 * (MP_ALL / 128), blk, 0, stream>>>(
        Ahbig, B1h, Y16, 512, 512, 3, 2);

    // --- layer 1 SpMM ---
    if (csr_in_ws) {
        spmm2_kernel<64, 2><<<NRNA + NPROT, blk, 0, stream>>>(
            rowptrR, rowptrP, NP1_R, NP1_P, evR, evP,
            Y16 + (size_t)MP_RNA * 512, Y16, 512,
            Y16 + 256, Y16 + (size_t)MP_RNA * 512 + 256, 512,
            nullptr, nullptr,
            out, out + (size_t)NRNA * 256, 256,
            NRNA, E);
    } else {
        spmm2_kernel<64, 0><<<NRNA + NPROT, blk, 0, stream>>>(
            rowptrR, rowptrP, NP1_R, NP1_P, evR, evP,
            Y16 + (size_t)MP_RNA * 512, Y16, 512,
            Y16 + 256, Y16 + (size_t)MP_RNA * 512 + 256, 512,
            nullptr, nullptr,
            nullptr, nullptr, 0,
            NRNA, E);
        relu_out_kernel<<<(NRNA * 256) / 256, blk, 0, stream>>>(Y16, 512, 256, out, NRNA);
        relu_out_kernel<<<(NPROT * 256) / 256, blk, 0, stream>>>(
            Y16 + (size_t)MP_RNA * 512, 512, 256, out + (size_t)NRNA * 256, NPROT);
    }
}

// Round 19
// 981.650 us; speedup vs baseline: 1.6293x; 1.0088x over previous
//
#include <hip/hip_runtime.h>
#include <hip/hip_bf16.h>

// ---------------------------------------------------------------------------
// StackGCNEncoder on MI355X — round 19:
//   FUSED L0-GEMM ∥ FILL: one dispatch, blocks [0,GG) run the GEMM tile
//   (compute-bound, MfmaUtil 32%), blocks [GG,..) run the CSR fill
//   (latency-bound, VALU 4%) -> disjoint resources overlap instead of
//   running serially (404 us -> ~max of the two).
//   fill reverted to cached loads (r18 NT regression); u16 rows kept.
//   Everything else identical to round 18.
// ---------------------------------------------------------------------------

typedef unsigned short u16;
typedef short s16x8 __attribute__((ext_vector_type(8)));
typedef float f32x4 __attribute__((ext_vector_type(4)));
typedef __attribute__((ext_vector_type(8))) unsigned short u16x8;
typedef unsigned long long u64;

__device__ __forceinline__ u16 f2bf(float x) {            // RNE f32->bf16
    unsigned u = __float_as_uint(x);
    return (u16)((u + 0x7fff + ((u >> 16) & 1)) >> 16);
}
__device__ __forceinline__ float bf2f(u16 h) {
    return __uint_as_float(((unsigned)h) << 16);
}

__device__ __forceinline__ void gload16(const u16* g, u16* l) {
    __builtin_amdgcn_global_load_lds(
        (const __attribute__((address_space(1))) unsigned int*)g,
        (__attribute__((address_space(3))) unsigned int*)l,
        16, 0, 0);
}

// ---------------------------------------------------------------------------
// GEMM block body (proven r12 structure): Y16 = A x B^T, all-bf16 out.
// 128x128 tile, BK=32, 32 KB dbuf LDS (ldsb), XOR chunk swizzle,
// counted-vmcnt barriers, bijective XCD swizzle over nwg blocks (id bx).
// ---------------------------------------------------------------------------
__device__ __forceinline__
void gemm_body(u16* ldsb, int bx, int nwg,
               const u16* __restrict__ Ah, const u16* __restrict__ Bh,
               u16* __restrict__ Y, int ldy, int K, int nxmask, int nxshift)
{
    const int q   = nwg >> 3, r8 = nwg & 7;
    const int xcd = bx & 7, pos = bx >> 3;
    const int lin = (xcd < r8 ? xcd * (q + 1) : r8 * (q + 1) + (xcd - r8) * q) + pos;
    const int bm0 = (lin >> nxshift) * 128;
    const int bn0 = (lin & nxmask) * 128;

    const int tid  = threadIdx.x;
    const int lane = tid & 63;
    const int wid  = tid >> 6;
    const int wr   = wid >> 1;
    const int wc   = wid & 1;

    const int srow = tid >> 2;
    const int scol = ((tid & 3) ^ ((tid >> 3) & 3)) * 8;   // u16 units
    const size_t aoff0 = (size_t)(bm0 + srow) * K + scol;
    const size_t aoff1 = (size_t)(bm0 + srow + 64) * K + scol;
    const size_t boff0 = (size_t)(bn0 + srow) * K + scol;
    const size_t boff1 = (size_t)(bn0 + srow + 64) * K + scol;
    const int c0 = tid * 8;
    const int c1 = 2048 + tid * 8;

    f32x4 zero = {0.f, 0.f, 0.f, 0.f};
    f32x4 acc[4][4];
    #pragma unroll
    for (int i = 0; i < 4; ++i)
        #pragma unroll
        for (int j = 0; j < 4; ++j) acc[i][j] = zero;

    const int fchunk = (((lane >> 4) ^ ((lane >> 1) & 3))) * 8;
    const int a_fr = (wr * 64 + (lane & 15)) * 32 + fchunk;
    const int b_fr = (wc * 64 + (lane & 15)) * 32 + fchunk;

    const int nk = K >> 5;

    {
        u16* L = ldsb;
        gload16(Ah + aoff0, L + c0);          gload16(Ah + aoff1, L + c1);
        gload16(Bh + boff0, L + 4096 + c0);   gload16(Bh + boff1, L + 4096 + c1);
    }
    int cur = 0;
    for (int t = 0; t < nk; ++t) {
        if (t + 1 < nk) {
            const int k0 = (t + 1) * 32;
            u16* L = ldsb + (cur ^ 1) * 8192;
            gload16(Ah + aoff0 + k0, L + c0);         gload16(Ah + aoff1 + k0, L + c1);
            gload16(Bh + boff0 + k0, L + 4096 + c0);  gload16(Bh + boff1 + k0, L + 4096 + c1);
            asm volatile("s_waitcnt vmcnt(4)\n\ts_barrier" ::: "memory");
        } else {
            asm volatile("s_waitcnt vmcnt(0)\n\ts_barrier" ::: "memory");
        }
        const u16* L = ldsb + cur * 8192;
        s16x8 bh[4];
        #pragma unroll
        for (int nf = 0; nf < 4; ++nf)
            bh[nf] = *(const s16x8*)(L + 4096 + b_fr + nf * 512);
        #pragma unroll
        for (int mf = 0; mf < 4; ++mf) {
            s16x8 ahv = *(const s16x8*)(L + a_fr + mf * 512);
            #pragma unroll
            for (int nf = 0; nf < 4; ++nf)
                acc[mf][nf] = __builtin_amdgcn_mfma_f32_16x16x32_bf16(ahv, bh[nf], acc[mf][nf], 0, 0, 0);
        }
        asm volatile("s_barrier" ::: "memory");
        cur ^= 1;
    }

    #pragma unroll
    for (int mf = 0; mf < 4; ++mf) {
        const int row0 = bm0 + wr * 64 + mf * 16 + (lane >> 4) * 4;
        #pragma unroll
        for (int nf = 0; nf < 4; ++nf) {
            const int col = bn0 + wc * 64 + nf * 16 + (lane & 15);
            #pragma unroll
            for (int r = 0; r < 4; ++r)
                Y[(size_t)(row0 + r) * ldy + col] = f2bf(acc[mf][nf][r]);
        }
    }
}

// standalone GEMM (layer 1)
__global__ __launch_bounds__(256)
void gemm_bf16_kernel(const u16* __restrict__ Ah, const u16* __restrict__ Bh,
                      u16* __restrict__ Y, int ldy,
                      int K, int nxmask, int nxshift)
{
    __shared__ u16 lds[2][2][4096];   // 32 KB
    gemm_body(&lds[0][0][0], blockIdx.x, gridDim.x, Ah, Bh, Y, ldy, K, nxmask, nxshift);
}

// ---------------------------------------------------------------------------
// fill block body: row-sliced XCD-affine, u16 rows, cached loads,
// cols/vals loaded only on slice match.
// ---------------------------------------------------------------------------
__device__ __forceinline__
void fill_body(int fx, int s, int side,
               const u16* __restrict__ r16R, const int* __restrict__ colsR,
               const float* __restrict__ valsR,
               const u16* __restrict__ r16P, const int* __restrict__ colsP,
               const float* __restrict__ valsP,
               int* __restrict__ curR, int* __restrict__ curP,
               int2* __restrict__ evR, int2* __restrict__ evP,
               int NR, int NP, int E)
{
    const int slice = fx & 7;
    const int chunk = fx >> 3;
    const int N          = side ? NP : NR;
    const u16* r16       = side ? r16P : r16R;
    const int* cols      = side ? colsP : colsR;
    const float* vals    = side ? valsP : valsR;
    int* cursor          = side ? curP : curR;
    int2* ev             = side ? evP : evR;

    const int Nsl = (N + 7) >> 3;
    const int r0 = slice * Nsl;
    const int r1 = min(N, r0 + Nsl);

    const int e0 = chunk * 1024 + threadIdx.x * 4;
    if (e0 >= E) return;
    const size_t base = (size_t)s * E;

    if (e0 + 4 <= E) {
        u64 rq = *(const u64*)(r16 + base + e0);
        int rr[4] = {(int)(u16)rq, (int)(u16)(rq >> 16),
                     (int)(u16)(rq >> 32), (int)(u16)(rq >> 48)};
        #pragma unroll
        for (int j = 0; j < 4; ++j) {
            if (rr[j] >= r0 && rr[j] < r1) {
                int pos = atomicAdd(cursor + s * N + rr[j], 1);
                ev[base + pos] = make_int2(cols[base + e0 + j],
                                           __float_as_int(vals[base + e0 + j]));
            }
        }
    } else {
        for (int j = 0; j < 4 && e0 + j < E; ++j) {
            int r = (int)r16[base + e0 + j];
            if (r >= r0 && r < r1) {
                int pos = atomicAdd(cursor + s * N + r, 1);
                ev[base + pos] = make_int2(cols[base + e0 + j],
                                           __float_as_int(vals[base + e0 + j]));
            }
        }
    }
}

// ---------------------------------------------------------------------------
// FUSED: blocks [0,GG) at (by,bz)==(0,0) -> L0 GEMM; blocks [GG,..) -> fill.
// GG % 8 == 0 so fill slice = bx&7 keeps XCD affinity.
// ---------------------------------------------------------------------------
__global__ __launch_bounds__(256)
void fused_gemm_fill_kernel(const u16* __restrict__ Ah, const u16* __restrict__ Bh,
                            u16* __restrict__ Y, int ldy, int K,
                            int nxmask, int nxshift, int GG,
                            const u16* __restrict__ r16R, const int* __restrict__ colsR,
                            const float* __restrict__ valsR,
                            const u16* __restrict__ r16P, const int* __restrict__ colsP,
                            const float* __restrict__ valsP,
                            int* __restrict__ curR, int* __restrict__ curP,
                            int2* __restrict__ evR, int2* __restrict__ evP,
                            int NR, int NP, int E)
{
    __shared__ u16 lds[2][2][4096];   // 32 KB (GEMM blocks only)
    const int bx = blockIdx.x;
    if (bx < GG) {
        if (blockIdx.y || blockIdx.z) return;   // idle replicas
        gemm_body(&lds[0][0][0], bx, GG, Ah, Bh, Y, ldy, K, nxmask, nxshift);
    } else {
        fill_body(bx - GG, blockIdx.y, blockIdx.z,
                  r16R, colsR, valsR, r16P, colsP, valsP,
                  curR, curP, evR, evP, NR, NP, E);
    }
}

// ---------------------------------------------------------------------------
// f32 [M][K] -> bf16 [Mpad][K], zero-padded rows. 8 elems/thread.
// ---------------------------------------------------------------------------
__global__ __launch_bounds__(256)
void cvt_bf16_kernel(const float* __restrict__ A, u16* __restrict__ Hh,
                     int M, int kshift)
{
    const size_t g  = (size_t)blockIdx.x * 256 + threadIdx.x;
    const size_t i8 = g * 8;
    const int row   = (int)(i8 >> kshift);
    f32x4 a = {0.f, 0.f, 0.f, 0.f}, b = {0.f, 0.f, 0.f, 0.f};
    if (row < M) {
        a = *(const f32x4*)(A + i8);
        b = *(const f32x4*)(A + i8 + 4);
    }
    u16x8 h;
    #pragma unroll
    for (int j = 0; j < 4; ++j) { h[j] = f2bf(a[j]); h[4 + j] = f2bf(b[j]); }
    *(u16x8*)(Hh + i8) = h;
}

__global__ __launch_bounds__(256)
void zero_u16_kernel(u16* __restrict__ a, int n)
{
    int i = blockIdx.x * 256 + threadIdx.x;
    if (i < n) a[i] = 0;
}

// ---------------------------------------------------------------------------
// CSR build
// ---------------------------------------------------------------------------
__global__ __launch_bounds__(256)
void zero2_i32_kernel(int* __restrict__ a, int na, int* __restrict__ b, int nb)
{
    int i = blockIdx.x * 256 + threadIdx.x;
    if (i < na) a[i] = 0;
    if (i < nb) b[i] = 0;
}

__global__ __launch_bounds__(256)
void pack_rows2_kernel(const int* __restrict__ rowsR, const int* __restrict__ rowsP,
                       u16* __restrict__ r16R, u16* __restrict__ r16P, int E)
{
    int s = blockIdx.y;
    int e = (blockIdx.x * 256 + threadIdx.x) * 4;
    if (e >= E) return;
    const int* rows = blockIdx.z ? rowsP : rowsR;
    u16* r16 = blockIdx.z ? r16P : r16R;
    size_t base = (size_t)s * E;
    if (e + 4 <= E) {
        int4 r4 = *(const int4*)(rows + base + e);
        u16 p[4] = {(u16)r4.x, (u16)r4.y, (u16)r4.z, (u16)r4.w};
        *(u64*)(r16 + base + e) = *(const u64*)p;
    } else {
        for (int j = 0; j < 4 && e + j < E; ++j)
            r16[base + e + j] = (u16)rows[base + e + j];
    }
}

__global__ __launch_bounds__(256)
void hist2_kernel(const u16* __restrict__ rowsR, const u16* __restrict__ rowsP,
                  int* __restrict__ cntR, int* __restrict__ cntP,
                  int NR, int NP, int E)
{
    int s = blockIdx.y;
    int e = blockIdx.x * 256 + threadIdx.x;
    if (e >= E) return;
    if (blockIdx.z == 0) atomicAdd(cntR + s * NR + (int)rowsR[(size_t)s * E + e], 1);
    else                 atomicAdd(cntP + s * NP + (int)rowsP[(size_t)s * E + e], 1);
}

__global__ __launch_bounds__(256)
void scan_block2_kernel(const int* __restrict__ cR, int* __restrict__ rpR,
                        int* __restrict__ bsR, int NR, int np1R, int NBR,
                        const int* __restrict__ cP, int* __restrict__ rpP,
                        int* __restrict__ bsP, int NP, int np1P, int NBP)
{
    const int side = blockIdx.z;
    const int NB = side ? NBP : NBR;
    if ((int)blockIdx.x >= NB) return;
    const int N = side ? NP : NR;
    const int np1 = side ? np1P : np1R;
    const int* counts = side ? cP : cR;
    int* rowptr = side ? rpP : rpR;
    int* blocksum = side ? bsP : bsR;

    __shared__ int sd[256];
    int s = blockIdx.y;
    int i = blockIdx.x * 256 + threadIdx.x;
    int tid = threadIdx.x;
    int v = (i < N) ? counts[s * N + i] : 0;
    sd[tid] = v;
    __syncthreads();
    #pragma unroll
    for (int off = 1; off < 256; off <<= 1) {
        int t = (tid >= off) ? sd[tid - off] : 0;
        __syncthreads();
        sd[tid] += t;
        __syncthreads();
    }
    if (i < N) rowptr[s * np1 + i] = sd[tid] - v;
    if (tid == 255) blocksum[s * NB + blockIdx.x] = sd[255];
}

__global__ __launch_bounds__(256)
void scan_aux2_kernel(int* __restrict__ bsR, int NBR, int* __restrict__ bsP, int NBP)
{
    const int side = blockIdx.x >> 2;
    const int s = blockIdx.x & 3;
    int* blocksum = side ? bsP : bsR;
    const int NB = side ? NBP : NBR;

    __shared__ int sd[256];
    int tid = threadIdx.x;
    int v = (tid < NB) ? blocksum[s * NB + tid] : 0;
    sd[tid] = v;
    __syncthreads();
    #pragma unroll
    for (int off = 1; off < 256; off <<= 1) {
        int t = (tid >= off) ? sd[tid - off] : 0;
        __syncthreads();
        sd[tid] += t;
        __syncthreads();
    }
    if (tid < NB) blocksum[s * NB + tid] = sd[tid] - v;
}

__global__ __launch_bounds__(256)
void finalize2_kernel(int* __restrict__ rpR, const int* __restrict__ bsR,
                      int* __restrict__ curR, int NR, int np1R, int NBR,
                      int* __restrict__ rpP, const int* __restrict__ bsP,
                      int* __restrict__ curP, int NP, int np1P, int NBP, int E)
{
    const int side = blockIdx.z;
    const int NB = side ? NBP : NBR;
    if ((int)blockIdx.x >= NB) return;
    const int N = side ? NP : NR;
    const int np1 = side ? np1P : np1R;
    int* rowptr = side ? rpP : rpR;
    const int* blocksum = side ? bsP : bsR;
    int* cursor = side ? curP : curR;

    int s = blockIdx.y;
    int i = blockIdx.x * 256 + threadIdx.x;
    if (i < N) {
        int v = rowptr[s * np1 + i] + blocksum[s * NB + blockIdx.x];
        rowptr[s * np1 + i] = v;
        cursor[s * N + i] = v;
    }
    if (i == N) rowptr[s * np1 + N] = E;
}

// ---------------------------------------------------------------------------
// CSR SpMM, quarter/eighth-wave edge parallelism (round 17, unchanged).
// ---------------------------------------------------------------------------
template<int KCH, int MODE>
__global__ __launch_bounds__(256)
void spmm2_kernel(const int* __restrict__ rpR, const int* __restrict__ rpP,
                  int np1R, int np1P,
                  const int2* __restrict__ evRg, const int2* __restrict__ evPg,
                  const u16* __restrict__ InR, const u16* __restrict__ InP, int ldi,
                  u16* __restrict__ BaseR, u16* __restrict__ BaseP, int ldb,
                  u16* __restrict__ OHR, u16* __restrict__ OHP,
                  float* __restrict__ OFR, float* __restrict__ OFP, int ldo,
                  int NR, int E)
{
    int r = blockIdx.x;
    const int s    = threadIdx.x >> 6;
    const int lane = threadIdx.x & 63;
    const int* rp; const int2* ev; const u16* In; u16* Base; int np1;
    u16* OH; float* OF;
    if (r < NR) { rp = rpR; ev = evRg; In = InR; Base = BaseR; np1 = np1R;
                  OH = OHR; OF = OFR; }
    else { r -= NR; rp = rpP; ev = evPg; In = InP; Base = BaseP; np1 = np1P;
           OH = OHP; OF = OFP; }
    int e0 = __builtin_amdgcn_readfirstlane(rp[s * np1 + r]);
    int e1 = __builtin_amdgcn_readfirstlane(rp[s * np1 + r + 1]);
    if (MODE == 0 && e0 == e1) return;
    ev += (size_t)s * E;

    if (KCH == 128) {
        const int qg = lane >> 4;
        const int ql = lane & 15;
        const int col = s * 128 + ql * 8;
        float a[8] = {0.f, 0.f, 0.f, 0.f, 0.f, 0.f, 0.f, 0.f};
        int e = e0;
        for (; e + 7 < e1; e += 8) {
            int2 p0 = ev[e + qg];
            int2 p1 = ev[e + 4 + qg];
            float v0 = __int_as_float(p0.y);
            float v1 = __int_as_float(p1.y);
            u16x8 x0 = *(const u16x8*)(In + (size_t)p0.x * ldi + col);
            u16x8 x1 = *(const u16x8*)(In + (size_t)p1.x * ldi + col);
            #pragma unroll
            for (int j = 0; j < 8; ++j)
                a[j] += v0 * bf2f(x0[j]) + v1 * bf2f(x1[j]);
        }
        for (; e < e1; e += 4) {
            if (e + qg < e1) {
                int2 pv = ev[e + qg];
                float v = __int_as_float(pv.y);
                u16x8 x = *(const u16x8*)(In + (size_t)pv.x * ldi + col);
                #pragma unroll
                for (int j = 0; j < 8; ++j)
                    a[j] += v * bf2f(x[j]);
            }
        }
        #pragma unroll
        for (int j = 0; j < 8; ++j) {
            a[j] += __shfl_xor(a[j], 16);
            a[j] += __shfl_xor(a[j], 32);
        }
        if (lane < 16) {
            u16x8* bp = (u16x8*)(Base + (size_t)r * ldb + col);
            u16x8 b = *bp;
            if (MODE == 0) {
                u16x8 nb;
                #pragma unroll
                for (int j = 0; j < 8; ++j) nb[j] = f2bf(bf2f(b[j]) + a[j]);
                *bp = nb;
            } else if (MODE == 1) {
                u16x8 h;
                #pragma unroll
                for (int j = 0; j < 8; ++j) h[j] = f2bf(fmaxf(bf2f(b[j]) + a[j], 0.f));
                *(u16x8*)(OH + (size_t)r * ldo + col) = h;
            } else {
                f32x4 o0, o1;
                #pragma unroll
                for (int j = 0; j < 4; ++j) {
                    o0[j] = fmaxf(bf2f(b[j]) + a[j], 0.f);
                    o1[j] = fmaxf(bf2f(b[4 + j]) + a[4 + j], 0.f);
                }
                *(f32x4*)(OF + (size_t)r * ldo + col) = o0;
                *(f32x4*)(OF + (size_t)r * ldo + col + 4) = o1;
            }
        }
    } else {   // KCH == 64
        const int og = lane >> 3;
        const int ol = lane & 7;
        const int col = s * 64 + ol * 8;
        float a[8] = {0.f, 0.f, 0.f, 0.f, 0.f, 0.f, 0.f, 0.f};
        int e = e0;
        for (; e + 15 < e1; e += 16) {
            int2 p0 = ev[e + og];
            int2 p1 = ev[e + 8 + og];
            float v0 = __int_as_float(p0.y);
            float v1 = __int_as_float(p1.y);
            u16x8 x0 = *(const u16x8*)(In + (size_t)p0.x * ldi + col);
            u16x8 x1 = *(const u16x8*)(In + (size_t)p1.x * ldi + col);
            #pragma unroll
            for (int j = 0; j < 8; ++j)
                a[j] += v0 * bf2f(x0[j]) + v1 * bf2f(x1[j]);
        }
        for (; e < e1; e += 8) {
            if (e + og < e1) {
                int2 pv = ev[e + og];
                float v = __int_as_float(pv.y);
                u16x8 x = *(const u16x8*)(In + (size_t)pv.x * ldi + col);
                #pragma unroll
                for (int j = 0; j < 8; ++j)
                    a[j] += v * bf2f(x[j]);
            }
        }
        #pragma unroll
        for (int j = 0; j < 8; ++j) {
            a[j] += __shfl_xor(a[j], 8);
            a[j] += __shfl_xor(a[j], 16);
            a[j] += __shfl_xor(a[j], 32);
        }
        if (lane < 8) {
            u16x8* bp = (u16x8*)(Base + (size_t)r * ldb + col);
            u16x8 b = *bp;
            if (MODE == 0) {
                u16x8 nb;
                #pragma unroll
                for (int j = 0; j < 8; ++j) nb[j] = f2bf(bf2f(b[j]) + a[j]);
                *bp = nb;
            } else {
                f32x4 o0, o1;
                #pragma unroll
                for (int j = 0; j < 4; ++j) {
                    o0[j] = fmaxf(bf2f(b[j]) + a[j], 0.f);
                    o1[j] = fmaxf(bf2f(b[4 + j]) + a[4 + j], 0.f);
                }
                *(f32x4*)(OF + (size_t)r * ldo + col) = o0;
                *(f32x4*)(OF + (size_t)r * ldo + col + 4) = o1;
            }
        }
    }
}

// fallback-only final relu over bf16 base
__global__ __launch_bounds__(256)
void relu_out_kernel(const u16* __restrict__ Z, int ld, int coff,
                     float* __restrict__ out, int M)
{
    int g = blockIdx.x * 256 + threadIdx.x;
    if (g >= M * 256) return;
    int row = g >> 8;
    int col = g & 255;
    out[g] = fmaxf(bf2f(Z[(size_t)row * ld + coff + col]), 0.f);
}

// ---------------------------------------------------------------------------
// weight packing (transposed [N][K], bf16)
// ---------------------------------------------------------------------------
__global__ __launch_bounds__(256)
void pack_b0_kernel(const float* __restrict__ w0, const float* __restrict__ sw0,
                    u16* __restrict__ Bh)
{
    int g = blockIdx.x * 256 + threadIdx.x;
    int j = g >> 10, d = g & 1023;
    float v;
    if (j < 512) v = w0[((size_t)(j >> 7) * 1024 + d) * 128 + (j & 127)];
    else         v = sw0[(size_t)d * 512 + (j - 512)];
    Bh[g] = f2bf(v);
}

__global__ __launch_bounds__(256)
void pack_b1_kernel(const float* __restrict__ w1, const float* __restrict__ sw1,
                    u16* __restrict__ Bh)
{
    int g = blockIdx.x * 256 + threadIdx.x;
    int j = g >> 9, d = g & 511;
    float v;
    if (j < 256) v = w1[((size_t)(j >> 6) * 512 + d) * 64 + (j & 63)];
    else         v = sw1[(size_t)d * 256 + (j - 256)];
    Bh[g] = f2bf(v);
}

extern "C" void kernel_launch(void* const* d_in, const int* in_sizes, int n_in,
                              void* d_out, int out_size, void* d_ws, size_t ws_size,
                              hipStream_t stream)
{
    const int*   rna_rows  = (const int*)  d_in[0];
    const int*   rna_cols  = (const int*)  d_in[1];
    const float* rna_vals  = (const float*)d_in[2];
    const int*   prot_rows = (const int*)  d_in[3];
    const int*   prot_cols = (const int*)  d_in[4];
    const float* prot_vals = (const float*)d_in[5];
    const float* H_rna     = (const float*)d_in[6];
    const float* H_prot    = (const float*)d_in[7];
    const float* w0        = (const float*)d_in[8];
    const float* sw0       = (const float*)d_in[9];
    const float* w1        = (const float*)d_in[10];
    const float* sw1       = (const float*)d_in[11];

    const int NRNA = 50000, NPROT = 20000, S = 4, E = 500000;
    const int MP_RNA = 50048, MP_PROT = 20096;
    const int MP_ALL = MP_RNA + MP_PROT;           // 70144 = 548 * 128
    const int NP1_R = NRNA + 1, NP1_P = NPROT + 1;
    const int NB_R = (NRNA + 255) / 256;
    const int NB_P = (NPROT + 255) / 256;
    const int EB   = (E + 255) / 256;
    const int EB4  = (E + 1023) / 1024;
    const int GG   = 8 * (MP_ALL / 128);           // 4384, %8==0
    const int FX   = EB4 * 8;                      // fill x-blocks

    // --- ws layout ---
    char* ws = (char*)d_ws;
    size_t off = 0;
    u16*   Y16   = (u16*)  (ws + off); off += (size_t)MP_ALL * 1024 * 2;  // L0 [*,1024]; L1 aliases [*,512]
    u16*   Ahbig = (u16*)  (ws + off); off += (size_t)MP_ALL * 1024 * 2;
    u16*   B0h   = (u16*)  (ws + off); off += (size_t)1024 * 1024 * 2;
    u16*   B1h   = (u16*)  (ws + off); off += (size_t)512 * 512 * 2;
    size_t base_bytes = off;

    u16* AhR = Ahbig;                               // layer-1 A views [MP_ALL][512]
    u16* AhP = Ahbig + (size_t)MP_RNA * 512;

    // CSR scratch (ev + packed rows + meta)
    size_t csr_bytes = 0;
    csr_bytes += (size_t)S * E * 8 * 2;                       // evR + evP
    csr_bytes += (size_t)S * E * 2 * 2;                       // r16R + r16P
    csr_bytes += ((size_t)S * (NRNA * 2 + NP1_R + NB_R)) * 4;
    csr_bytes += ((size_t)S * (NPROT * 2 + NP1_P + NB_P)) * 4;
    const bool csr_in_ws = (ws_size >= base_bytes + csr_bytes);

    char* csr = csr_in_ws ? (ws + base_bytes) : (char*)d_out;
    size_t coff = 0;
    int2*  evR     = (int2*) (csr + coff); coff += (size_t)S * E * 8;
    int2*  evP     = (int2*) (csr + coff); coff += (size_t)S * E * 8;
    u16*   r16R    = (u16*)  (csr + coff); coff += (size_t)S * E * 2;
    u16*   r16P    = (u16*)  (csr + coff); coff += (size_t)S * E * 2;
    int*   countsR = (int*)  (csr + coff); coff += (size_t)S * NRNA * 4;
    int*   rowptrR = (int*)  (csr + coff); coff += (size_t)S * NP1_R * 4;
    int*   cursorR = (int*)  (csr + coff); coff += (size_t)S * NRNA * 4;
    int*   bsumR   = (int*)  (csr + coff); coff += (size_t)S * NB_R * 4;
    int*   countsP = (int*)  (csr + coff); coff += (size_t)S * NPROT * 4;
    int*   rowptrP = (int*)  (csr + coff); coff += (size_t)S * NP1_P * 4;
    int*   cursorP = (int*)  (csr + coff); coff += (size_t)S * NPROT * 4;
    int*   bsumP   = (int*)  (csr + coff); coff += (size_t)S * NB_P * 4;

    dim3 blk(256);
    float* out = (float*)d_out;

    // --- pack weights ---
    pack_b0_kernel<<<(1024 * 1024) / 256, blk, 0, stream>>>(w0, sw0, B0h);
    pack_b1_kernel<<<(512 * 512) / 256, blk, 0, stream>>>(w1, sw1, B1h);

    // --- CSR build prefix ---
    pack_rows2_kernel<<<dim3(EB4, S, 2), blk, 0, stream>>>(rna_rows, prot_rows,
                                                           r16R, r16P, E);
    zero2_i32_kernel<<<(S * NRNA + 255) / 256, blk, 0, stream>>>(countsR, S * NRNA,
                                                                 countsP, S * NPROT);
    hist2_kernel<<<dim3(EB, S, 2), blk, 0, stream>>>(r16R, r16P,
                                                     countsR, countsP, NRNA, NPROT, E);
    scan_block2_kernel<<<dim3(NB_R, S, 2), blk, 0, stream>>>(
        countsR, rowptrR, bsumR, NRNA, NP1_R, NB_R,
        countsP, rowptrP, bsumP, NPROT, NP1_P, NB_P);
    scan_aux2_kernel<<<8, blk, 0, stream>>>(bsumR, NB_R, bsumP, NB_P);
    finalize2_kernel<<<dim3(NB_R, S, 2), blk, 0, stream>>>(
        rowptrR, bsumR, cursorR, NRNA, NP1_R, NB_R,
        rowptrP, bsumP, cursorP, NPROT, NP1_P, NB_P, E);

    // --- cvt (must precede fused GEMM) ---
    cvt_bf16_kernel<<<MP_RNA / 2, blk, 0, stream>>>(H_rna, Ahbig, NRNA, 10);
    cvt_bf16_kernel<<<MP_PROT / 2, blk, 0, stream>>>(H_prot, Ahbig + (size_t)MP_RNA * 1024,
                                                     NPROT, 10);

    // --- FUSED: L0 GEMM (blocks [0,GG)) ∥ fill (blocks [GG, GG+FX)) ---
    fused_gemm_fill_kernel<<<dim3(GG + FX, S, 2), blk, 0, stream>>>(
        Ahbig, B0h, Y16, 1024, 1024, 7, 3, GG,
        r16R, rna_cols, rna_vals, r16P, prot_cols, prot_vals,
        cursorR, cursorP, evR, evP, NRNA, NPROT, E);

    // --- layer 0 SpMM: Ah = bf16(relu(base + agg)) ---
    spmm2_kernel<128, 1><<<NRNA + NPROT, blk, 0, stream>>>(
        rowptrR, rowptrP, NP1_R, NP1_P, evR, evP,
        Y16 + (size_t)MP_RNA * 1024,      // RNA gathers prot tmp (cols 0..511)
        Y16,                              // PROT gathers rna tmp
        1024,
        Y16 + 512, Y16 + (size_t)MP_RNA * 1024 + 512, 1024,   // bf16 base halves
        AhR, AhP, nullptr, nullptr, 512,
        NRNA, E);

    // --- zero layer-1 A pad rows ---
    zero_u16_kernel<<<(48 * 512 + 255) / 256, blk, 0, stream>>>(
        AhR + (size_t)NRNA * 512, 48 * 512);
    zero_u16_kernel<<<(96 * 512 + 255) / 256, blk, 0, stream>>>(
        AhP + (size_t)NPROT * 512, 96 * 512);

    // --- layer 1: one GEMM (N=K=512), Y16_1 aliases Y16 [MP_ALL][512] ---
    gemm_bf16_kernel<<<4 * (MP_ALL / 128), blk, 0, stream>>>(
        Ahbig, B1h, Y16, 512, 512, 3, 2);

    // --- layer 1 SpMM ---
    if (csr_in_ws) {
        spmm2_kernel<64, 2><<<NRNA + NPROT, blk, 0, stream>>>(
            rowptrR, rowptrP, NP1_R, NP1_P, evR, evP,
            Y16 + (size_t)MP_RNA * 512, Y16, 512,
            Y16 + 256, Y16 + (size_t)MP_RNA * 512 + 256, 512,
            nullptr, nullptr,
            out, out + (size_t)NRNA * 256, 256,
            NRNA, E);
    } else {
        spmm2_kernel<64, 0><<<NRNA + NPROT, blk, 0, stream>>>(
            rowptrR, rowptrP, NP1_R, NP1_P, evR, evP,
            Y16 + (size_t)MP_RNA * 512, Y16, 512,
            Y16 + 256, Y16 + (size_t)MP_RNA * 512 + 256, 512,
            nullptr, nullptr,
            nullptr, nullptr, 0,
            NRNA, E);
        relu_out_kernel<<<(NRNA * 256) / 256, blk, 0, stream>>>(Y16, 512, 256, out, NRNA);
        relu_out_kernel<<<(NPROT * 256) / 256, blk, 0, stream>>>(
            Y16 + (size_t)MP_RNA * 512, 512, 256, out + (size_t)NRNA * 256, NPROT);
    }
}

// Round 20
// 961.946 us; speedup vs baseline: 1.6627x; 1.0205x over previous
//
#include <hip/hip_runtime.h>
#include <hip/hip_bf16.h>

// ---------------------------------------------------------------------------
// StackGCNEncoder on MI355X — round 20:
//   r19 post-mortem: fused GEMM∥fill null because 32KB static LDS capped the
//   latency-bound fill at 5 blocks/CU (vs 8 standalone).
//   -> GEMM un-fused (standalone r18 form);
//   -> fill: 16 edges/thread (4x deeper MLP, 4x fewer blocks);
//   -> fill fused with cvt instead (both LDS-free, resource-disjoint);
//   -> pack_rows+hist merged (one rows read pass).
//   Everything else identical to round 18/19.
// ---------------------------------------------------------------------------

typedef unsigned short u16;
typedef short s16x8 __attribute__((ext_vector_type(8)));
typedef float f32x4 __attribute__((ext_vector_type(4)));
typedef __attribute__((ext_vector_type(8))) unsigned short u16x8;
typedef unsigned long long u64;

__device__ __forceinline__ u16 f2bf(float x) {            // RNE f32->bf16
    unsigned u = __float_as_uint(x);
    return (u16)((u + 0x7fff + ((u >> 16) & 1)) >> 16);
}
__device__ __forceinline__ float bf2f(u16 h) {
    return __uint_as_float(((unsigned)h) << 16);
}

__device__ __forceinline__ void gload16(const u16* g, u16* l) {
    __builtin_amdgcn_global_load_lds(
        (const __attribute__((address_space(1))) unsigned int*)g,
        (__attribute__((address_space(3))) unsigned int*)l,
        16, 0, 0);
}

// ---------------------------------------------------------------------------
// bf16 GEMM (r18 form): Y16 = A x B^T, all-bf16 out. 128x128, BK=32.
// ---------------------------------------------------------------------------
__global__ __launch_bounds__(256)
void gemm_bf16_kernel(const u16* __restrict__ Ah, const u16* __restrict__ Bh,
                      u16* __restrict__ Y, int ldy,
                      int K, int nxmask, int nxshift)
{
    __shared__ u16 lds[2][2][4096];   // 32 KB

    const int nwg = gridDim.x;
    const int q   = nwg >> 3, r8 = nwg & 7;
    const int xcd = blockIdx.x & 7, pos = blockIdx.x >> 3;
    const int lin = (xcd < r8 ? xcd * (q + 1) : r8 * (q + 1) + (xcd - r8) * q) + pos;
    const int bm0 = (lin >> nxshift) * 128;
    const int bn0 = (lin & nxmask) * 128;

    const int tid  = threadIdx.x;
    const int lane = tid & 63;
    const int wid  = tid >> 6;
    const int wr   = wid >> 1;
    const int wc   = wid & 1;

    const int srow = tid >> 2;
    const int scol = ((tid & 3) ^ ((tid >> 3) & 3)) * 8;   // u16 units
    const size_t aoff0 = (size_t)(bm0 + srow) * K + scol;
    const size_t aoff1 = (size_t)(bm0 + srow + 64) * K + scol;
    const size_t boff0 = (size_t)(bn0 + srow) * K + scol;
    const size_t boff1 = (size_t)(bn0 + srow + 64) * K + scol;
    const int c0 = tid * 8;
    const int c1 = 2048 + tid * 8;

    u16* L0 = &lds[0][0][0];              // buffer stride 8192 u16

    f32x4 zero = {0.f, 0.f, 0.f, 0.f};
    f32x4 acc[4][4];
    #pragma unroll
    for (int i = 0; i < 4; ++i)
        #pragma unroll
        for (int j = 0; j < 4; ++j) acc[i][j] = zero;

    const int fchunk = (((lane >> 4) ^ ((lane >> 1) & 3))) * 8;
    const int a_fr = (wr * 64 + (lane & 15)) * 32 + fchunk;
    const int b_fr = (wc * 64 + (lane & 15)) * 32 + fchunk;

    const int nk = K >> 5;

    {
        u16* L = L0;
        gload16(Ah + aoff0, L + c0);          gload16(Ah + aoff1, L + c1);
        gload16(Bh + boff0, L + 4096 + c0);   gload16(Bh + boff1, L + 4096 + c1);
    }
    int cur = 0;
    for (int t = 0; t < nk; ++t) {
        if (t + 1 < nk) {
            const int k0 = (t + 1) * 32;
            u16* L = L0 + (cur ^ 1) * 8192;
            gload16(Ah + aoff0 + k0, L + c0);         gload16(Ah + aoff1 + k0, L + c1);
            gload16(Bh + boff0 + k0, L + 4096 + c0);  gload16(Bh + boff1 + k0, L + 4096 + c1);
            asm volatile("s_waitcnt vmcnt(4)\n\ts_barrier" ::: "memory");
        } else {
            asm volatile("s_waitcnt vmcnt(0)\n\ts_barrier" ::: "memory");
        }
        const u16* L = L0 + cur * 8192;
        s16x8 bh[4];
        #pragma unroll
        for (int nf = 0; nf < 4; ++nf)
            bh[nf] = *(const s16x8*)(L + 4096 + b_fr + nf * 512);
        #pragma unroll
        for (int mf = 0; mf < 4; ++mf) {
            s16x8 ahv = *(const s16x8*)(L + a_fr + mf * 512);
            #pragma unroll
            for (int nf = 0; nf < 4; ++nf)
                acc[mf][nf] = __builtin_amdgcn_mfma_f32_16x16x32_bf16(ahv, bh[nf], acc[mf][nf], 0, 0, 0);
        }
        asm volatile("s_barrier" ::: "memory");
        cur ^= 1;
    }

    #pragma unroll
    for (int mf = 0; mf < 4; ++mf) {
        const int row0 = bm0 + wr * 64 + mf * 16 + (lane >> 4) * 4;
        #pragma unroll
        for (int nf = 0; nf < 4; ++nf) {
            const int col = bn0 + wc * 64 + nf * 16 + (lane & 15);
            #pragma unroll
            for (int r = 0; r < 4; ++r)
                Y[(size_t)(row0 + r) * ldy + col] = f2bf(acc[mf][nf][r]);
        }
    }
}

// ---------------------------------------------------------------------------
// cvt body: f32 [M][1024] -> bf16 (8 elems/thread), zero-padded rows.
// ---------------------------------------------------------------------------
__device__ __forceinline__
void cvt_body(int bid, const float* __restrict__ A, u16* __restrict__ Hh, int M)
{
    const size_t g  = (size_t)bid * 256 + threadIdx.x;
    const size_t i8 = g * 8;
    const int row   = (int)(i8 >> 10);
    f32x4 a = {0.f, 0.f, 0.f, 0.f}, b = {0.f, 0.f, 0.f, 0.f};
    if (row < M) {
        a = *(const f32x4*)(A + i8);
        b = *(const f32x4*)(A + i8 + 4);
    }
    u16x8 h;
    #pragma unroll
    for (int j = 0; j < 4; ++j) { h[j] = f2bf(a[j]); h[4 + j] = f2bf(b[j]); }
    *(u16x8*)(Hh + i8) = h;
}

// ---------------------------------------------------------------------------
// fill body: 16 edges/thread, row-sliced XCD-affine, u16 rows.
// ---------------------------------------------------------------------------
__device__ __forceinline__
void fill_body16(int fx, int s, int side,
                 const u16* __restrict__ r16R, const int* __restrict__ colsR,
                 const float* __restrict__ valsR,
                 const u16* __restrict__ r16P, const int* __restrict__ colsP,
                 const float* __restrict__ valsP,
                 int* __restrict__ curR, int* __restrict__ curP,
                 int2* __restrict__ evR, int2* __restrict__ evP,
                 int NR, int NP, int E)
{
    const int slice = fx & 7;
    const int chunk = fx >> 3;
    const int N          = side ? NP : NR;
    const u16* r16       = side ? r16P : r16R;
    const int* cols      = side ? colsP : colsR;
    const float* vals    = side ? valsP : valsR;
    int* cursor          = side ? curP : curR;
    int2* ev             = side ? evP : evR;

    const int Nsl = (N + 7) >> 3;
    const int r0 = slice * Nsl;
    const int r1 = min(N, r0 + Nsl);

    const int e0 = chunk * 4096 + threadIdx.x * 16;
    if (e0 >= E) return;
    const size_t base = (size_t)s * E;

    if (e0 + 16 <= E) {
        u64 rq[4];
        #pragma unroll
        for (int g = 0; g < 4; ++g)
            rq[g] = *(const u64*)(r16 + base + e0 + g * 4);
        #pragma unroll
        for (int g = 0; g < 4; ++g) {
            #pragma unroll
            for (int j = 0; j < 4; ++j) {
                int r = (int)(u16)(rq[g] >> (16 * j));
                if (r >= r0 && r < r1) {
                    int idx = e0 + g * 4 + j;
                    int pos = atomicAdd(cursor + s * N + r, 1);
                    ev[base + pos] = make_int2(cols[base + idx],
                                               __float_as_int(vals[base + idx]));
                }
            }
        }
    } else {
        for (int j = 0; j < 16 && e0 + j < E; ++j) {
            int r = (int)r16[base + e0 + j];
            if (r >= r0 && r < r1) {
                int pos = atomicAdd(cursor + s * N + r, 1);
                ev[base + pos] = make_int2(cols[base + e0 + j],
                                           __float_as_int(vals[base + e0 + j]));
            }
        }
    }
}

// ---------------------------------------------------------------------------
// FUSED cvt ∥ fill: grid (XW, 4, 3). z==0 -> cvt (id = y*XW+x);
// z in {1,2} -> fill side z-1, s=y, fx=x (x < FX16). No LDS -> 8 blocks/CU.
// ---------------------------------------------------------------------------
__global__ __launch_bounds__(256)
void fused_cvt_fill_kernel(const float* __restrict__ H_rna, const float* __restrict__ H_prot,
                           u16* __restrict__ AhR_full, u16* __restrict__ AhP_full,
                           int CVR, int CV, int XW,
                           const u16* __restrict__ r16R, const int* __restrict__ colsR,
                           const float* __restrict__ valsR,
                           const u16* __restrict__ r16P, const int* __restrict__ colsP,
                           const float* __restrict__ valsP,
                           int* __restrict__ curR, int* __restrict__ curP,
                           int2* __restrict__ evR, int2* __restrict__ evP,
                           int NR, int NP, int E, int FX16)
{
    const int z = blockIdx.z;
    if (z == 0) {
        int id = blockIdx.y * XW + blockIdx.x;
        if (id >= CV) return;
        if (id < CVR) cvt_body(id, H_rna, AhR_full, NR);
        else          cvt_body(id - CVR, H_prot, AhP_full, NP);
    } else {
        if ((int)blockIdx.x >= FX16) return;
        fill_body16(blockIdx.x, blockIdx.y, z - 1,
                    r16R, colsR, valsR, r16P, colsP, valsP,
                    curR, curP, evR, evP, NR, NP, E);
    }
}

__global__ __launch_bounds__(256)
void zero_u16_kernel(u16* __restrict__ a, int n)
{
    int i = blockIdx.x * 256 + threadIdx.x;
    if (i < n) a[i] = 0;
}

// ---------------------------------------------------------------------------
// CSR build
// ---------------------------------------------------------------------------
__global__ __launch_bounds__(256)
void zero2_i32_kernel(int* __restrict__ a, int na, int* __restrict__ b, int nb)
{
    int i = blockIdx.x * 256 + threadIdx.x;
    if (i < na) a[i] = 0;
    if (i < nb) b[i] = 0;
}

// merged: pack rows int32 -> u16 AND histogram, one read pass. 4 edges/thread.
__global__ __launch_bounds__(256)
void pack_hist2_kernel(const int* __restrict__ rowsR, const int* __restrict__ rowsP,
                       u16* __restrict__ r16R, u16* __restrict__ r16P,
                       int* __restrict__ cntR, int* __restrict__ cntP,
                       int NR, int NP, int E)
{
    int s = blockIdx.y;
    int e = (blockIdx.x * 256 + threadIdx.x) * 4;
    if (e >= E) return;
    const int* rows = blockIdx.z ? rowsP : rowsR;
    u16* r16 = blockIdx.z ? r16P : r16R;
    int* cnt = blockIdx.z ? cntP : cntR;
    const int N = blockIdx.z ? NP : NR;
    size_t base = (size_t)s * E;
    if (e + 4 <= E) {
        int4 r4 = *(const int4*)(rows + base + e);
        u16 p[4] = {(u16)r4.x, (u16)r4.y, (u16)r4.z, (u16)r4.w};
        *(u64*)(r16 + base + e) = *(const u64*)p;
        atomicAdd(cnt + s * N + r4.x, 1);
        atomicAdd(cnt + s * N + r4.y, 1);
        atomicAdd(cnt + s * N + r4.z, 1);
        atomicAdd(cnt + s * N + r4.w, 1);
    } else {
        for (int j = 0; j < 4 && e + j < E; ++j) {
            int r = rows[base + e + j];
            r16[base + e + j] = (u16)r;
            atomicAdd(cnt + s * N + r, 1);
        }
    }
}

__global__ __launch_bounds__(256)
void scan_block2_kernel(const int* __restrict__ cR, int* __restrict__ rpR,
                        int* __restrict__ bsR, int NR, int np1R, int NBR,
                        const int* __restrict__ cP, int* __restrict__ rpP,
                        int* __restrict__ bsP, int NP, int np1P, int NBP)
{
    const int side = blockIdx.z;
    const int NB = side ? NBP : NBR;
    if ((int)blockIdx.x >= NB) return;
    const int N = side ? NP : NR;
    const int np1 = side ? np1P : np1R;
    const int* counts = side ? cP : cR;
    int* rowptr = side ? rpP : rpR;
    int* blocksum = side ? bsP : bsR;

    __shared__ int sd[256];
    int s = blockIdx.y;
    int i = blockIdx.x * 256 + threadIdx.x;
    int tid = threadIdx.x;
    int v = (i < N) ? counts[s * N + i] : 0;
    sd[tid] = v;
    __syncthreads();
    #pragma unroll
    for (int off = 1; off < 256; off <<= 1) {
        int t = (tid >= off) ? sd[tid - off] : 0;
        __syncthreads();
        sd[tid] += t;
        __syncthreads();
    }
    if (i < N) rowptr[s * np1 + i] = sd[tid] - v;
    if (tid == 255) blocksum[s * NB + blockIdx.x] = sd[255];
}

__global__ __launch_bounds__(256)
void scan_aux2_kernel(int* __restrict__ bsR, int NBR, int* __restrict__ bsP, int NBP)
{
    const int side = blockIdx.x >> 2;
    const int s = blockIdx.x & 3;
    int* blocksum = side ? bsP : bsR;
    const int NB = side ? NBP : NBR;

    __shared__ int sd[256];
    int tid = threadIdx.x;
    int v = (tid < NB) ? blocksum[s * NB + tid] : 0;
    sd[tid] = v;
    __syncthreads();
    #pragma unroll
    for (int off = 1; off < 256; off <<= 1) {
        int t = (tid >= off) ? sd[tid - off] : 0;
        __syncthreads();
        sd[tid] += t;
        __syncthreads();
    }
    if (tid < NB) blocksum[s * NB + tid] = sd[tid] - v;
}

__global__ __launch_bounds__(256)
void finalize2_kernel(int* __restrict__ rpR, const int* __restrict__ bsR,
                      int* __restrict__ curR, int NR, int np1R, int NBR,
                      int* __restrict__ rpP, const int* __restrict__ bsP,
                      int* __restrict__ curP, int NP, int np1P, int NBP, int E)
{
    const int side = blockIdx.z;
    const int NB = side ? NBP : NBR;
    if ((int)blockIdx.x >= NB) return;
    const int N = side ? NP : NR;
    const int np1 = side ? np1P : np1R;
    int* rowptr = side ? rpP : rpR;
    const int* blocksum = side ? bsP : bsR;
    int* cursor = side ? curP : curR;

    int s = blockIdx.y;
    int i = blockIdx.x * 256 + threadIdx.x;
    if (i < N) {
        int v = rowptr[s * np1 + i] + blocksum[s * NB + blockIdx.x];
        rowptr[s * np1 + i] = v;
        cursor[s * N + i] = v;
    }
    if (i == N) rowptr[s * np1 + N] = E;
}

// ---------------------------------------------------------------------------
// CSR SpMM, quarter/eighth-wave edge parallelism (round 17, unchanged).
// ---------------------------------------------------------------------------
template<int KCH, int MODE>
__global__ __launch_bounds__(256)
void spmm2_kernel(const int* __restrict__ rpR, const int* __restrict__ rpP,
                  int np1R, int np1P,
                  const int2* __restrict__ evRg, const int2* __restrict__ evPg,
                  const u16* __restrict__ InR, const u16* __restrict__ InP, int ldi,
                  u16* __restrict__ BaseR, u16* __restrict__ BaseP, int ldb,
                  u16* __restrict__ OHR, u16* __restrict__ OHP,
                  float* __restrict__ OFR, float* __restrict__ OFP, int ldo,
                  int NR, int E)
{
    int r = blockIdx.x;
    const int s    = threadIdx.x >> 6;
    const int lane = threadIdx.x & 63;
    const int* rp; const int2* ev; const u16* In; u16* Base; int np1;
    u16* OH; float* OF;
    if (r < NR) { rp = rpR; ev = evRg; In = InR; Base = BaseR; np1 = np1R;
                  OH = OHR; OF = OFR; }
    else { r -= NR; rp = rpP; ev = evPg; In = InP; Base = BaseP; np1 = np1P;
           OH = OHP; OF = OFP; }
    int e0 = __builtin_amdgcn_readfirstlane(rp[s * np1 + r]);
    int e1 = __builtin_amdgcn_readfirstlane(rp[s * np1 + r + 1]);
    if (MODE == 0 && e0 == e1) return;
    ev += (size_t)s * E;

    if (KCH == 128) {
        const int qg = lane >> 4;
        const int ql = lane & 15;
        const int col = s * 128 + ql * 8;
        float a[8] = {0.f, 0.f, 0.f, 0.f, 0.f, 0.f, 0.f, 0.f};
        int e = e0;
        for (; e + 7 < e1; e += 8) {
            int2 p0 = ev[e + qg];
            int2 p1 = ev[e + 4 + qg];
            float v0 = __int_as_float(p0.y);
            float v1 = __int_as_float(p1.y);
            u16x8 x0 = *(const u16x8*)(In + (size_t)p0.x * ldi + col);
            u16x8 x1 = *(const u16x8*)(In + (size_t)p1.x * ldi + col);
            #pragma unroll
            for (int j = 0; j < 8; ++j)
                a[j] += v0 * bf2f(x0[j]) + v1 * bf2f(x1[j]);
        }
        for (; e < e1; e += 4) {
            if (e + qg < e1) {
                int2 pv = ev[e + qg];
                float v = __int_as_float(pv.y);
                u16x8 x = *(const u16x8*)(In + (size_t)pv.x * ldi + col);
                #pragma unroll
                for (int j = 0; j < 8; ++j)
                    a[j] += v * bf2f(x[j]);
            }
        }
        #pragma unroll
        for (int j = 0; j < 8; ++j) {
            a[j] += __shfl_xor(a[j], 16);
            a[j] += __shfl_xor(a[j], 32);
        }
        if (lane < 16) {
            u16x8* bp = (u16x8*)(Base + (size_t)r * ldb + col);
            u16x8 b = *bp;
            if (MODE == 0) {
                u16x8 nb;
                #pragma unroll
                for (int j = 0; j < 8; ++j) nb[j] = f2bf(bf2f(b[j]) + a[j]);
                *bp = nb;
            } else if (MODE == 1) {
                u16x8 h;
                #pragma unroll
                for (int j = 0; j < 8; ++j) h[j] = f2bf(fmaxf(bf2f(b[j]) + a[j], 0.f));
                *(u16x8*)(OH + (size_t)r * ldo + col) = h;
            } else {
                f32x4 o0, o1;
                #pragma unroll
                for (int j = 0; j < 4; ++j) {
                    o0[j] = fmaxf(bf2f(b[j]) + a[j], 0.f);
                    o1[j] = fmaxf(bf2f(b[4 + j]) + a[4 + j], 0.f);
                }
                *(f32x4*)(OF + (size_t)r * ldo + col) = o0;
                *(f32x4*)(OF + (size_t)r * ldo + col + 4) = o1;
            }
        }
    } else {   // KCH == 64
        const int og = lane >> 3;
        const int ol = lane & 7;
        const int col = s * 64 + ol * 8;
        float a[8] = {0.f, 0.f, 0.f, 0.f, 0.f, 0.f, 0.f, 0.f};
        int e = e0;
        for (; e + 15 < e1; e += 16) {
            int2 p0 = ev[e + og];
            int2 p1 = ev[e + 8 + og];
            float v0 = __int_as_float(p0.y);
            float v1 = __int_as_float(p1.y);
            u16x8 x0 = *(const u16x8*)(In + (size_t)p0.x * ldi + col);
            u16x8 x1 = *(const u16x8*)(In + (size_t)p1.x * ldi + col);
            #pragma unroll
            for (int j = 0; j < 8; ++j)
                a[j] += v0 * bf2f(x0[j]) + v1 * bf2f(x1[j]);
        }
        for (; e < e1; e += 8) {
            if (e + og < e1) {
                int2 pv = ev[e + og];
                float v = __int_as_float(pv.y);
                u16x8 x = *(const u16x8*)(In + (size_t)pv.x * ldi + col);
                #pragma unroll
                for (int j = 0; j < 8; ++j)
                    a[j] += v * bf2f(x[j]);
            }
        }
        #pragma unroll
        for (int j = 0; j < 8; ++j) {
            a[j] += __shfl_xor(a[j], 8);
            a[j] += __shfl_xor(a[j], 16);
            a[j] += __shfl_xor(a[j], 32);
        }
        if (lane < 8) {
            u16x8* bp = (u16x8*)(Base + (size_t)r * ldb + col);
            u16x8 b = *bp;
            if (MODE == 0) {
                u16x8 nb;
                #pragma unroll
                for (int j = 0; j < 8; ++j) nb[j] = f2bf(bf2f(b[j]) + a[j]);
                *bp = nb;
            } else {
                f32x4 o0, o1;
                #pragma unroll
                for (int j = 0; j < 4; ++j) {
                    o0[j] = fmaxf(bf2f(b[j]) + a[j], 0.f);
                    o1[j] = fmaxf(bf2f(b[4 + j]) + a[4 + j], 0.f);
                }
                *(f32x4*)(OF + (size_t)r * ldo + col) = o0;
                *(f32x4*)(OF + (size_t)r * ldo + col + 4) = o1;
            }
        }
    }
}

// fallback-only final relu over bf16 base
__global__ __launch_bounds__(256)
void relu_out_kernel(const u16* __restrict__ Z, int ld, int coff,
                     float* __restrict__ out, int M)
{
    int g = blockIdx.x * 256 + threadIdx.x;
    if (g >= M * 256) return;
    int row = g >> 8;
    int col = g & 255;
    out[g] = fmaxf(bf2f(Z[(size_t)row * ld + coff + col]), 0.f);
}

// ---------------------------------------------------------------------------
// weight packing (transposed [N][K], bf16)
// ---------------------------------------------------------------------------
__global__ __launch_bounds__(256)
void pack_b0_kernel(const float* __restrict__ w0, const float* __restrict__ sw0,
                    u16* __restrict__ Bh)
{
    int g = blockIdx.x * 256 + threadIdx.x;
    int j = g >> 10, d = g & 1023;
    float v;
    if (j < 512) v = w0[((size_t)(j >> 7) * 1024 + d) * 128 + (j & 127)];
    else         v = sw0[(size_t)d * 512 + (j - 512)];
    Bh[g] = f2bf(v);
}

__global__ __launch_bounds__(256)
void pack_b1_kernel(const float* __restrict__ w1, const float* __restrict__ sw1,
                    u16* __restrict__ Bh)
{
    int g = blockIdx.x * 256 + threadIdx.x;
    int j = g >> 9, d = g & 511;
    float v;
    if (j < 256) v = w1[((size_t)(j >> 6) * 512 + d) * 64 + (j & 63)];
    else         v = sw1[(size_t)d * 256 + (j - 256)];
    Bh[g] = f2bf(v);
}

extern "C" void kernel_launch(void* const* d_in, const int* in_sizes, int n_in,
                              void* d_out, int out_size, void* d_ws, size_t ws_size,
                              hipStream_t stream)
{
    const int*   rna_rows  = (const int*)  d_in[0];
    const int*   rna_cols  = (const int*)  d_in[1];
    const float* rna_vals  = (const float*)d_in[2];
    const int*   prot_rows = (const int*)  d_in[3];
    const int*   prot_cols = (const int*)  d_in[4];
    const float* prot_vals = (const float*)d_in[5];
    const float* H_rna     = (const float*)d_in[6];
    const float* H_prot    = (const float*)d_in[7];
    const float* w0        = (const float*)d_in[8];
    const float* sw0       = (const float*)d_in[9];
    const float* w1        = (const float*)d_in[10];
    const float* sw1       = (const float*)d_in[11];

    const int NRNA = 50000, NPROT = 20000, S = 4, E = 500000;
    const int MP_RNA = 50048, MP_PROT = 20096;
    const int MP_ALL = MP_RNA + MP_PROT;           // 70144 = 548 * 128
    const int NP1_R = NRNA + 1, NP1_P = NPROT + 1;
    const int NB_R = (NRNA + 255) / 256;
    const int NB_P = (NPROT + 255) / 256;
    const int EB4  = (E + 1023) / 1024;
    const int EB16 = (E + 4095) / 4096;            // 123
    const int FX16 = EB16 * 8;                     // 984 fill x-blocks
    const int CVR  = MP_RNA / 2, CVP = MP_PROT / 2;
    const int CV   = CVR + CVP;                    // 35072 cvt blocks
    const int XW   = (CV + 3) / 4;                 // 8768

    // --- ws layout ---
    char* ws = (char*)d_ws;
    size_t off = 0;
    u16*   Y16   = (u16*)  (ws + off); off += (size_t)MP_ALL * 1024 * 2;  // L0 [*,1024]; L1 aliases [*,512]
    u16*   Ahbig = (u16*)  (ws + off); off += (size_t)MP_ALL * 1024 * 2;
    u16*   B0h   = (u16*)  (ws + off); off += (size_t)1024 * 1024 * 2;
    u16*   B1h   = (u16*)  (ws + off); off += (size_t)512 * 512 * 2;
    size_t base_bytes = off;

    u16* AhR = Ahbig;                               // layer-1 A views [MP_ALL][512]
    u16* AhP = Ahbig + (size_t)MP_RNA * 512;

    // CSR scratch (ev + packed rows + meta)
    size_t csr_bytes = 0;
    csr_bytes += (size_t)S * E * 8 * 2;                       // evR + evP
    csr_bytes += (size_t)S * E * 2 * 2;                       // r16R + r16P
    csr_bytes += ((size_t)S * (NRNA * 2 + NP1_R + NB_R)) * 4;
    csr_bytes += ((size_t)S * (NPROT * 2 + NP1_P + NB_P)) * 4;
    const bool csr_in_ws = (ws_size >= base_bytes + csr_bytes);

    char* csr = csr_in_ws ? (ws + base_bytes) : (char*)d_out;
    size_t coff = 0;
    int2*  evR     = (int2*) (csr + coff); coff += (size_t)S * E * 8;
    int2*  evP     = (int2*) (csr + coff); coff += (size_t)S * E * 8;
    u16*   r16R    = (u16*)  (csr + coff); coff += (size_t)S * E * 2;
    u16*   r16P    = (u16*)  (csr + coff); coff += (size_t)S * E * 2;
    int*   countsR = (int*)  (csr + coff); coff += (size_t)S * NRNA * 4;
    int*   rowptrR = (int*)  (csr + coff); coff += (size_t)S * NP1_R * 4;
    int*   cursorR = (int*)  (csr + coff); coff += (size_t)S * NRNA * 4;
    int*   bsumR   = (int*)  (csr + coff); coff += (size_t)S * NB_R * 4;
    int*   countsP = (int*)  (csr + coff); coff += (size_t)S * NPROT * 4;
    int*   rowptrP = (int*)  (csr + coff); coff += (size_t)S * NP1_P * 4;
    int*   cursorP = (int*)  (csr + coff); coff += (size_t)S * NPROT * 4;
    int*   bsumP   = (int*)  (csr + coff); coff += (size_t)S * NB_P * 4;

    dim3 blk(256);
    float* out = (float*)d_out;

    // --- pack weights ---
    pack_b0_kernel<<<(1024 * 1024) / 256, blk, 0, stream>>>(w0, sw0, B0h);
    pack_b1_kernel<<<(512 * 512) / 256, blk, 0, stream>>>(w1, sw1, B1h);

    // --- CSR build prefix (pack+hist merged) ---
    zero2_i32_kernel<<<(S * NRNA + 255) / 256, blk, 0, stream>>>(countsR, S * NRNA,
                                                                 countsP, S * NPROT);
    pack_hist2_kernel<<<dim3(EB4, S, 2), blk, 0, stream>>>(
        rna_rows, prot_rows, r16R, r16P, countsR, countsP, NRNA, NPROT, E);
    scan_block2_kernel<<<dim3(NB_R, S, 2), blk, 0, stream>>>(
        countsR, rowptrR, bsumR, NRNA, NP1_R, NB_R,
        countsP, rowptrP, bsumP, NPROT, NP1_P, NB_P);
    scan_aux2_kernel<<<8, blk, 0, stream>>>(bsumR, NB_R, bsumP, NB_P);
    finalize2_kernel<<<dim3(NB_R, S, 2), blk, 0, stream>>>(
        rowptrR, bsumR, cursorR, NRNA, NP1_R, NB_R,
        rowptrP, bsumP, cursorP, NPROT, NP1_P, NB_P, E);

    // --- FUSED cvt ∥ fill (both LDS-free, 8 blocks/CU) ---
    fused_cvt_fill_kernel<<<dim3(XW, 4, 3), blk, 0, stream>>>(
        H_rna, H_prot, Ahbig, Ahbig + (size_t)MP_RNA * 1024, CVR, CV, XW,
        r16R, rna_cols, rna_vals, r16P, prot_cols, prot_vals,
        cursorR, cursorP, evR, evP, NRNA, NPROT, E, FX16);

    // --- layer 0 GEMM (standalone, r18 form) ---
    gemm_bf16_kernel<<<8 * (MP_ALL / 128), blk, 0, stream>>>(
        Ahbig, B0h, Y16, 1024, 1024, 7, 3);

    // --- layer 0 SpMM: Ah = bf16(relu(base + agg)) ---
    spmm2_kernel<128, 1><<<NRNA + NPROT, blk, 0, stream>>>(
        rowptrR, rowptrP, NP1_R, NP1_P, evR, evP,
        Y16 + (size_t)MP_RNA * 1024,      // RNA gathers prot tmp (cols 0..511)
        Y16,                              // PROT gathers rna tmp
        1024,
        Y16 + 512, Y16 + (size_t)MP_RNA * 1024 + 512, 1024,   // bf16 base halves
        AhR, AhP, nullptr, nullptr, 512,
        NRNA, E);

    // --- zero layer-1 A pad rows ---
    zero_u16_kernel<<<(48 * 512 + 255) / 256, blk, 0, stream>>>(
        AhR + (size_t)NRNA * 512, 48 * 512);
    zero_u16_kernel<<<(96 * 512 + 255) / 256, blk, 0, stream>>>(
        AhP + (size_t)NPROT * 512, 96 * 512);

    // --- layer 1: one GEMM (N=K=512), Y16_1 aliases Y16 [MP_ALL][512] ---
    gemm_bf16_kernel<<<4 * (MP_ALL / 128), blk, 0, stream>>>(
        Ahbig, B1h, Y16, 512, 512, 3, 2);

    // --- layer 1 SpMM ---
    if (csr_in_ws) {
        spmm2_kernel<64, 2><<<NRNA + NPROT, blk, 0, stream>>>(
            rowptrR, rowptrP, NP1_R, NP1_P, evR, evP,
            Y16 + (size_t)MP_RNA * 512, Y16, 512,
            Y16 + 256, Y16 + (size_t)MP_RNA * 512 + 256, 512,
            nullptr, nullptr,
            out, out + (size_t)NRNA * 256, 256,
            NRNA, E);
    } else {
        spmm2_kernel<64, 0><<<NRNA + NPROT, blk, 0, stream>>>(
            rowptrR, rowptrP, NP1_R, NP1_P, evR, evP,
            Y16 + (size_t)MP_RNA * 512, Y16, 512,
            Y16 + 256, Y16 + (size_t)MP_RNA * 512 + 256, 512,
            nullptr, nullptr,
            nullptr, nullptr, 0,
            NRNA, E);
        relu_out_kernel<<<(NRNA * 256) / 256, blk, 0, stream>>>(Y16, 512, 256, out, NRNA);
        relu_out_kernel<<<(NPROT * 256) / 256, blk, 0, stream>>>(
            Y16 + (size_t)MP_RNA * 512, 512, 256, out + (size_t)NRNA * 256, NPROT);
    }
}